// Round 6
// baseline (909.650 us; speedup 1.0000x reference)
//
#include <hip/hip_runtime.h>
#include <math.h>

// Problem constants (fixed by the reference)
constexpr int kN0 = 400000, kN1 = 100000, kN2 = 20000;
constexpr int kE1 = 1000000, kE2 = 200000;
constexpr int kIN = 128, kHID = 256, kOUT = 47;
constexpr float kEPS = 1e-5f, kNEG = 0.2f;

#define DEV static __device__ __forceinline__

typedef __attribute__((ext_vector_type(8))) short short8;
typedef __attribute__((ext_vector_type(4))) float f32x4;

DEV float b2f(unsigned short u) { return __uint_as_float(((unsigned)u) << 16); }
DEV unsigned short f2bf(float f) {
    unsigned u = __float_as_uint(f);
    unsigned r = (u + 0x7fffu + ((u >> 16) & 1u)) >> 16;   // RNE
    return (unsigned short)r;
}

DEV void gload_lds16(const void* g, void* l) {
    __builtin_amdgcn_global_load_lds(
        (const __attribute__((address_space(1))) void*)g,
        (__attribute__((address_space(3))) void*)l, 16, 0, 0);
}

// ---------------- utility ----------------
__global__ void zero_f32(float* __restrict__ p, int n) {
    int i = blockIdx.x * blockDim.x + threadIdx.x;
    int st = gridDim.x * blockDim.x;
    for (; i < n; i += st) p[i] = 0.f;
}

// f32 -> bf16 bulk convert (n multiple of 8), grid-stride
__global__ __launch_bounds__(256) void conv_bf16(const float* __restrict__ in,
                                                 unsigned short* __restrict__ out, int n) {
    int st = gridDim.x * blockDim.x;
    for (int t = blockIdx.x * blockDim.x + threadIdx.x; t * 8 < n; t += st) {
        int i = t * 8;
        float4 v0 = *reinterpret_cast<const float4*>(&in[i]);
        float4 v1 = *reinterpret_cast<const float4*>(&in[i + 4]);
        ushort4 o0, o1;
        o0.x = f2bf(v0.x); o0.y = f2bf(v0.y); o0.z = f2bf(v0.z); o0.w = f2bf(v0.w);
        o1.x = f2bf(v1.x); o1.y = f2bf(v1.y); o1.z = f2bf(v1.z); o1.w = f2bf(v1.w);
        *reinterpret_cast<ushort4*>(&out[i]) = o0;
        *reinterpret_cast<ushort4*>(&out[i + 4]) = o1;
    }
}

// W[K][N] f32 -> Wt[N][K] bf16, element-parallel (K = power of 2, kshift = log2 K)
__global__ void transp_w_par(const float* __restrict__ W, unsigned short* __restrict__ Wt,
                             int kshift, int N) {
    int i = blockIdx.x * blockDim.x + threadIdx.x;
    int K = 1 << kshift;
    if (i >= N * K) return;
    int n = i >> kshift, k = i & (K - 1);
    Wt[i] = f2bf(W[(size_t)k * N + n]);
}

// ================= CSR build =================
__global__ void hist_dst(const int* __restrict__ dst, int* __restrict__ counts, int E) {
    int e = blockIdx.x * blockDim.x + threadIdx.x;
    if (e < E) atomicAdd(&counts[dst[e]], 1);
}

__global__ __launch_bounds__(256) void scan_block(const int* __restrict__ counts, int n,
                                                  int* __restrict__ offs, int* __restrict__ bsum) {
    __shared__ int sh[256];
    int tid = threadIdx.x;
    int base = blockIdx.x * 1024 + tid * 4;
    int c0 = (base + 0 < n) ? counts[base + 0] : 0;
    int c1 = (base + 1 < n) ? counts[base + 1] : 0;
    int c2 = (base + 2 < n) ? counts[base + 2] : 0;
    int c3 = (base + 3 < n) ? counts[base + 3] : 0;
    int tot = c0 + c1 + c2 + c3;
    sh[tid] = tot;
    __syncthreads();
    for (int o = 1; o < 256; o <<= 1) {
        int t = (tid >= o) ? sh[tid - o] : 0;
        __syncthreads();
        sh[tid] += t;
        __syncthreads();
    }
    int excl = sh[tid] - tot;
    if (base + 0 < n) offs[base + 0] = excl;
    if (base + 1 < n) offs[base + 1] = excl + c0;
    if (base + 2 < n) offs[base + 2] = excl + c0 + c1;
    if (base + 3 < n) offs[base + 3] = excl + c0 + c1 + c2;
    if (tid == 255) bsum[blockIdx.x] = sh[255];
}

__global__ __launch_bounds__(256) void scan_bsums(const int* __restrict__ bsum,
                                                  int* __restrict__ bscan, int nb) {
    __shared__ int sh[256];
    int tid = threadIdx.x;
    int v = (tid < nb) ? bsum[tid] : 0;
    sh[tid] = v;
    __syncthreads();
    for (int o = 1; o < 256; o <<= 1) {
        int t = (tid >= o) ? sh[tid - o] : 0;
        __syncthreads();
        sh[tid] += t;
        __syncthreads();
    }
    if (tid < nb) bscan[tid] = sh[tid] - v;
}

__global__ void scan_add(int* __restrict__ offs, const int* __restrict__ bscan,
                         const int* __restrict__ counts, int n) {
    int i = blockIdx.x * blockDim.x + threadIdx.x;
    if (i < n) {
        int v = offs[i] + bscan[i >> 10];
        offs[i] = v;
        if (i == n - 1) offs[n] = v + counts[i];
    }
}

// store src node id directly
__global__ void csr_scatter(const int* __restrict__ dst, const int* __restrict__ src,
                            const int* __restrict__ offs,
                            int* __restrict__ cur, int* __restrict__ srcs, int E) {
    int e = blockIdx.x * blockDim.x + threadIdx.x;
    if (e >= E) return;
    int d = dst[e];
    int pos = offs[d] + atomicAdd(&cur[d], 1);
    srcs[pos] = src[e];
}

// ================= bf16 MFMA GEMM, single-stage full-K =================
// C[M][N] (+)= A[M][K]bf16 @ Bt[N][K]bf16^T (+ biases), K = KSEG*64 staged entirely
// upfront as KSEG LDS planes (one barrier total). BM=BN=128, 4 waves (2x2).
// STATS: per-column sum/sumsq into stats[0..255]/[256..511].
// AL: fused attention dots als[row][h] = <out_row_head, a_src[h]>, ald for row<Ndst.
//     (each wave owns 64 rows x one head, so the reduction is 4 shfl_xor, no atomics)
template <bool OUTBF, bool ACCUM, bool STATS, bool AL, int KSEG>
__global__ __launch_bounds__(256) void mfma_gemm_fk(const unsigned short* __restrict__ A,
                                                    const unsigned short* __restrict__ Bt,
                                                    void* __restrict__ Cv,
                                                    const float* __restrict__ bias1,
                                                    const float* __restrict__ bias2,
                                                    float* __restrict__ stats,
                                                    const float* __restrict__ a_src,
                                                    const float* __restrict__ a_dst,
                                                    float* __restrict__ als,
                                                    float* __restrict__ ald,
                                                    int M, int N, int Ndst) {
    constexpr int K = KSEG * 64;
    __shared__ unsigned short As[KSEG][128 * 64];
    __shared__ unsigned short Bs[KSEG][128 * 64];
    const int tid = threadIdx.x;
    const int wid = tid >> 6, lane = tid & 63;
    const int wr = wid >> 1, wc = wid & 1;
    const int l15 = lane & 15, l4 = lane >> 4;
    const int m0 = blockIdx.y * 128, n0 = blockIdx.x * 128;

    const int rsub = lane >> 3;            // 0..7 (row within 8-row chunk)
    const int kslot = (lane & 7) ^ rsub;   // pre-swizzled source k-slot (16B units)

    // ---- stage ALL of K (KSEG planes x 16 chunks of 1KB each per matrix) ----
    #pragma unroll
    for (int ks = 0; ks < KSEG; ++ks) {
        #pragma unroll
        for (int c = 0; c < 4; ++c) {
            int q = wid * 4 + c;
            int rowA = m0 + q * 8 + rsub; if (rowA > M - 1) rowA = M - 1;
            gload_lds16(A + (size_t)rowA * K + ks * 64 + kslot * 8, &As[ks][q * 512]);
            int rowB = n0 + q * 8 + rsub;
            gload_lds16(Bt + (size_t)rowB * K + ks * 64 + kslot * 8, &Bs[ks][q * 512]);
        }
    }
    __syncthreads();

    f32x4 acc[4][4];
    #pragma unroll
    for (int i = 0; i < 4; ++i)
        #pragma unroll
        for (int j = 0; j < 4; ++j) acc[i][j] = (f32x4){0.f, 0.f, 0.f, 0.f};

    // ---- MFMA sweep over planes (no barriers; planes pipeline freely) ----
    #pragma unroll
    for (int ks = 0; ks < KSEG; ++ks) {
        short8 af[2][4], bf[2][4];
        #pragma unroll
        for (int kk = 0; kk < 2; ++kk) {
            #pragma unroll
            for (int mi = 0; mi < 4; ++mi) {
                int row = wr * 64 + mi * 16 + l15;
                af[kk][mi] = *reinterpret_cast<const short8*>(
                    &As[ks][row * 64 + (((kk * 4 + l4) ^ (row & 7)) << 3)]);
            }
            #pragma unroll
            for (int ni = 0; ni < 4; ++ni) {
                int row = wc * 64 + ni * 16 + l15;
                bf[kk][ni] = *reinterpret_cast<const short8*>(
                    &Bs[ks][row * 64 + (((kk * 4 + l4) ^ (row & 7)) << 3)]);
            }
        }
        #pragma unroll
        for (int kk = 0; kk < 2; ++kk)
            #pragma unroll
            for (int mi = 0; mi < 4; ++mi)
                #pragma unroll
                for (int ni = 0; ni < 4; ++ni)
                    acc[mi][ni] = __builtin_amdgcn_mfma_f32_16x16x32_bf16(
                        af[kk][mi], bf[kk][ni], acc[mi][ni], 0, 0, 0);
    }

    // ---- epilogue ----
    float* Cf = (float*)Cv;
    unsigned short* Cb = (unsigned short*)Cv;
    float csum[4] = {0.f, 0.f, 0.f, 0.f}, csq[4] = {0.f, 0.f, 0.f, 0.f};
    float as4[4], ad4[4];
    int hh = 0;
    if (AL) {
        hh = (n0 >> 6) + wc;   // this wave's head
        #pragma unroll
        for (int ni = 0; ni < 4; ++ni) {
            as4[ni] = a_src[hh * 64 + ni * 16 + l15];
            ad4[ni] = a_dst[hh * 64 + ni * 16 + l15];
        }
    }
    #pragma unroll
    for (int mi = 0; mi < 4; ++mi) {
        int row0 = m0 + wr * 64 + mi * 16 + l4 * 4;
        float sal[4] = {0.f, 0.f, 0.f, 0.f}, dal[4] = {0.f, 0.f, 0.f, 0.f};
        #pragma unroll
        for (int ni = 0; ni < 4; ++ni) {
            int col = n0 + wc * 64 + ni * 16 + l15;
            float badd = 0.f;
            if (bias1) badd += bias1[col];
            if (bias2) badd += bias2[col];
            f32x4 v = acc[mi][ni];
            #pragma unroll
            for (int i = 0; i < 4; ++i) {
                int row = row0 + i;
                if (row < M) {
                    size_t idx = (size_t)row * N + col;
                    float o = v[i] + badd;
                    if (ACCUM) o += Cf[idx];
                    if (STATS) { csum[ni] += o; csq[ni] += o * o; }
                    if (AL) { sal[i] = fmaf(o, as4[ni], sal[i]); dal[i] = fmaf(o, ad4[ni], dal[i]); }
                    if (OUTBF) Cb[idx] = f2bf(o);
                    else Cf[idx] = o;
                }
            }
        }
        if (AL) {
            #pragma unroll
            for (int i = 0; i < 4; ++i) {
                float s = sal[i], t = dal[i];
                s += __shfl_xor(s, 1, 64); t += __shfl_xor(t, 1, 64);
                s += __shfl_xor(s, 2, 64); t += __shfl_xor(t, 2, 64);
                s += __shfl_xor(s, 4, 64); t += __shfl_xor(t, 4, 64);
                s += __shfl_xor(s, 8, 64); t += __shfl_xor(t, 8, 64);
                int row = row0 + i;
                if (l15 == 0) {
                    if (row < M)    als[(size_t)row * 4 + hh] = s;
                    if (row < Ndst) ald[(size_t)row * 4 + hh] = t;
                }
            }
        }
    }
    if (STATS) {
        #pragma unroll
        for (int ni = 0; ni < 4; ++ni) {
            float s = csum[ni], q = csq[ni];
            s += __shfl_xor(s, 16, 64); q += __shfl_xor(q, 16, 64);
            s += __shfl_xor(s, 32, 64); q += __shfl_xor(q, 32, 64);
            if (l4 == 0) {
                int col = n0 + wc * 64 + ni * 16 + l15;
                atomicAdd(&stats[col], s);
                atomicAdd(&stats[256 + col], q);
            }
        }
    }
}

// ---------------- fused edge softmax + aggregate: one wave per dst ----------------
__global__ __launch_bounds__(256) void fused_agg(const unsigned short* __restrict__ xp,
                                                 const float* __restrict__ als,
                                                 const float* __restrict__ ald,
                                                 const int* __restrict__ srcs,
                                                 const int* __restrict__ offs,
                                                 float* __restrict__ out, int Ndst) {
    int d = blockIdx.x * 4 + (threadIdx.x >> 6);
    if (d >= Ndst) return;
    int lane = threadIdx.x & 63;
    int beg = offs[d], end = offs[d + 1];
    float4 ad = *reinterpret_cast<const float4*>(&ald[(size_t)d * 4]);

    // pass 1: per-head max
    float4 lm = make_float4(-1e30f, -1e30f, -1e30f, -1e30f);
    for (int i = beg + lane; i < end; i += 64) {
        int s = srcs[i];
        float4 a = *reinterpret_cast<const float4*>(&als[(size_t)s * 4]);
        float l0 = a.x + ad.x; l0 = l0 > 0.f ? l0 : kNEG * l0;
        float l1 = a.y + ad.y; l1 = l1 > 0.f ? l1 : kNEG * l1;
        float l2 = a.z + ad.z; l2 = l2 > 0.f ? l2 : kNEG * l2;
        float l3 = a.w + ad.w; l3 = l3 > 0.f ? l3 : kNEG * l3;
        lm.x = fmaxf(lm.x, l0); lm.y = fmaxf(lm.y, l1);
        lm.z = fmaxf(lm.z, l2); lm.w = fmaxf(lm.w, l3);
    }
    #pragma unroll
    for (int off = 1; off < 64; off <<= 1) {
        lm.x = fmaxf(lm.x, __shfl_xor(lm.x, off, 64));
        lm.y = fmaxf(lm.y, __shfl_xor(lm.y, off, 64));
        lm.z = fmaxf(lm.z, __shfl_xor(lm.z, off, 64));
        lm.w = fmaxf(lm.w, __shfl_xor(lm.w, off, 64));
    }
    // pass 2: per-head sum of exp
    float4 se = make_float4(0.f, 0.f, 0.f, 0.f);
    for (int i = beg + lane; i < end; i += 64) {
        int s = srcs[i];
        float4 a = *reinterpret_cast<const float4*>(&als[(size_t)s * 4]);
        float l0 = a.x + ad.x; l0 = l0 > 0.f ? l0 : kNEG * l0;
        float l1 = a.y + ad.y; l1 = l1 > 0.f ? l1 : kNEG * l1;
        float l2 = a.z + ad.z; l2 = l2 > 0.f ? l2 : kNEG * l2;
        float l3 = a.w + ad.w; l3 = l3 > 0.f ? l3 : kNEG * l3;
        se.x += expf(l0 - lm.x); se.y += expf(l1 - lm.y);
        se.z += expf(l2 - lm.z); se.w += expf(l3 - lm.w);
    }
    #pragma unroll
    for (int off = 1; off < 64; off <<= 1) {
        se.x += __shfl_xor(se.x, off, 64);
        se.y += __shfl_xor(se.y, off, 64);
        se.z += __shfl_xor(se.z, off, 64);
        se.w += __shfl_xor(se.w, off, 64);
    }
    int h = lane >> 4;
    float mh  = (h == 0) ? lm.x : (h == 1) ? lm.y : (h == 2) ? lm.z : lm.w;
    float sh  = (h == 0) ? se.x : (h == 1) ? se.y : (h == 2) ? se.z : se.w;
    float adh = (h == 0) ? ad.x : (h == 1) ? ad.y : (h == 2) ? ad.z : ad.w;
    float invh = 1.f / (sh + 1e-16f);

    // pass 3: aggregate, 4-way unrolled for memory-level parallelism
    float a0 = 0.f, a1 = 0.f, a2 = 0.f, a3 = 0.f;
    int i = beg;
    for (; i + 4 <= end; i += 4) {
        int s0 = srcs[i + 0], s1 = srcs[i + 1], s2 = srcs[i + 2], s3 = srcs[i + 3];
        float l0 = als[(size_t)s0 * 4 + h] + adh;
        float l1 = als[(size_t)s1 * 4 + h] + adh;
        float l2 = als[(size_t)s2 * 4 + h] + adh;
        float l3 = als[(size_t)s3 * 4 + h] + adh;
        ushort4 x0 = *reinterpret_cast<const ushort4*>(&xp[(size_t)s0 * 256 + lane * 4]);
        ushort4 x1 = *reinterpret_cast<const ushort4*>(&xp[(size_t)s1 * 256 + lane * 4]);
        ushort4 x2 = *reinterpret_cast<const ushort4*>(&xp[(size_t)s2 * 256 + lane * 4]);
        ushort4 x3 = *reinterpret_cast<const ushort4*>(&xp[(size_t)s3 * 256 + lane * 4]);
        l0 = l0 > 0.f ? l0 : kNEG * l0; float w0 = expf(l0 - mh) * invh;
        l1 = l1 > 0.f ? l1 : kNEG * l1; float w1 = expf(l1 - mh) * invh;
        l2 = l2 > 0.f ? l2 : kNEG * l2; float w2 = expf(l2 - mh) * invh;
        l3 = l3 > 0.f ? l3 : kNEG * l3; float w3 = expf(l3 - mh) * invh;
        a0 = fmaf(w0, b2f(x0.x), a0); a1 = fmaf(w0, b2f(x0.y), a1);
        a2 = fmaf(w0, b2f(x0.z), a2); a3 = fmaf(w0, b2f(x0.w), a3);
        a0 = fmaf(w1, b2f(x1.x), a0); a1 = fmaf(w1, b2f(x1.y), a1);
        a2 = fmaf(w1, b2f(x1.z), a2); a3 = fmaf(w1, b2f(x1.w), a3);
        a0 = fmaf(w2, b2f(x2.x), a0); a1 = fmaf(w2, b2f(x2.y), a1);
        a2 = fmaf(w2, b2f(x2.z), a2); a3 = fmaf(w2, b2f(x2.w), a3);
        a0 = fmaf(w3, b2f(x3.x), a0); a1 = fmaf(w3, b2f(x3.y), a1);
        a2 = fmaf(w3, b2f(x3.z), a2); a3 = fmaf(w3, b2f(x3.w), a3);
    }
    for (; i < end; ++i) {
        int s = srcs[i];
        float l = als[(size_t)s * 4 + h] + adh;
        l = l > 0.f ? l : kNEG * l;
        float w = expf(l - mh) * invh;
        ushort4 xv = *reinterpret_cast<const ushort4*>(&xp[(size_t)s * 256 + lane * 4]);
        a0 = fmaf(w, b2f(xv.x), a0);
        a1 = fmaf(w, b2f(xv.y), a1);
        a2 = fmaf(w, b2f(xv.z), a2);
        a3 = fmaf(w, b2f(xv.w), a3);
    }
    *reinterpret_cast<float4*>(&out[(size_t)d * 256 + lane * 4]) =
        make_float4(a0, a1, a2, a3);
}

// ---------------- BN apply (stats precomputed in GEMM epilogue) ----------------
template <int ACT, bool OUTBF>
__global__ __launch_bounds__(256) void bn_apply(const float* __restrict__ X,
                                                const float* __restrict__ stats,
                                                const float* __restrict__ gamma,
                                                const float* __restrict__ beta,
                                                void* __restrict__ out, int M) {
    int c = threadIdx.x;
    float mu = stats[c] / (float)M;
    float var = stats[256 + c] / (float)M - mu * mu;
    float sc = rsqrtf(var + kEPS) * gamma[c];
    float sh = beta[c];
    for (int row = blockIdx.x; row < M; row += gridDim.x) {
        size_t idx = (size_t)row * 256 + c;
        float v = (X[idx] - mu) * sc + sh;
        if (ACT == 0) v = v > 0.f ? v : expm1f(v);
        else v = fmaxf(v, 0.f);
        if (OUTBF) ((unsigned short*)out)[idx] = f2bf(v);
        else ((float*)out)[idx] = v;
    }
}

// ---------------- fp32 tiled GEMM (final N=47 head) ----------------
template <bool ACCUM>
__global__ __launch_bounds__(256) void gemm64(const float* __restrict__ A,
                                              const float* __restrict__ B,
                                              float* __restrict__ Cmat,
                                              const float* __restrict__ bias1,
                                              const float* __restrict__ bias2,
                                              int M, int N, int K) {
    __shared__ float As[32][68];
    __shared__ float Bs[32][68];
    const int tid = threadIdx.x;
    const int tx = tid & 15, ty = tid >> 4;
    const int m0 = blockIdx.y * 64, n0 = blockIdx.x * 64;
    float acc[4][4] = {};

    for (int k0 = 0; k0 < K; k0 += 32) {
        #pragma unroll
        for (int t = 0; t < 2; ++t) {
            int i = tid + t * 256;
            int row = i >> 3;
            int kq = (i & 7) << 2;
            float4 v = make_float4(0.f, 0.f, 0.f, 0.f);
            int gr = m0 + row;
            if (gr < M) v = *reinterpret_cast<const float4*>(&A[(size_t)gr * K + k0 + kq]);
            As[kq + 0][row] = v.x; As[kq + 1][row] = v.y;
            As[kq + 2][row] = v.z; As[kq + 3][row] = v.w;
        }
        #pragma unroll
        for (int t = 0; t < 2; ++t) {
            int i = tid + t * 256;
            int kr = i >> 4;
            int cq = (i & 15) << 2;
            #pragma unroll
            for (int j = 0; j < 4; ++j) {
                int gc = n0 + cq + j;
                Bs[kr][cq + j] = (gc < N) ? B[(size_t)(k0 + kr) * N + gc] : 0.f;
            }
        }
        __syncthreads();
        #pragma unroll
        for (int kk = 0; kk < 32; ++kk) {
            float4 a4 = *reinterpret_cast<const float4*>(&As[kk][ty << 2]);
            float4 b4 = *reinterpret_cast<const float4*>(&Bs[kk][tx << 2]);
            float a[4] = {a4.x, a4.y, a4.z, a4.w};
            float b[4] = {b4.x, b4.y, b4.z, b4.w};
            #pragma unroll
            for (int i2 = 0; i2 < 4; ++i2)
                #pragma unroll
                for (int j = 0; j < 4; ++j)
                    acc[i2][j] = fmaf(a[i2], b[j], acc[i2][j]);
        }
        __syncthreads();
    }

    #pragma unroll
    for (int i2 = 0; i2 < 4; ++i2) {
        int row = m0 + (ty << 2) + i2;
        if (row >= M) continue;
        #pragma unroll
        for (int j = 0; j < 4; ++j) {
            int col = n0 + (tx << 2) + j;
            if (col >= N) continue;
            float v = acc[i2][j];
            if (bias1) v += bias1[col];
            if (bias2) v += bias2[col];
            size_t idx = (size_t)row * N + col;
            if (ACCUM) v += Cmat[idx];
            Cmat[idx] = v;
        }
    }
}

extern "C" void kernel_launch(void* const* d_in, const int* in_sizes, int n_in,
                              void* d_out, int out_size, void* d_ws, size_t ws_size,
                              hipStream_t stream) {
    (void)in_sizes; (void)n_in; (void)out_size; (void)ws_size;

    const float* x      = (const float*)d_in[0];
    const int*   src1   = (const int*)d_in[1];
    const int*   dst1   = (const int*)d_in[2];
    const int*   src2   = (const int*)d_in[3];
    const int*   dst2   = (const int*)d_in[4];
    const float* W1     = (const float*)d_in[5];
    const float* a_src1 = (const float*)d_in[6];
    const float* a_dst1 = (const float*)d_in[7];
    const float* b1     = (const float*)d_in[8];
    const float* Wsk1   = (const float*)d_in[9];
    const float* bsk1   = (const float*)d_in[10];
    const float* g1     = (const float*)d_in[11];
    const float* be1    = (const float*)d_in[12];
    const float* W2     = (const float*)d_in[13];
    const float* a_src2 = (const float*)d_in[14];
    const float* a_dst2 = (const float*)d_in[15];
    const float* b2     = (const float*)d_in[16];
    const float* Wsk2   = (const float*)d_in[17];
    const float* bsk2   = (const float*)d_in[18];
    const float* g2     = (const float*)d_in[19];
    const float* be2    = (const float*)d_in[20];
    const float* Wm1    = (const float*)d_in[21];
    const float* bm1    = (const float*)d_in[22];
    const float* gm     = (const float*)d_in[23];
    const float* bem    = (const float*)d_in[24];
    const float* Wm2    = (const float*)d_in[25];
    const float* bm2    = (const float*)d_in[26];

    // ---- workspace layout (float units; all chunks 16B-aligned) ----
    float* ws = (float*)d_ws;
    size_t off = 0;
    auto alloc = [&](size_t n) { float* p = ws + off; off += n; return p; };
    unsigned short* xb  = (unsigned short*)alloc((size_t)kN0 * 128 / 2);
    unsigned short* xp1 = (unsigned short*)alloc((size_t)kN0 * 256 / 2);   // reused as xp2
    float* h1           = alloc((size_t)kN1 * 256);
    unsigned short* h1b = (unsigned short*)alloc((size_t)kN1 * 256 / 2);
    float* h2           = alloc((size_t)kN2 * 256);
    unsigned short* h2b = (unsigned short*)alloc((size_t)kN2 * 256 / 2);
    float* h3           = alloc((size_t)kN2 * 256);
    unsigned short* W1t   = (unsigned short*)alloc(128 * 256 / 2);
    unsigned short* Wsk1t = (unsigned short*)alloc(128 * 256 / 2);
    unsigned short* W2t   = (unsigned short*)alloc(256 * 256 / 2);
    unsigned short* Wsk2t = (unsigned short*)alloc(256 * 256 / 2);
    unsigned short* Wm1t  = (unsigned short*)alloc(256 * 256 / 2);
    float* als1 = alloc((size_t)kN0 * 4);
    float* ald1 = alloc((size_t)kN1 * 4);
    float* als2 = alloc((size_t)kN1 * 4);
    float* ald2 = alloc((size_t)kN2 * 4);
    // contiguous zero-init region: stats + cnt1 + cur1 + cnt2 + cur2
    float* zreg = alloc(1536 + kN1 + kN1 + kN2 + kN2);
    float* stats = zreg;
    float* stats1 = stats, *stats2 = stats + 512, *stats3 = stats + 1024;
    int* cnt1 = (int*)(zreg + 1536);
    int* cur1 = cnt1 + kN1;
    int* cnt2 = cur1 + kN1;
    int* cur2 = cnt2 + kN2;
    const int nzreg = 1536 + 2 * kN1 + 2 * kN2;
    int* srcs1  = (int*)alloc(kE1);
    int* offs1  = (int*)alloc(kN1 + 4);
    int* bsum1  = (int*)alloc(128);
    int* bscan1 = (int*)alloc(128);
    int* srcs2  = (int*)alloc(kE2);
    int* offs2  = (int*)alloc(kN2 + 4);
    int* bsum2  = (int*)alloc(128);
    int* bscan2 = (int*)alloc(128);
    unsigned short* xp2 = xp1;

    hipStream_t st = stream;
    const int nb1 = (kN1 + 1023) / 1024;
    const int nb2 = (kN2 + 1023) / 1024;

    // ---- converts (parallel) ----
    conv_bf16<<<2048, 256, 0, st>>>(x, xb, kN0 * 128);
    transp_w_par<<<(256 * 128 + 255) / 256, 256, 0, st>>>(W1, W1t, 7, 256);
    transp_w_par<<<(256 * 128 + 255) / 256, 256, 0, st>>>(Wsk1, Wsk1t, 7, 256);
    transp_w_par<<<(256 * 256 + 255) / 256, 256, 0, st>>>(W2, W2t, 8, 256);
    transp_w_par<<<(256 * 256 + 255) / 256, 256, 0, st>>>(Wsk2, Wsk2t, 8, 256);
    transp_w_par<<<(256 * 256 + 255) / 256, 256, 0, st>>>(Wm1, Wm1t, 8, 256);

    // ---- init (single contiguous zero) ----
    zero_f32<<<512, 256, 0, st>>>(zreg, nzreg);

    // ---- CSR builds ----
    hist_dst<<<(kE1 + 255) / 256, 256, 0, st>>>(dst1, cnt1, kE1);
    scan_block<<<nb1, 256, 0, st>>>(cnt1, kN1, offs1, bsum1);
    scan_bsums<<<1, 256, 0, st>>>(bsum1, bscan1, nb1);
    scan_add<<<(kN1 + 255) / 256, 256, 0, st>>>(offs1, bscan1, cnt1, kN1);
    csr_scatter<<<(kE1 + 255) / 256, 256, 0, st>>>(dst1, src1, offs1, cur1, srcs1, kE1);

    hist_dst<<<(kE2 + 255) / 256, 256, 0, st>>>(dst2, cnt2, kE2);
    scan_block<<<nb2, 256, 0, st>>>(cnt2, kN2, offs2, bsum2);
    scan_bsums<<<1, 256, 0, st>>>(bsum2, bscan2, nb2);
    scan_add<<<(kN2 + 255) / 256, 256, 0, st>>>(offs2, bscan2, cnt2, kN2);
    csr_scatter<<<(kE2 + 255) / 256, 256, 0, st>>>(dst2, src2, offs2, cur2, srcs2, kE2);

    // ================= layer 1 =================
    mfma_gemm_fk<true, false, false, true, 2><<<dim3(2, (kN0 + 127) / 128), 256, 0, st>>>(
        xb, W1t, xp1, nullptr, nullptr, nullptr, a_src1, a_dst1, als1, ald1, kN0, 256, kN1);
    fused_agg<<<(kN1 + 3) / 4, 256, 0, st>>>(xp1, als1, ald1, srcs1, offs1, h1, kN1);
    mfma_gemm_fk<false, true, true, false, 2><<<dim3(2, (kN1 + 127) / 128), 256, 0, st>>>(
        xb, Wsk1t, h1, b1, bsk1, stats1, nullptr, nullptr, nullptr, nullptr, kN1, 256, 0);
    bn_apply<0, true><<<2048, 256, 0, st>>>(h1, stats1, g1, be1, h1b, kN1);

    // ================= layer 2 =================
    mfma_gemm_fk<true, false, false, true, 4><<<dim3(2, (kN1 + 127) / 128), 256, 0, st>>>(
        h1b, W2t, xp2, nullptr, nullptr, nullptr, a_src2, a_dst2, als2, ald2, kN1, 256, kN2);
    fused_agg<<<(kN2 + 3) / 4, 256, 0, st>>>(xp2, als2, ald2, srcs2, offs2, h2, kN2);
    mfma_gemm_fk<false, true, true, false, 4><<<dim3(2, (kN2 + 127) / 128), 256, 0, st>>>(
        h1b, Wsk2t, h2, b2, bsk2, stats2, nullptr, nullptr, nullptr, nullptr, kN2, 256, 0);
    bn_apply<0, true><<<2048, 256, 0, st>>>(h2, stats2, g2, be2, h2b, kN2);

    // ================= MLP head =================
    mfma_gemm_fk<false, false, true, false, 4><<<dim3(2, (kN2 + 127) / 128), 256, 0, st>>>(
        h2b, Wm1t, h3, bm1, nullptr, stats3, nullptr, nullptr, nullptr, nullptr, kN2, 256, 0);
    bn_apply<1, false><<<2048, 256, 0, st>>>(h3, stats3, gm, bem, h3, kN2);
    gemm64<false><<<dim3(1, (kN2 + 63) / 64), 256, 0, st>>>(
        h3, Wm2, (float*)d_out, bm2, nullptr, kN2, kOUT, 256);
}

// Round 7
// 844.602 us; speedup vs baseline: 1.0770x; 1.0770x over previous
//
#include <hip/hip_runtime.h>
#include <math.h>

// Problem constants (fixed by the reference)
constexpr int kN0 = 400000, kN1 = 100000, kN2 = 20000;
constexpr int kE1 = 1000000, kE2 = 200000;
constexpr int kIN = 128, kHID = 256, kOUT = 47;
constexpr float kEPS = 1e-5f, kNEG = 0.2f;

#define DEV static __device__ __forceinline__

typedef __attribute__((ext_vector_type(8))) short short8;
typedef __attribute__((ext_vector_type(4))) float f32x4;

DEV float b2f(unsigned short u) { return __uint_as_float(((unsigned)u) << 16); }
DEV unsigned short f2bf(float f) {
    unsigned u = __float_as_uint(f);
    unsigned r = (u + 0x7fffu + ((u >> 16) & 1u)) >> 16;   // RNE
    return (unsigned short)r;
}
DEV float lrelu(float v) { return v > 0.f ? v : kNEG * v; }

DEV void gload_lds16(const void* g, void* l) {
    __builtin_amdgcn_global_load_lds(
        (const __attribute__((address_space(1))) void*)g,
        (__attribute__((address_space(3))) void*)l, 16, 0, 0);
}

// ---------------- utility ----------------
__global__ void zero_f32(float* __restrict__ p, int n) {
    int i = blockIdx.x * blockDim.x + threadIdx.x;
    int st = gridDim.x * blockDim.x;
    for (; i < n; i += st) p[i] = 0.f;
}

// ---- tiny weight precomputes ----
// v[kin][j] = sum_c W[kin][h*64+c] * a[h][c];  j=0..3: a_src heads, j=4..7: a_dst heads
__global__ void build_v(const float* __restrict__ W, const float* __restrict__ as_,
                        const float* __restrict__ ad_, float* __restrict__ v, int K) {
    int i = blockIdx.x * blockDim.x + threadIdx.x;
    if (i >= K * 8) return;
    int kin = i >> 3, j = i & 7;
    int h = j & 3;
    const float* a = (j >= 4) ? ad_ : as_;
    float s = 0.f;
    for (int c = 0; c < 64; ++c) s += W[(size_t)kin * 256 + h * 64 + c] * a[h * 64 + c];
    v[i] = s;
}

// Wcat1t[256][640] bf16: k<512 -> blockdiag W1 (head h=k>>7, kin=k&127); k>=512 -> Wsk1[k-512]
__global__ void build_wcat1(const float* __restrict__ W1, const float* __restrict__ Wsk1,
                            unsigned short* __restrict__ Bt) {
    int i = blockIdx.x * blockDim.x + threadIdx.x;
    if (i >= 256 * 640) return;
    int n = i / 640, k = i % 640;
    float v;
    if (k < 512) { int h = k >> 7, kin = k & 127; v = ((n >> 6) == h) ? W1[(size_t)kin * 256 + n] : 0.f; }
    else v = Wsk1[(size_t)(k - 512) * 256 + n];
    Bt[i] = f2bf(v);
}

// Wcat2t[256][1280] bf16: k<1024 -> blockdiag W2 (head h=k>>8, kin=k&255); k>=1024 -> Wsk2
__global__ void build_wcat2(const float* __restrict__ W2, const float* __restrict__ Wsk2,
                            unsigned short* __restrict__ Bt) {
    int i = blockIdx.x * blockDim.x + threadIdx.x;
    if (i >= 256 * 1280) return;
    int n = i / 1280, k = i % 1280;
    float v;
    if (k < 1024) { int h = k >> 8, kin = k & 255; v = ((n >> 6) == h) ? W2[(size_t)kin * 256 + n] : 0.f; }
    else v = Wsk2[(size_t)(k - 1024) * 256 + n];
    Bt[i] = f2bf(v);
}

// W[K][N] f32 -> Wt[N][K] bf16 (for Wm1)
__global__ void transp_w_par(const float* __restrict__ W, unsigned short* __restrict__ Wt,
                             int kshift, int N) {
    int i = blockIdx.x * blockDim.x + threadIdx.x;
    int K = 1 << kshift;
    if (i >= N * K) return;
    int n = i >> kshift, k = i & (K - 1);
    Wt[i] = f2bf(W[(size_t)k * N + n]);
}

// ---- fused x->bf16 convert + layer-1 attention dots (wave per node) ----
__global__ __launch_bounds__(256) void conv_als1(const float* __restrict__ x,
                                                 const float* __restrict__ v1,
                                                 unsigned short* __restrict__ xb,
                                                 float* __restrict__ als,
                                                 float* __restrict__ ald) {
    int wid = threadIdx.x >> 6, lane = threadIdx.x & 63;
    int nw = gridDim.x * 4;
    float vt0[8], vt1[8];
    const float* vp = v1 + lane * 16;   // ch 2*lane
    #pragma unroll
    for (int j = 0; j < 8; ++j) { vt0[j] = vp[j]; vt1[j] = vp[8 + j]; }
    for (int n = blockIdx.x * 4 + wid; n < kN0; n += nw) {
        float2 xv = *reinterpret_cast<const float2*>(&x[(size_t)n * 128 + lane * 2]);
        ushort2 o; o.x = f2bf(xv.x); o.y = f2bf(xv.y);
        *reinterpret_cast<ushort2*>(&xb[(size_t)n * 128 + lane * 2]) = o;
        float p[8];
        #pragma unroll
        for (int j = 0; j < 8; ++j) p[j] = xv.x * vt0[j] + xv.y * vt1[j];
        #pragma unroll
        for (int off = 1; off < 64; off <<= 1)
            #pragma unroll
            for (int j = 0; j < 8; ++j) p[j] += __shfl_xor(p[j], off, 64);
        if (lane == 0) {
            *reinterpret_cast<float4*>(&als[(size_t)n * 4]) = make_float4(p[0], p[1], p[2], p[3]);
            if (n < kN1)
                *reinterpret_cast<float4*>(&ald[(size_t)n * 4]) = make_float4(p[4], p[5], p[6], p[7]);
        }
    }
}

// ================= CSR build =================
__global__ void hist_dst(const int* __restrict__ dst, int* __restrict__ counts, int E) {
    int e = blockIdx.x * blockDim.x + threadIdx.x;
    if (e < E) atomicAdd(&counts[dst[e]], 1);
}

__global__ __launch_bounds__(256) void scan_block(const int* __restrict__ counts, int n,
                                                  int* __restrict__ offs, int* __restrict__ bsum) {
    __shared__ int sh[256];
    int tid = threadIdx.x;
    int base = blockIdx.x * 1024 + tid * 4;
    int c0 = (base + 0 < n) ? counts[base + 0] : 0;
    int c1 = (base + 1 < n) ? counts[base + 1] : 0;
    int c2 = (base + 2 < n) ? counts[base + 2] : 0;
    int c3 = (base + 3 < n) ? counts[base + 3] : 0;
    int tot = c0 + c1 + c2 + c3;
    sh[tid] = tot;
    __syncthreads();
    for (int o = 1; o < 256; o <<= 1) {
        int t = (tid >= o) ? sh[tid - o] : 0;
        __syncthreads();
        sh[tid] += t;
        __syncthreads();
    }
    int excl = sh[tid] - tot;
    if (base + 0 < n) offs[base + 0] = excl;
    if (base + 1 < n) offs[base + 1] = excl + c0;
    if (base + 2 < n) offs[base + 2] = excl + c0 + c1;
    if (base + 3 < n) offs[base + 3] = excl + c0 + c1 + c2;
    if (tid == 255) bsum[blockIdx.x] = sh[255];
}

__global__ __launch_bounds__(256) void scan_bsums(const int* __restrict__ bsum,
                                                  int* __restrict__ bscan, int nb) {
    __shared__ int sh[256];
    int tid = threadIdx.x;
    int v = (tid < nb) ? bsum[tid] : 0;
    sh[tid] = v;
    __syncthreads();
    for (int o = 1; o < 256; o <<= 1) {
        int t = (tid >= o) ? sh[tid - o] : 0;
        __syncthreads();
        sh[tid] += t;
        __syncthreads();
    }
    if (tid < nb) bscan[tid] = sh[tid] - v;
}

__global__ void scan_add(int* __restrict__ offs, const int* __restrict__ bscan,
                         const int* __restrict__ counts, int n) {
    int i = blockIdx.x * blockDim.x + threadIdx.x;
    if (i < n) {
        int v = offs[i] + bscan[i >> 10];
        offs[i] = v;
        if (i == n - 1) offs[n] = v + counts[i];
    }
}

__global__ void csr_scatter(const int* __restrict__ dst, const int* __restrict__ src,
                            const int* __restrict__ offs,
                            int* __restrict__ cur, int* __restrict__ srcs, int E) {
    int e = blockIdx.x * blockDim.x + threadIdx.x;
    if (e >= E) return;
    int d = dst[e];
    int pos = offs[d] + atomicAdd(&cur[d], 1);
    srcs[pos] = src[e];
}

// ================= pipelined bf16 MFMA GEMM (2-phase double-buffer) =================
// C[M][N] = A[M][K]bf16 @ Bt[N][K]^T + bias1 + bias2. BM=BN=128, BK=64, 4 waves.
// LDS-staged epilogue for coalesced stores. N multiple of 128; Bt has exactly N rows.
template <bool OUTBF, bool STATS>
__global__ __launch_bounds__(256) void gemm_pipe(const unsigned short* __restrict__ A,
                                                 const unsigned short* __restrict__ Bt,
                                                 void* __restrict__ Cv,
                                                 const float* __restrict__ bias1,
                                                 const float* __restrict__ bias2,
                                                 float* __restrict__ stats,
                                                 int M, int N, int K) {
    __shared__ unsigned short SH[4][128 * 64];   // SH[0..1]=A dbuf, SH[2..3]=B dbuf (64 KB)
    const int tid = threadIdx.x;
    const int wid = tid >> 6, lane = tid & 63;
    const int wr = wid >> 1, wc = wid & 1;
    const int l15 = lane & 15, l4 = lane >> 4;
    const int m0 = blockIdx.y * 128, n0 = blockIdx.x * 128;
    const int rsub = lane >> 3;
    const int kslot = (lane & 7) ^ rsub;   // pre-swizzled source k-slot (16B units)

    auto stage = [&](int buf, int k0) {
        #pragma unroll
        for (int c = 0; c < 4; ++c) {
            int q = wid * 4 + c;
            int rowA = m0 + q * 8 + rsub; if (rowA > M - 1) rowA = M - 1;
            gload_lds16(A + (size_t)rowA * K + k0 + kslot * 8, &SH[buf][q * 512]);
            int rowB = n0 + q * 8 + rsub;
            gload_lds16(Bt + (size_t)rowB * K + k0 + kslot * 8, &SH[2 + buf][q * 512]);
        }
    };

    f32x4 acc[4][4];
    #pragma unroll
    for (int i = 0; i < 4; ++i)
        #pragma unroll
        for (int j = 0; j < 4; ++j) acc[i][j] = (f32x4){0.f, 0.f, 0.f, 0.f};

    stage(0, 0);
    __syncthreads();
    const int nt = K >> 6;
    for (int t = 0; t < nt; ++t) {
        if (t + 1 < nt) stage((t + 1) & 1, (t + 1) << 6);
        int b = t & 1;
        short8 af[2][4], bf[2][4];
        #pragma unroll
        for (int kk = 0; kk < 2; ++kk) {
            #pragma unroll
            for (int mi = 0; mi < 4; ++mi) {
                int row = wr * 64 + mi * 16 + l15;
                af[kk][mi] = *reinterpret_cast<const short8*>(
                    &SH[b][row * 64 + (((kk * 4 + l4) ^ (row & 7)) << 3)]);
            }
            #pragma unroll
            for (int ni = 0; ni < 4; ++ni) {
                int row = wc * 64 + ni * 16 + l15;
                bf[kk][ni] = *reinterpret_cast<const short8*>(
                    &SH[2 + b][row * 64 + (((kk * 4 + l4) ^ (row & 7)) << 3)]);
            }
        }
        #pragma unroll
        for (int kk = 0; kk < 2; ++kk)
            #pragma unroll
            for (int mi = 0; mi < 4; ++mi)
                #pragma unroll
                for (int ni = 0; ni < 4; ++ni)
                    acc[mi][ni] = __builtin_amdgcn_mfma_f32_16x16x32_bf16(
                        af[kk][mi], bf[kk][ni], acc[mi][ni], 0, 0, 0);
        __syncthreads();
    }

    // ---- epilogue: bias, stats, LDS-staged coalesced store ----
    float csum[4] = {0.f, 0.f, 0.f, 0.f}, csq[4] = {0.f, 0.f, 0.f, 0.f};
    unsigned short* LB = (unsigned short*)SH;
    float* LF = (float*)SH;
    #pragma unroll
    for (int mi = 0; mi < 4; ++mi) {
        int lrow0 = wr * 64 + mi * 16 + l4 * 4;
        #pragma unroll
        for (int ni = 0; ni < 4; ++ni) {
            int lcol = wc * 64 + ni * 16 + l15;
            int col = n0 + lcol;
            float badd = 0.f;
            if (bias1) badd += bias1[col];
            if (bias2) badd += bias2[col];
            f32x4 v = acc[mi][ni];
            #pragma unroll
            for (int i = 0; i < 4; ++i) {
                float o = v[i] + badd;
                if (STATS && (m0 + lrow0 + i) < M) { csum[ni] += o; csq[ni] += o * o; }
                if (OUTBF) LB[(lrow0 + i) * 128 + lcol] = f2bf(o);
                else LF[(lrow0 + i) * 128 + lcol] = o;
            }
        }
    }
    if (STATS) {
        #pragma unroll
        for (int ni = 0; ni < 4; ++ni) {
            float s = csum[ni], q = csq[ni];
            s += __shfl_xor(s, 16, 64); q += __shfl_xor(q, 16, 64);
            s += __shfl_xor(s, 32, 64); q += __shfl_xor(q, 32, 64);
            if (l4 == 0) {
                int col = n0 + wc * 64 + ni * 16 + l15;
                atomicAdd(&stats[col], s);
                atomicAdd(&stats[256 + col], q);
            }
        }
    }
    __syncthreads();
    if (OUTBF) {
        unsigned short* Cb = (unsigned short*)Cv;
        #pragma unroll
        for (int it = 0; it < 8; ++it) {
            int lin = (it * 256 + tid) * 8;      // ushort index in 128x128 tile
            int r = lin >> 7, c0 = lin & 127;
            int gr = m0 + r;
            if (gr < M)
                *reinterpret_cast<short8*>(&Cb[(size_t)gr * N + n0 + c0]) =
                    *reinterpret_cast<const short8*>(&LB[lin]);
        }
    } else {
        float* Cf = (float*)Cv;
        #pragma unroll
        for (int it = 0; it < 16; ++it) {
            int lin = (it * 256 + tid) * 4;      // f32 index in 128x128 tile
            int r = lin >> 7, c0 = lin & 127;
            int gr = m0 + r;
            if (gr < M)
                *reinterpret_cast<float4*>(&Cf[(size_t)gr * N + n0 + c0]) =
                    *reinterpret_cast<const float4*>(&LF[lin]);
        }
    }
}

// ---------------- layer-1 fused softmax+aggregate in INPUT space (wave per dst) ----------------
// agg_h[d] = sum_e exp(lrelu(als[s]+ald[d]))*x[s] / sum_e exp(...)  (128 ch, lane=2ch)
// writes Acat[d][640]: cols 0..511 = agg (head-major), cols 512..639 = x[d] (skip operand)
__global__ __launch_bounds__(256) void fused_agg1(const unsigned short* __restrict__ xb,
                                                  const float* __restrict__ als,
                                                  const float* __restrict__ ald,
                                                  const int* __restrict__ srcs,
                                                  const int* __restrict__ offs,
                                                  unsigned short* __restrict__ Acat, int Ndst) {
    int d = blockIdx.x * 4 + (threadIdx.x >> 6);
    if (d >= Ndst) return;
    int lane = threadIdx.x & 63;
    int beg = offs[d], end = offs[d + 1];
    float4 ad = *reinterpret_cast<const float4*>(&ald[(size_t)d * 4]);
    float ac[4][2] = {};
    float se0 = 0.f, se1 = 0.f, se2 = 0.f, se3 = 0.f;

    auto edge = [&](int s) {
        float4 a = *reinterpret_cast<const float4*>(&als[(size_t)s * 4]);
        unsigned xv = *reinterpret_cast<const unsigned*>(&xb[(size_t)s * 128 + lane * 2]);
        float e0 = expf(lrelu(a.x + ad.x));
        float e1 = expf(lrelu(a.y + ad.y));
        float e2 = expf(lrelu(a.z + ad.z));
        float e3 = expf(lrelu(a.w + ad.w));
        se0 += e0; se1 += e1; se2 += e2; se3 += e3;
        float fx = b2f((unsigned short)(xv & 0xffff));
        float fy = b2f((unsigned short)(xv >> 16));
        ac[0][0] = fmaf(e0, fx, ac[0][0]); ac[0][1] = fmaf(e0, fy, ac[0][1]);
        ac[1][0] = fmaf(e1, fx, ac[1][0]); ac[1][1] = fmaf(e1, fy, ac[1][1]);
        ac[2][0] = fmaf(e2, fx, ac[2][0]); ac[2][1] = fmaf(e2, fy, ac[2][1]);
        ac[3][0] = fmaf(e3, fx, ac[3][0]); ac[3][1] = fmaf(e3, fy, ac[3][1]);
    };
    int i = beg;
    for (; i + 4 <= end; i += 4) {
        int s0 = srcs[i], s1 = srcs[i + 1], s2 = srcs[i + 2], s3 = srcs[i + 3];
        edge(s0); edge(s1); edge(s2); edge(s3);
    }
    for (; i < end; ++i) edge(srcs[i]);

    float inv0 = 1.f / (se0 + 1e-16f), inv1 = 1.f / (se1 + 1e-16f);
    float inv2 = 1.f / (se2 + 1e-16f), inv3 = 1.f / (se3 + 1e-16f);
    unsigned short* row = Acat + (size_t)d * 640;
    ushort2 o;
    o.x = f2bf(ac[0][0] * inv0); o.y = f2bf(ac[0][1] * inv0);
    *reinterpret_cast<ushort2*>(&row[0 * 128 + lane * 2]) = o;
    o.x = f2bf(ac[1][0] * inv1); o.y = f2bf(ac[1][1] * inv1);
    *reinterpret_cast<ushort2*>(&row[1 * 128 + lane * 2]) = o;
    o.x = f2bf(ac[2][0] * inv2); o.y = f2bf(ac[2][1] * inv2);
    *reinterpret_cast<ushort2*>(&row[2 * 128 + lane * 2]) = o;
    o.x = f2bf(ac[3][0] * inv3); o.y = f2bf(ac[3][1] * inv3);
    *reinterpret_cast<ushort2*>(&row[3 * 128 + lane * 2]) = o;
    // skip operand copy: x[d]
    *reinterpret_cast<ushort2*>(&row[512 + lane * 2]) =
        *reinterpret_cast<const ushort2*>(&xb[(size_t)d * 128 + lane * 2]);
}

// ---------------- layer-2 fused softmax+aggregate (256 ch, lane=4ch) ----------------
// writes Acat2[d][1280]: cols 0..1023 = agg (head-major 256/head), 1024..1279 = h1b[d]
__global__ __launch_bounds__(256) void fused_agg2(const unsigned short* __restrict__ hb,
                                                  const float* __restrict__ als,
                                                  const float* __restrict__ ald,
                                                  const int* __restrict__ srcs,
                                                  const int* __restrict__ offs,
                                                  unsigned short* __restrict__ Acat, int Ndst) {
    int d = blockIdx.x * 4 + (threadIdx.x >> 6);
    if (d >= Ndst) return;
    int lane = threadIdx.x & 63;
    int beg = offs[d], end = offs[d + 1];
    float4 ad = *reinterpret_cast<const float4*>(&ald[(size_t)d * 4]);
    float ac[4][4] = {};
    float se0 = 0.f, se1 = 0.f, se2 = 0.f, se3 = 0.f;

    auto edge = [&](int s) {
        float4 a = *reinterpret_cast<const float4*>(&als[(size_t)s * 4]);
        ushort4 xv = *reinterpret_cast<const ushort4*>(&hb[(size_t)s * 256 + lane * 4]);
        float e0 = expf(lrelu(a.x + ad.x));
        float e1 = expf(lrelu(a.y + ad.y));
        float e2 = expf(lrelu(a.z + ad.z));
        float e3 = expf(lrelu(a.w + ad.w));
        se0 += e0; se1 += e1; se2 += e2; se3 += e3;
        float f0 = b2f(xv.x), f1 = b2f(xv.y), f2 = b2f(xv.z), f3 = b2f(xv.w);
        ac[0][0] = fmaf(e0, f0, ac[0][0]); ac[0][1] = fmaf(e0, f1, ac[0][1]);
        ac[0][2] = fmaf(e0, f2, ac[0][2]); ac[0][3] = fmaf(e0, f3, ac[0][3]);
        ac[1][0] = fmaf(e1, f0, ac[1][0]); ac[1][1] = fmaf(e1, f1, ac[1][1]);
        ac[1][2] = fmaf(e1, f2, ac[1][2]); ac[1][3] = fmaf(e1, f3, ac[1][3]);
        ac[2][0] = fmaf(e2, f0, ac[2][0]); ac[2][1] = fmaf(e2, f1, ac[2][1]);
        ac[2][2] = fmaf(e2, f2, ac[2][2]); ac[2][3] = fmaf(e2, f3, ac[2][3]);
        ac[3][0] = fmaf(e3, f0, ac[3][0]); ac[3][1] = fmaf(e3, f1, ac[3][1]);
        ac[3][2] = fmaf(e3, f2, ac[3][2]); ac[3][3] = fmaf(e3, f3, ac[3][3]);
    };
    int i = beg;
    for (; i + 2 <= end; i += 2) { edge(srcs[i]); edge(srcs[i + 1]); }
    for (; i < end; ++i) edge(srcs[i]);

    float inv[4] = {1.f / (se0 + 1e-16f), 1.f / (se1 + 1e-16f),
                    1.f / (se2 + 1e-16f), 1.f / (se3 + 1e-16f)};
    unsigned short* row = Acat + (size_t)d * 1280;
    #pragma unroll
    for (int h = 0; h < 4; ++h) {
        ushort4 o;
        o.x = f2bf(ac[h][0] * inv[h]); o.y = f2bf(ac[h][1] * inv[h]);
        o.z = f2bf(ac[h][2] * inv[h]); o.w = f2bf(ac[h][3] * inv[h]);
        *reinterpret_cast<ushort4*>(&row[h * 256 + lane * 4]) = o;
    }
    *reinterpret_cast<ushort4*>(&row[1024 + lane * 4]) =
        *reinterpret_cast<const ushort4*>(&hb[(size_t)d * 256 + lane * 4]);
}

// ---------------- BN apply per row (wave/row), optional fused layer-2 logit dots ----------------
// ACT: 0=ELU, 1=ReLU. OUTBF: bf16 out. AL: als/ald dots vs v2[256][8].
template <int ACT, bool OUTBF, bool AL>
__global__ __launch_bounds__(256) void bn_rows(const float* __restrict__ X,
                                               const float* __restrict__ stats,
                                               const float* __restrict__ gamma,
                                               const float* __restrict__ beta,
                                               void* __restrict__ out,
                                               const float* __restrict__ v2,
                                               float* __restrict__ als,
                                               float* __restrict__ ald,
                                               int M, int Ndst) {
    int wid = threadIdx.x >> 6, lane = threadIdx.x & 63;
    int nw = gridDim.x * 4;
    float4 s4 = *reinterpret_cast<const float4*>(&stats[lane * 4]);
    float4 q4 = *reinterpret_cast<const float4*>(&stats[256 + lane * 4]);
    float4 g4 = *reinterpret_cast<const float4*>(&gamma[lane * 4]);
    float4 b4 = *reinterpret_cast<const float4*>(&beta[lane * 4]);
    float invM = 1.f / (float)M;
    float mu[4] = {s4.x * invM, s4.y * invM, s4.z * invM, s4.w * invM};
    float sc[4], sh_[4] = {b4.x, b4.y, b4.z, b4.w};
    {
        float g[4] = {g4.x, g4.y, g4.z, g4.w};
        float q[4] = {q4.x, q4.y, q4.z, q4.w};
        #pragma unroll
        for (int c = 0; c < 4; ++c) {
            float var = q[c] * invM - mu[c] * mu[c];
            sc[c] = rsqrtf(var + kEPS) * g[c];
        }
    }
    float vt[4][8];
    if (AL) {
        const float* vp = v2 + lane * 32;
        #pragma unroll
        for (int c = 0; c < 4; ++c)
            #pragma unroll
            for (int j = 0; j < 8; ++j) vt[c][j] = vp[c * 8 + j];
    }
    for (int row = blockIdx.x * 4 + wid; row < M; row += nw) {
        float4 xv = *reinterpret_cast<const float4*>(&X[(size_t)row * 256 + lane * 4]);
        float v[4] = {xv.x, xv.y, xv.z, xv.w};
        #pragma unroll
        for (int c = 0; c < 4; ++c) {
            float t = (v[c] - mu[c]) * sc[c] + sh_[c];
            if (ACT == 0) t = t > 0.f ? t : expm1f(t);
            else t = fmaxf(t, 0.f);
            v[c] = t;
        }
        if (OUTBF) {
            ushort4 o; o.x = f2bf(v[0]); o.y = f2bf(v[1]); o.z = f2bf(v[2]); o.w = f2bf(v[3]);
            *reinterpret_cast<ushort4*>(&((unsigned short*)out)[(size_t)row * 256 + lane * 4]) = o;
        } else {
            *reinterpret_cast<float4*>(&((float*)out)[(size_t)row * 256 + lane * 4]) =
                make_float4(v[0], v[1], v[2], v[3]);
        }
        if (AL) {
            float p[8];
            #pragma unroll
            for (int j = 0; j < 8; ++j)
                p[j] = v[0] * vt[0][j] + v[1] * vt[1][j] + v[2] * vt[2][j] + v[3] * vt[3][j];
            #pragma unroll
            for (int off = 1; off < 64; off <<= 1)
                #pragma unroll
                for (int j = 0; j < 8; ++j) p[j] += __shfl_xor(p[j], off, 64);
            if (lane == 0) {
                *reinterpret_cast<float4*>(&als[(size_t)row * 4]) =
                    make_float4(p[0], p[1], p[2], p[3]);
                if (row < Ndst)
                    *reinterpret_cast<float4*>(&ald[(size_t)row * 4]) =
                        make_float4(p[4], p[5], p[6], p[7]);
            }
        }
    }
}

// ---------------- fp32 tiled GEMM (final N=47 head) ----------------
template <bool ACCUM>
__global__ __launch_bounds__(256) void gemm64(const float* __restrict__ A,
                                              const float* __restrict__ B,
                                              float* __restrict__ Cmat,
                                              const float* __restrict__ bias1,
                                              const float* __restrict__ bias2,
                                              int M, int N, int K) {
    __shared__ float As[32][68];
    __shared__ float Bs[32][68];
    const int tid = threadIdx.x;
    const int tx = tid & 15, ty = tid >> 4;
    const int m0 = blockIdx.y * 64, n0 = blockIdx.x * 64;
    float acc[4][4] = {};

    for (int k0 = 0; k0 < K; k0 += 32) {
        #pragma unroll
        for (int t = 0; t < 2; ++t) {
            int i = tid + t * 256;
            int row = i >> 3;
            int kq = (i & 7) << 2;
            float4 v = make_float4(0.f, 0.f, 0.f, 0.f);
            int gr = m0 + row;
            if (gr < M) v = *reinterpret_cast<const float4*>(&A[(size_t)gr * K + k0 + kq]);
            As[kq + 0][row] = v.x; As[kq + 1][row] = v.y;
            As[kq + 2][row] = v.z; As[kq + 3][row] = v.w;
        }
        #pragma unroll
        for (int t = 0; t < 2; ++t) {
            int i = tid + t * 256;
            int kr = i >> 4;
            int cq = (i & 15) << 2;
            #pragma unroll
            for (int j = 0; j < 4; ++j) {
                int gc = n0 + cq + j;
                Bs[kr][cq + j] = (gc < N) ? B[(size_t)(k0 + kr) * N + gc] : 0.f;
            }
        }
        __syncthreads();
        #pragma unroll
        for (int kk = 0; kk < 32; ++kk) {
            float4 a4 = *reinterpret_cast<const float4*>(&As[kk][ty << 2]);
            float4 b4 = *reinterpret_cast<const float4*>(&Bs[kk][tx << 2]);
            float a[4] = {a4.x, a4.y, a4.z, a4.w};
            float b[4] = {b4.x, b4.y, b4.z, b4.w};
            #pragma unroll
            for (int i2 = 0; i2 < 4; ++i2)
                #pragma unroll
                for (int j = 0; j < 4; ++j)
                    acc[i2][j] = fmaf(a[i2], b[j], acc[i2][j]);
        }
        __syncthreads();
    }

    #pragma unroll
    for (int i2 = 0; i2 < 4; ++i2) {
        int row = m0 + (ty << 2) + i2;
        if (row >= M) continue;
        #pragma unroll
        for (int j = 0; j < 4; ++j) {
            int col = n0 + (tx << 2) + j;
            if (col >= N) continue;
            float v = acc[i2][j];
            if (bias1) v += bias1[col];
            if (bias2) v += bias2[col];
            size_t idx = (size_t)row * N + col;
            if (ACCUM) v += Cmat[idx];
            Cmat[idx] = v;
        }
    }
}

extern "C" void kernel_launch(void* const* d_in, const int* in_sizes, int n_in,
                              void* d_out, int out_size, void* d_ws, size_t ws_size,
                              hipStream_t stream) {
    (void)in_sizes; (void)n_in; (void)out_size; (void)ws_size;

    const float* x      = (const float*)d_in[0];
    const int*   src1   = (const int*)d_in[1];
    const int*   dst1   = (const int*)d_in[2];
    const int*   src2   = (const int*)d_in[3];
    const int*   dst2   = (const int*)d_in[4];
    const float* W1     = (const float*)d_in[5];
    const float* a_src1 = (const float*)d_in[6];
    const float* a_dst1 = (const float*)d_in[7];
    const float* b1     = (const float*)d_in[8];
    const float* Wsk1   = (const float*)d_in[9];
    const float* bsk1   = (const float*)d_in[10];
    const float* g1     = (const float*)d_in[11];
    const float* be1    = (const float*)d_in[12];
    const float* W2     = (const float*)d_in[13];
    const float* a_src2 = (const float*)d_in[14];
    const float* a_dst2 = (const float*)d_in[15];
    const float* b2     = (const float*)d_in[16];
    const float* Wsk2   = (const float*)d_in[17];
    const float* bsk2   = (const float*)d_in[18];
    const float* g2     = (const float*)d_in[19];
    const float* be2    = (const float*)d_in[20];
    const float* Wm1    = (const float*)d_in[21];
    const float* bm1    = (const float*)d_in[22];
    const float* gm     = (const float*)d_in[23];
    const float* bem    = (const float*)d_in[24];
    const float* Wm2    = (const float*)d_in[25];
    const float* bm2    = (const float*)d_in[26];

    // ---- workspace layout (float units; all chunks 16B-aligned) ----
    float* ws = (float*)d_ws;
    size_t off = 0;
    auto alloc = [&](size_t n) { float* p = ws + off; off += n; return p; };
    unsigned short* xb    = (unsigned short*)alloc((size_t)kN0 * 128 / 2);   // bf16 x
    unsigned short* Acat1 = (unsigned short*)alloc((size_t)kN1 * 640 / 2);   // [N1][640] bf16
    unsigned short* Acat2 = (unsigned short*)alloc((size_t)kN2 * 1280 / 2);  // [N2][1280] bf16
    float* h1             = alloc((size_t)kN1 * 256);
    unsigned short* h1b   = (unsigned short*)alloc((size_t)kN1 * 256 / 2);
    float* h2             = alloc((size_t)kN2 * 256);
    unsigned short* h2b   = (unsigned short*)alloc((size_t)kN2 * 256 / 2);
    float* h3             = alloc((size_t)kN2 * 256);
    unsigned short* Wcat1t = (unsigned short*)alloc(256 * 640 / 2);
    unsigned short* Wcat2t = (unsigned short*)alloc(256 * 1280 / 2);
    unsigned short* Wm1t   = (unsigned short*)alloc(256 * 256 / 2);
    float* v1   = alloc(128 * 8);
    float* v2   = alloc(256 * 8);
    float* als1 = alloc((size_t)kN0 * 4);
    float* ald1 = alloc((size_t)kN1 * 4);
    float* als2 = alloc((size_t)kN1 * 4);
    float* ald2 = alloc((size_t)kN2 * 4);
    float* zreg = alloc(1536 + kN1 + kN1 + kN2 + kN2);
    float* stats1 = zreg, *stats2 = zreg + 512, *stats3 = zreg + 1024;
    int* cnt1 = (int*)(zreg + 1536);
    int* cur1 = cnt1 + kN1;
    int* cnt2 = cur1 + kN1;
    int* cur2 = cnt2 + kN2;
    const int nzreg = 1536 + 2 * kN1 + 2 * kN2;
    int* srcs1  = (int*)alloc(kE1);
    int* offs1  = (int*)alloc(kN1 + 4);
    int* bsum1  = (int*)alloc(128);
    int* bscan1 = (int*)alloc(128);
    int* srcs2  = (int*)alloc(kE2);
    int* offs2  = (int*)alloc(kN2 + 4);
    int* bsum2  = (int*)alloc(128);
    int* bscan2 = (int*)alloc(128);

    hipStream_t st = stream;
    const int nb1 = (kN1 + 1023) / 1024;
    const int nb2 = (kN2 + 1023) / 1024;

    // ---- tiny precomputes ----
    build_v<<<(128 * 8 + 255) / 256, 256, 0, st>>>(W1, a_src1, a_dst1, v1, 128);
    build_v<<<(256 * 8 + 255) / 256, 256, 0, st>>>(W2, a_src2, a_dst2, v2, 256);
    build_wcat1<<<(256 * 640 + 255) / 256, 256, 0, st>>>(W1, Wsk1, Wcat1t);
    build_wcat2<<<(256 * 1280 + 255) / 256, 256, 0, st>>>(W2, Wsk2, Wcat2t);
    transp_w_par<<<(256 * 256 + 255) / 256, 256, 0, st>>>(Wm1, Wm1t, 8, 256);
    zero_f32<<<512, 256, 0, st>>>(zreg, nzreg);

    // ---- x -> bf16 + layer-1 attention dots (fused) ----
    conv_als1<<<2048, 256, 0, st>>>(x, v1, xb, als1, ald1);

    // ---- CSR builds ----
    hist_dst<<<(kE1 + 255) / 256, 256, 0, st>>>(dst1, cnt1, kE1);
    scan_block<<<nb1, 256, 0, st>>>(cnt1, kN1, offs1, bsum1);
    scan_bsums<<<1, 256, 0, st>>>(bsum1, bscan1, nb1);
    scan_add<<<(kN1 + 255) / 256, 256, 0, st>>>(offs1, bscan1, cnt1, kN1);
    csr_scatter<<<(kE1 + 255) / 256, 256, 0, st>>>(dst1, src1, offs1, cur1, srcs1, kE1);

    hist_dst<<<(kE2 + 255) / 256, 256, 0, st>>>(dst2, cnt2, kE2);
    scan_block<<<nb2, 256, 0, st>>>(cnt2, kN2, offs2, bsum2);
    scan_bsums<<<1, 256, 0, st>>>(bsum2, bscan2, nb2);
    scan_add<<<(kN2 + 255) / 256, 256, 0, st>>>(offs2, bscan2, cnt2, kN2);
    csr_scatter<<<(kE2 + 255) / 256, 256, 0, st>>>(dst2, src2, offs2, cur2, srcs2, kE2);

    // ================= layer 1 =================
    fused_agg1<<<(kN1 + 3) / 4, 256, 0, st>>>(xb, als1, ald1, srcs1, offs1, Acat1, kN1);
    gemm_pipe<false, true><<<dim3(2, (kN1 + 127) / 128), 256, 0, st>>>(
        Acat1, Wcat1t, h1, b1, bsk1, stats1, kN1, 256, 640);
    bn_rows<0, true, true><<<2048, 256, 0, st>>>(h1, stats1, g1, be1, h1b, v2, als2, ald2, kN1, kN2);

    // ================= layer 2 =================
    fused_agg2<<<(kN2 + 3) / 4, 256, 0, st>>>(h1b, als2, ald2, srcs2, offs2, Acat2, kN2);
    gemm_pipe<false, true><<<dim3(2, (kN2 + 127) / 128), 256, 0, st>>>(
        Acat2, Wcat2t, h2, b2, bsk2, stats2, kN2, 256, 1280);
    bn_rows<0, true, false><<<2048, 256, 0, st>>>(h2, stats2, g2, be2, h2b,
                                                  nullptr, nullptr, nullptr, kN2, 0);

    // ================= MLP head =================
    gemm_pipe<false, true><<<dim3(2, (kN2 + 127) / 128), 256, 0, st>>>(
        h2b, Wm1t, h3, bm1, nullptr, stats3, kN2, 256, 256);
    bn_rows<1, false, false><<<2048, 256, 0, st>>>(h3, stats3, gm, bem, h3,
                                                   nullptr, nullptr, nullptr, kN2, 0);
    gemm64<false><<<dim3(1, (kN2 + 63) / 64), 256, 0, st>>>(
        h3, Wm2, (float*)d_out, bm2, nullptr, kN2, kOUT, 256);
}

// Round 8
// 706.472 us; speedup vs baseline: 1.2876x; 1.1955x over previous
//
#include <hip/hip_runtime.h>
#include <math.h>

// Problem constants (fixed by the reference)
constexpr int kN0 = 400000, kN1 = 100000, kN2 = 20000;
constexpr int kE1 = 1000000, kE2 = 200000;
constexpr int kIN = 128, kHID = 256, kOUT = 47;
constexpr float kEPS = 1e-5f, kNEG = 0.2f;

#define DEV static __device__ __forceinline__

typedef __attribute__((ext_vector_type(8))) short short8;
typedef __attribute__((ext_vector_type(4))) float f32x4;

DEV float b2f(unsigned short u) { return __uint_as_float(((unsigned)u) << 16); }
DEV unsigned short f2bf(float f) {
    unsigned u = __float_as_uint(f);
    unsigned r = (u + 0x7fffu + ((u >> 16) & 1u)) >> 16;   // RNE
    return (unsigned short)r;
}
DEV float lrelu(float v) { return v > 0.f ? v : kNEG * v; }

DEV void gload_lds16(const void* g, void* l) {
    __builtin_amdgcn_global_load_lds(
        (const __attribute__((address_space(1))) void*)g,
        (__attribute__((address_space(3))) void*)l, 16, 0, 0);
}

// ---------------- utility ----------------
__global__ void zero_f32(float* __restrict__ p, int n) {
    int i = blockIdx.x * blockDim.x + threadIdx.x;
    int st = gridDim.x * blockDim.x;
    for (; i < n; i += st) p[i] = 0.f;
}

// ---- tiny weight precomputes ----
// vt[16][K] bf16: row j<8 -> (W @ a_j) transposed; j=0..3 a_src heads, 4..7 a_dst heads; rows 8..15 zero
__global__ void build_vt(const float* __restrict__ W, const float* __restrict__ as_,
                         const float* __restrict__ ad_, unsigned short* __restrict__ vt, int K) {
    int i = blockIdx.x * blockDim.x + threadIdx.x;
    if (i >= 16 * K) return;
    int j = i / K, k = i - j * K;
    float s = 0.f;
    if (j < 8) {
        int h = j & 3;
        const float* a = (j >= 4) ? ad_ : as_;
        for (int c = 0; c < 64; ++c) s += W[(size_t)k * 256 + h * 64 + c] * a[h * 64 + c];
    }
    vt[i] = f2bf(s);
}

// Wcat1t[256][640] bf16: k<512 -> blockdiag W1 (head h=k>>7, kin=k&127); k>=512 -> Wsk1[k-512]
__global__ void build_wcat1(const float* __restrict__ W1, const float* __restrict__ Wsk1,
                            unsigned short* __restrict__ Bt) {
    int i = blockIdx.x * blockDim.x + threadIdx.x;
    if (i >= 256 * 640) return;
    int n = i / 640, k = i % 640;
    float v;
    if (k < 512) { int h = k >> 7, kin = k & 127; v = ((n >> 6) == h) ? W1[(size_t)kin * 256 + n] : 0.f; }
    else v = Wsk1[(size_t)(k - 512) * 256 + n];
    Bt[i] = f2bf(v);
}

// Wcat2t[256][1280] bf16: k<1024 -> blockdiag W2 (head h=k>>8, kin=k&255); k>=1024 -> Wsk2
__global__ void build_wcat2(const float* __restrict__ W2, const float* __restrict__ Wsk2,
                            unsigned short* __restrict__ Bt) {
    int i = blockIdx.x * blockDim.x + threadIdx.x;
    if (i >= 256 * 1280) return;
    int n = i / 1280, k = i % 1280;
    float v;
    if (k < 1024) { int h = k >> 8, kin = k & 255; v = ((n >> 6) == h) ? W2[(size_t)kin * 256 + n] : 0.f; }
    else v = Wsk2[(size_t)(k - 1024) * 256 + n];
    Bt[i] = f2bf(v);
}

// W[K][N] f32 -> Wt[N][K] bf16 (for Wm1)
__global__ void transp_w_par(const float* __restrict__ W, unsigned short* __restrict__ Wt,
                             int kshift, int N) {
    int i = blockIdx.x * blockDim.x + threadIdx.x;
    int K = 1 << kshift;
    if (i >= N * K) return;
    int n = i >> kshift, k = i & (K - 1);
    Wt[i] = f2bf(W[(size_t)k * N + n]);
}

// ---- fused x->bf16 convert + layer-1 attention dots via MFMA (wave per 16 nodes) ----
// als[n][j] = <x[n], v1[:,j]>  computed as 16x16x32 MFMA against v1t[16][128] bf16.
__global__ __launch_bounds__(256) void conv_als_mfma(const float* __restrict__ x,
                                                     const unsigned short* __restrict__ v1t,
                                                     unsigned short* __restrict__ xb,
                                                     float* __restrict__ als,
                                                     float* __restrict__ ald) {
    int wid = threadIdx.x >> 6, lane = threadIdx.x & 63;
    int l15 = lane & 15, l4 = lane >> 4;
    short8 bfr[4];
    #pragma unroll
    for (int ks = 0; ks < 4; ++ks)
        bfr[ks] = *reinterpret_cast<const short8*>(&v1t[l15 * 128 + ks * 32 + l4 * 8]);

    const int ntile = kN0 / 16;
    int nw = gridDim.x * 4;
    for (int t = blockIdx.x * 4 + wid; t < ntile; t += nw) {
        int base = t * 16;
        int r = base + l15;
        f32x4 acc = (f32x4){0.f, 0.f, 0.f, 0.f};
        #pragma unroll
        for (int ks = 0; ks < 4; ++ks) {
            size_t o = (size_t)r * 128 + ks * 32 + l4 * 8;
            float4 xa = *reinterpret_cast<const float4*>(&x[o]);
            float4 xc = *reinterpret_cast<const float4*>(&x[o + 4]);
            short8 af;
            af[0] = (short)f2bf(xa.x); af[1] = (short)f2bf(xa.y);
            af[2] = (short)f2bf(xa.z); af[3] = (short)f2bf(xa.w);
            af[4] = (short)f2bf(xc.x); af[5] = (short)f2bf(xc.y);
            af[6] = (short)f2bf(xc.z); af[7] = (short)f2bf(xc.w);
            *reinterpret_cast<short8*>(&xb[o]) = af;
            acc = __builtin_amdgcn_mfma_f32_16x16x32_bf16(af, bfr[ks], acc, 0, 0, 0);
        }
        if (l15 < 8) {
            #pragma unroll
            for (int i = 0; i < 4; ++i) {
                int node = base + l4 * 4 + i;
                if (l15 < 4) als[(size_t)node * 4 + l15] = acc[i];
                else if (node < kN1) ald[(size_t)node * 4 + (l15 - 4)] = acc[i];
            }
        }
    }
}

// ---- fused BN(ELU) -> bf16 + layer-2 attention dots via MFMA (wave per 16 rows) ----
__global__ __launch_bounds__(256) void bn_mfma(const float* __restrict__ X,
                                               const float* __restrict__ stats,
                                               const float* __restrict__ gamma,
                                               const float* __restrict__ beta,
                                               unsigned short* __restrict__ outb,
                                               const unsigned short* __restrict__ v2t,
                                               float* __restrict__ als,
                                               float* __restrict__ ald,
                                               int M, int Ndst) {
    __shared__ float smu[256], ssc[256], ssh[256];
    {
        int c = threadIdx.x;
        float invM = 1.f / (float)M;
        float mu = stats[c] * invM;
        float var = stats[256 + c] * invM - mu * mu;
        smu[c] = mu;
        ssc[c] = rsqrtf(var + kEPS) * gamma[c];
        ssh[c] = beta[c];
    }
    __syncthreads();

    int wid = threadIdx.x >> 6, lane = threadIdx.x & 63;
    int l15 = lane & 15, l4 = lane >> 4;
    short8 bfr[8];
    #pragma unroll
    for (int ks = 0; ks < 8; ++ks)
        bfr[ks] = *reinterpret_cast<const short8*>(&v2t[l15 * 256 + ks * 32 + l4 * 8]);
    float mu8[8][2], sc8[8][2], sh8[8][2];
    #pragma unroll
    for (int ks = 0; ks < 8; ++ks) {
        int c0 = ks * 32 + l4 * 8;
        *reinterpret_cast<float4*>(&mu8[ks][0]) = *reinterpret_cast<const float4*>(&smu[c0]);
        *reinterpret_cast<float4*>(&sc8[ks][0]) = *reinterpret_cast<const float4*>(&ssc[c0]);
        *reinterpret_cast<float4*>(&sh8[ks][0]) = *reinterpret_cast<const float4*>(&ssh[c0]);
        // (loads 4; second half read in loop from LDS)
    }

    const int ntile = M / 16;
    int nw = gridDim.x * 4;
    for (int t = blockIdx.x * 4 + wid; t < ntile; t += nw) {
        int base = t * 16;
        int r = base + l15;
        f32x4 acc = (f32x4){0.f, 0.f, 0.f, 0.f};
        #pragma unroll
        for (int ks = 0; ks < 8; ++ks) {
            int c0 = ks * 32 + l4 * 8;
            size_t o = (size_t)r * 256 + c0;
            float4 xa = *reinterpret_cast<const float4*>(&X[o]);
            float4 xc = *reinterpret_cast<const float4*>(&X[o + 4]);
            float4 mua = *reinterpret_cast<const float4*>(&smu[c0]);
            float4 muc = *reinterpret_cast<const float4*>(&smu[c0 + 4]);
            float4 sca = *reinterpret_cast<const float4*>(&ssc[c0]);
            float4 scc = *reinterpret_cast<const float4*>(&ssc[c0 + 4]);
            float4 sha = *reinterpret_cast<const float4*>(&ssh[c0]);
            float4 shc = *reinterpret_cast<const float4*>(&ssh[c0 + 4]);
            float v[8];
            v[0] = (xa.x - mua.x) * sca.x + sha.x;
            v[1] = (xa.y - mua.y) * sca.y + sha.y;
            v[2] = (xa.z - mua.z) * sca.z + sha.z;
            v[3] = (xa.w - mua.w) * sca.w + sha.w;
            v[4] = (xc.x - muc.x) * scc.x + shc.x;
            v[5] = (xc.y - muc.y) * scc.y + shc.y;
            v[6] = (xc.z - muc.z) * scc.z + shc.z;
            v[7] = (xc.w - muc.w) * scc.w + shc.w;
            short8 af;
            #pragma unroll
            for (int i = 0; i < 8; ++i) {
                float tv = v[i] > 0.f ? v[i] : expm1f(v[i]);
                af[i] = (short)f2bf(tv);
            }
            *reinterpret_cast<short8*>(&outb[o]) = af;
            acc = __builtin_amdgcn_mfma_f32_16x16x32_bf16(af, bfr[ks], acc, 0, 0, 0);
        }
        if (l15 < 8) {
            #pragma unroll
            for (int i = 0; i < 4; ++i) {
                int node = base + l4 * 4 + i;
                if (l15 < 4) als[(size_t)node * 4 + l15] = acc[i];
                else if (node < Ndst) ald[(size_t)node * 4 + (l15 - 4)] = acc[i];
            }
        }
    }
}

// ================= CSR build =================
__global__ void hist_dst(const int* __restrict__ dst, int* __restrict__ counts, int E) {
    int e = blockIdx.x * blockDim.x + threadIdx.x;
    if (e < E) atomicAdd(&counts[dst[e]], 1);
}

__global__ __launch_bounds__(256) void scan_block(const int* __restrict__ counts, int n,
                                                  int* __restrict__ offs, int* __restrict__ bsum) {
    __shared__ int sh[256];
    int tid = threadIdx.x;
    int base = blockIdx.x * 1024 + tid * 4;
    int c0 = (base + 0 < n) ? counts[base + 0] : 0;
    int c1 = (base + 1 < n) ? counts[base + 1] : 0;
    int c2 = (base + 2 < n) ? counts[base + 2] : 0;
    int c3 = (base + 3 < n) ? counts[base + 3] : 0;
    int tot = c0 + c1 + c2 + c3;
    sh[tid] = tot;
    __syncthreads();
    for (int o = 1; o < 256; o <<= 1) {
        int t = (tid >= o) ? sh[tid - o] : 0;
        __syncthreads();
        sh[tid] += t;
        __syncthreads();
    }
    int excl = sh[tid] - tot;
    if (base + 0 < n) offs[base + 0] = excl;
    if (base + 1 < n) offs[base + 1] = excl + c0;
    if (base + 2 < n) offs[base + 2] = excl + c0 + c1;
    if (base + 3 < n) offs[base + 3] = excl + c0 + c1 + c2;
    if (tid == 255) bsum[blockIdx.x] = sh[255];
}

__global__ __launch_bounds__(256) void scan_bsums(const int* __restrict__ bsum,
                                                  int* __restrict__ bscan, int nb) {
    __shared__ int sh[256];
    int tid = threadIdx.x;
    int v = (tid < nb) ? bsum[tid] : 0;
    sh[tid] = v;
    __syncthreads();
    for (int o = 1; o < 256; o <<= 1) {
        int t = (tid >= o) ? sh[tid - o] : 0;
        __syncthreads();
        sh[tid] += t;
        __syncthreads();
    }
    if (tid < nb) bscan[tid] = sh[tid] - v;
}

__global__ void scan_add(int* __restrict__ offs, const int* __restrict__ bscan,
                         const int* __restrict__ counts, int n) {
    int i = blockIdx.x * blockDim.x + threadIdx.x;
    if (i < n) {
        int v = offs[i] + bscan[i >> 10];
        offs[i] = v;
        if (i == n - 1) offs[n] = v + counts[i];
    }
}

__global__ void csr_scatter(const int* __restrict__ dst, const int* __restrict__ src,
                            const int* __restrict__ offs,
                            int* __restrict__ cur, int* __restrict__ srcs, int E) {
    int e = blockIdx.x * blockDim.x + threadIdx.x;
    if (e >= E) return;
    int d = dst[e];
    int pos = offs[d] + atomicAdd(&cur[d], 1);
    srcs[pos] = src[e];
}

// ================= pipelined bf16 MFMA GEMM (2-phase double-buffer) =================
template <bool OUTBF, bool STATS>
__global__ __launch_bounds__(256) void gemm_pipe(const unsigned short* __restrict__ A,
                                                 const unsigned short* __restrict__ Bt,
                                                 void* __restrict__ Cv,
                                                 const float* __restrict__ bias1,
                                                 const float* __restrict__ bias2,
                                                 float* __restrict__ stats,
                                                 int M, int N, int K) {
    __shared__ unsigned short SH[4][128 * 64];   // SH[0..1]=A dbuf, SH[2..3]=B dbuf (64 KB)
    const int tid = threadIdx.x;
    const int wid = tid >> 6, lane = tid & 63;
    const int wr = wid >> 1, wc = wid & 1;
    const int l15 = lane & 15, l4 = lane >> 4;
    const int m0 = blockIdx.y * 128, n0 = blockIdx.x * 128;
    const int rsub = lane >> 3;
    const int kslot = (lane & 7) ^ rsub;

    auto stage = [&](int buf, int k0) {
        #pragma unroll
        for (int c = 0; c < 4; ++c) {
            int q = wid * 4 + c;
            int rowA = m0 + q * 8 + rsub; if (rowA > M - 1) rowA = M - 1;
            gload_lds16(A + (size_t)rowA * K + k0 + kslot * 8, &SH[buf][q * 512]);
            int rowB = n0 + q * 8 + rsub;
            gload_lds16(Bt + (size_t)rowB * K + k0 + kslot * 8, &SH[2 + buf][q * 512]);
        }
    };

    f32x4 acc[4][4];
    #pragma unroll
    for (int i = 0; i < 4; ++i)
        #pragma unroll
        for (int j = 0; j < 4; ++j) acc[i][j] = (f32x4){0.f, 0.f, 0.f, 0.f};

    stage(0, 0);
    __syncthreads();
    const int nt = K >> 6;
    for (int t = 0; t < nt; ++t) {
        if (t + 1 < nt) stage((t + 1) & 1, (t + 1) << 6);
        int b = t & 1;
        short8 af[2][4], bf[2][4];
        #pragma unroll
        for (int kk = 0; kk < 2; ++kk) {
            #pragma unroll
            for (int mi = 0; mi < 4; ++mi) {
                int row = wr * 64 + mi * 16 + l15;
                af[kk][mi] = *reinterpret_cast<const short8*>(
                    &SH[b][row * 64 + (((kk * 4 + l4) ^ (row & 7)) << 3)]);
            }
            #pragma unroll
            for (int ni = 0; ni < 4; ++ni) {
                int row = wc * 64 + ni * 16 + l15;
                bf[kk][ni] = *reinterpret_cast<const short8*>(
                    &SH[2 + b][row * 64 + (((kk * 4 + l4) ^ (row & 7)) << 3)]);
            }
        }
        #pragma unroll
        for (int kk = 0; kk < 2; ++kk)
            #pragma unroll
            for (int mi = 0; mi < 4; ++mi)
                #pragma unroll
                for (int ni = 0; ni < 4; ++ni)
                    acc[mi][ni] = __builtin_amdgcn_mfma_f32_16x16x32_bf16(
                        af[kk][mi], bf[kk][ni], acc[mi][ni], 0, 0, 0);
        __syncthreads();
    }

    float csum[4] = {0.f, 0.f, 0.f, 0.f}, csq[4] = {0.f, 0.f, 0.f, 0.f};
    unsigned short* LB = (unsigned short*)SH;
    float* LF = (float*)SH;
    #pragma unroll
    for (int mi = 0; mi < 4; ++mi) {
        int lrow0 = wr * 64 + mi * 16 + l4 * 4;
        #pragma unroll
        for (int ni = 0; ni < 4; ++ni) {
            int lcol = wc * 64 + ni * 16 + l15;
            int col = n0 + lcol;
            float badd = 0.f;
            if (bias1) badd += bias1[col];
            if (bias2) badd += bias2[col];
            f32x4 v = acc[mi][ni];
            #pragma unroll
            for (int i = 0; i < 4; ++i) {
                float o = v[i] + badd;
                if (STATS && (m0 + lrow0 + i) < M) { csum[ni] += o; csq[ni] += o * o; }
                if (OUTBF) LB[(lrow0 + i) * 128 + lcol] = f2bf(o);
                else LF[(lrow0 + i) * 128 + lcol] = o;
            }
        }
    }
    if (STATS) {
        #pragma unroll
        for (int ni = 0; ni < 4; ++ni) {
            float s = csum[ni], q = csq[ni];
            s += __shfl_xor(s, 16, 64); q += __shfl_xor(q, 16, 64);
            s += __shfl_xor(s, 32, 64); q += __shfl_xor(q, 32, 64);
            if (l4 == 0) {
                int col = n0 + wc * 64 + ni * 16 + l15;
                atomicAdd(&stats[col], s);
                atomicAdd(&stats[256 + col], q);
            }
        }
    }
    __syncthreads();
    if (OUTBF) {
        unsigned short* Cb = (unsigned short*)Cv;
        #pragma unroll
        for (int it = 0; it < 8; ++it) {
            int lin = (it * 256 + tid) * 8;
            int r = lin >> 7, c0 = lin & 127;
            int gr = m0 + r;
            if (gr < M)
                *reinterpret_cast<short8*>(&Cb[(size_t)gr * N + n0 + c0]) =
                    *reinterpret_cast<const short8*>(&LB[lin]);
        }
    } else {
        float* Cf = (float*)Cv;
        #pragma unroll
        for (int it = 0; it < 16; ++it) {
            int lin = (it * 256 + tid) * 4;
            int r = lin >> 7, c0 = lin & 127;
            int gr = m0 + r;
            if (gr < M)
                *reinterpret_cast<float4*>(&Cf[(size_t)gr * N + n0 + c0]) =
                    *reinterpret_cast<const float4*>(&LF[lin]);
        }
    }
}

// ---------------- layer-1 fused softmax+aggregate in INPUT space (wave per dst) ----------------
__global__ __launch_bounds__(256) void fused_agg1(const unsigned short* __restrict__ xb,
                                                  const float* __restrict__ als,
                                                  const float* __restrict__ ald,
                                                  const int* __restrict__ srcs,
                                                  const int* __restrict__ offs,
                                                  unsigned short* __restrict__ Acat, int Ndst) {
    int d = blockIdx.x * 4 + (threadIdx.x >> 6);
    if (d >= Ndst) return;
    int lane = threadIdx.x & 63;
    int beg = offs[d], end = offs[d + 1];
    float4 ad = *reinterpret_cast<const float4*>(&ald[(size_t)d * 4]);
    float ac[4][2] = {};
    float se0 = 0.f, se1 = 0.f, se2 = 0.f, se3 = 0.f;

    auto edge = [&](int s) {
        float4 a = *reinterpret_cast<const float4*>(&als[(size_t)s * 4]);
        unsigned xv = *reinterpret_cast<const unsigned*>(&xb[(size_t)s * 128 + lane * 2]);
        float e0 = expf(lrelu(a.x + ad.x));
        float e1 = expf(lrelu(a.y + ad.y));
        float e2 = expf(lrelu(a.z + ad.z));
        float e3 = expf(lrelu(a.w + ad.w));
        se0 += e0; se1 += e1; se2 += e2; se3 += e3;
        float fx = b2f((unsigned short)(xv & 0xffff));
        float fy = b2f((unsigned short)(xv >> 16));
        ac[0][0] = fmaf(e0, fx, ac[0][0]); ac[0][1] = fmaf(e0, fy, ac[0][1]);
        ac[1][0] = fmaf(e1, fx, ac[1][0]); ac[1][1] = fmaf(e1, fy, ac[1][1]);
        ac[2][0] = fmaf(e2, fx, ac[2][0]); ac[2][1] = fmaf(e2, fy, ac[2][1]);
        ac[3][0] = fmaf(e3, fx, ac[3][0]); ac[3][1] = fmaf(e3, fy, ac[3][1]);
    };
    int i = beg;
    for (; i + 4 <= end; i += 4) {
        int s0 = srcs[i], s1 = srcs[i + 1], s2 = srcs[i + 2], s3 = srcs[i + 3];
        edge(s0); edge(s1); edge(s2); edge(s3);
    }
    for (; i < end; ++i) edge(srcs[i]);

    float inv0 = 1.f / (se0 + 1e-16f), inv1 = 1.f / (se1 + 1e-16f);
    float inv2 = 1.f / (se2 + 1e-16f), inv3 = 1.f / (se3 + 1e-16f);
    unsigned short* row = Acat + (size_t)d * 640;
    ushort2 o;
    o.x = f2bf(ac[0][0] * inv0); o.y = f2bf(ac[0][1] * inv0);
    *reinterpret_cast<ushort2*>(&row[0 * 128 + lane * 2]) = o;
    o.x = f2bf(ac[1][0] * inv1); o.y = f2bf(ac[1][1] * inv1);
    *reinterpret_cast<ushort2*>(&row[1 * 128 + lane * 2]) = o;
    o.x = f2bf(ac[2][0] * inv2); o.y = f2bf(ac[2][1] * inv2);
    *reinterpret_cast<ushort2*>(&row[2 * 128 + lane * 2]) = o;
    o.x = f2bf(ac[3][0] * inv3); o.y = f2bf(ac[3][1] * inv3);
    *reinterpret_cast<ushort2*>(&row[3 * 128 + lane * 2]) = o;
    *reinterpret_cast<ushort2*>(&row[512 + lane * 2]) =
        *reinterpret_cast<const ushort2*>(&xb[(size_t)d * 128 + lane * 2]);
}

// ---------------- layer-2 fused softmax+aggregate (256 ch, lane=4ch) ----------------
__global__ __launch_bounds__(256) void fused_agg2(const unsigned short* __restrict__ hb,
                                                  const float* __restrict__ als,
                                                  const float* __restrict__ ald,
                                                  const int* __restrict__ srcs,
                                                  const int* __restrict__ offs,
                                                  unsigned short* __restrict__ Acat, int Ndst) {
    int d = blockIdx.x * 4 + (threadIdx.x >> 6);
    if (d >= Ndst) return;
    int lane = threadIdx.x & 63;
    int beg = offs[d], end = offs[d + 1];
    float4 ad = *reinterpret_cast<const float4*>(&ald[(size_t)d * 4]);
    float ac[4][4] = {};
    float se0 = 0.f, se1 = 0.f, se2 = 0.f, se3 = 0.f;

    auto edge = [&](int s) {
        float4 a = *reinterpret_cast<const float4*>(&als[(size_t)s * 4]);
        ushort4 xv = *reinterpret_cast<const ushort4*>(&hb[(size_t)s * 256 + lane * 4]);
        float e0 = expf(lrelu(a.x + ad.x));
        float e1 = expf(lrelu(a.y + ad.y));
        float e2 = expf(lrelu(a.z + ad.z));
        float e3 = expf(lrelu(a.w + ad.w));
        se0 += e0; se1 += e1; se2 += e2; se3 += e3;
        float f0 = b2f(xv.x), f1 = b2f(xv.y), f2 = b2f(xv.z), f3 = b2f(xv.w);
        ac[0][0] = fmaf(e0, f0, ac[0][0]); ac[0][1] = fmaf(e0, f1, ac[0][1]);
        ac[0][2] = fmaf(e0, f2, ac[0][2]); ac[0][3] = fmaf(e0, f3, ac[0][3]);
        ac[1][0] = fmaf(e1, f0, ac[1][0]); ac[1][1] = fmaf(e1, f1, ac[1][1]);
        ac[1][2] = fmaf(e1, f2, ac[1][2]); ac[1][3] = fmaf(e1, f3, ac[1][3]);
        ac[2][0] = fmaf(e2, f0, ac[2][0]); ac[2][1] = fmaf(e2, f1, ac[2][1]);
        ac[2][2] = fmaf(e2, f2, ac[2][2]); ac[2][3] = fmaf(e2, f3, ac[2][3]);
        ac[3][0] = fmaf(e3, f0, ac[3][0]); ac[3][1] = fmaf(e3, f1, ac[3][1]);
        ac[3][2] = fmaf(e3, f2, ac[3][2]); ac[3][3] = fmaf(e3, f3, ac[3][3]);
    };
    int i = beg;
    for (; i + 2 <= end; i += 2) { edge(srcs[i]); edge(srcs[i + 1]); }
    for (; i < end; ++i) edge(srcs[i]);

    float inv[4] = {1.f / (se0 + 1e-16f), 1.f / (se1 + 1e-16f),
                    1.f / (se2 + 1e-16f), 1.f / (se3 + 1e-16f)};
    unsigned short* row = Acat + (size_t)d * 1280;
    #pragma unroll
    for (int h = 0; h < 4; ++h) {
        ushort4 o;
        o.x = f2bf(ac[h][0] * inv[h]); o.y = f2bf(ac[h][1] * inv[h]);
        o.z = f2bf(ac[h][2] * inv[h]); o.w = f2bf(ac[h][3] * inv[h]);
        *reinterpret_cast<ushort4*>(&row[h * 256 + lane * 4]) = o;
    }
    *reinterpret_cast<ushort4*>(&row[1024 + lane * 4]) =
        *reinterpret_cast<const ushort4*>(&hb[(size_t)d * 256 + lane * 4]);
}

// ---------------- BN apply per row (no AL) ----------------
template <int ACT, bool OUTBF>
__global__ __launch_bounds__(256) void bn_rows(const float* __restrict__ X,
                                               const float* __restrict__ stats,
                                               const float* __restrict__ gamma,
                                               const float* __restrict__ beta,
                                               void* __restrict__ out, int M) {
    int wid = threadIdx.x >> 6, lane = threadIdx.x & 63;
    int nw = gridDim.x * 4;
    float4 s4 = *reinterpret_cast<const float4*>(&stats[lane * 4]);
    float4 q4 = *reinterpret_cast<const float4*>(&stats[256 + lane * 4]);
    float4 g4 = *reinterpret_cast<const float4*>(&gamma[lane * 4]);
    float4 b4 = *reinterpret_cast<const float4*>(&beta[lane * 4]);
    float invM = 1.f / (float)M;
    float mu[4] = {s4.x * invM, s4.y * invM, s4.z * invM, s4.w * invM};
    float sc[4], sh_[4] = {b4.x, b4.y, b4.z, b4.w};
    {
        float g[4] = {g4.x, g4.y, g4.z, g4.w};
        float q[4] = {q4.x, q4.y, q4.z, q4.w};
        #pragma unroll
        for (int c = 0; c < 4; ++c) {
            float var = q[c] * invM - mu[c] * mu[c];
            sc[c] = rsqrtf(var + kEPS) * g[c];
        }
    }
    for (int row = blockIdx.x * 4 + wid; row < M; row += nw) {
        float4 xv = *reinterpret_cast<const float4*>(&X[(size_t)row * 256 + lane * 4]);
        float v[4] = {xv.x, xv.y, xv.z, xv.w};
        #pragma unroll
        for (int c = 0; c < 4; ++c) {
            float t = (v[c] - mu[c]) * sc[c] + sh_[c];
            if (ACT == 0) t = t > 0.f ? t : expm1f(t);
            else t = fmaxf(t, 0.f);
            v[c] = t;
        }
        if (OUTBF) {
            ushort4 o; o.x = f2bf(v[0]); o.y = f2bf(v[1]); o.z = f2bf(v[2]); o.w = f2bf(v[3]);
            *reinterpret_cast<ushort4*>(&((unsigned short*)out)[(size_t)row * 256 + lane * 4]) = o;
        } else {
            *reinterpret_cast<float4*>(&((float*)out)[(size_t)row * 256 + lane * 4]) =
                make_float4(v[0], v[1], v[2], v[3]);
        }
    }
}

// ---------------- fp32 tiled GEMM (final N=47 head) ----------------
template <bool ACCUM>
__global__ __launch_bounds__(256) void gemm64(const float* __restrict__ A,
                                              const float* __restrict__ B,
                                              float* __restrict__ Cmat,
                                              const float* __restrict__ bias1,
                                              const float* __restrict__ bias2,
                                              int M, int N, int K) {
    __shared__ float As[32][68];
    __shared__ float Bs[32][68];
    const int tid = threadIdx.x;
    const int tx = tid & 15, ty = tid >> 4;
    const int m0 = blockIdx.y * 64, n0 = blockIdx.x * 64;
    float acc[4][4] = {};

    for (int k0 = 0; k0 < K; k0 += 32) {
        #pragma unroll
        for (int t = 0; t < 2; ++t) {
            int i = tid + t * 256;
            int row = i >> 3;
            int kq = (i & 7) << 2;
            float4 v = make_float4(0.f, 0.f, 0.f, 0.f);
            int gr = m0 + row;
            if (gr < M) v = *reinterpret_cast<const float4*>(&A[(size_t)gr * K + k0 + kq]);
            As[kq + 0][row] = v.x; As[kq + 1][row] = v.y;
            As[kq + 2][row] = v.z; As[kq + 3][row] = v.w;
        }
        #pragma unroll
        for (int t = 0; t < 2; ++t) {
            int i = tid + t * 256;
            int kr = i >> 4;
            int cq = (i & 15) << 2;
            #pragma unroll
            for (int j = 0; j < 4; ++j) {
                int gc = n0 + cq + j;
                Bs[kr][cq + j] = (gc < N) ? B[(size_t)(k0 + kr) * N + gc] : 0.f;
            }
        }
        __syncthreads();
        #pragma unroll
        for (int kk = 0; kk < 32; ++kk) {
            float4 a4 = *reinterpret_cast<const float4*>(&As[kk][ty << 2]);
            float4 b4 = *reinterpret_cast<const float4*>(&Bs[kk][tx << 2]);
            float a[4] = {a4.x, a4.y, a4.z, a4.w};
            float b[4] = {b4.x, b4.y, b4.z, b4.w};
            #pragma unroll
            for (int i2 = 0; i2 < 4; ++i2)
                #pragma unroll
                for (int j = 0; j < 4; ++j)
                    acc[i2][j] = fmaf(a[i2], b[j], acc[i2][j]);
        }
        __syncthreads();
    }

    #pragma unroll
    for (int i2 = 0; i2 < 4; ++i2) {
        int row = m0 + (ty << 2) + i2;
        if (row >= M) continue;
        #pragma unroll
        for (int j = 0; j < 4; ++j) {
            int col = n0 + (tx << 2) + j;
            if (col >= N) continue;
            float v = acc[i2][j];
            if (bias1) v += bias1[col];
            if (bias2) v += bias2[col];
            size_t idx = (size_t)row * N + col;
            if (ACCUM) v += Cmat[idx];
            Cmat[idx] = v;
        }
    }
}

extern "C" void kernel_launch(void* const* d_in, const int* in_sizes, int n_in,
                              void* d_out, int out_size, void* d_ws, size_t ws_size,
                              hipStream_t stream) {
    (void)in_sizes; (void)n_in; (void)out_size; (void)ws_size;

    const float* x      = (const float*)d_in[0];
    const int*   src1   = (const int*)d_in[1];
    const int*   dst1   = (const int*)d_in[2];
    const int*   src2   = (const int*)d_in[3];
    const int*   dst2   = (const int*)d_in[4];
    const float* W1     = (const float*)d_in[5];
    const float* a_src1 = (const float*)d_in[6];
    const float* a_dst1 = (const float*)d_in[7];
    const float* b1     = (const float*)d_in[8];
    const float* Wsk1   = (const float*)d_in[9];
    const float* bsk1   = (const float*)d_in[10];
    const float* g1     = (const float*)d_in[11];
    const float* be1    = (const float*)d_in[12];
    const float* W2     = (const float*)d_in[13];
    const float* a_src2 = (const float*)d_in[14];
    const float* a_dst2 = (const float*)d_in[15];
    const float* b2     = (const float*)d_in[16];
    const float* Wsk2   = (const float*)d_in[17];
    const float* bsk2   = (const float*)d_in[18];
    const float* g2     = (const float*)d_in[19];
    const float* be2    = (const float*)d_in[20];
    const float* Wm1    = (const float*)d_in[21];
    const float* bm1    = (const float*)d_in[22];
    const float* gm     = (const float*)d_in[23];
    const float* bem    = (const float*)d_in[24];
    const float* Wm2    = (const float*)d_in[25];
    const float* bm2    = (const float*)d_in[26];

    // ---- workspace layout (float units; all chunks 16B-aligned) ----
    float* ws = (float*)d_ws;
    size_t off = 0;
    auto alloc = [&](size_t n) { float* p = ws + off; off += n; return p; };
    unsigned short* xb    = (unsigned short*)alloc((size_t)kN0 * 128 / 2);
    unsigned short* Acat1 = (unsigned short*)alloc((size_t)kN1 * 640 / 2);
    unsigned short* Acat2 = (unsigned short*)alloc((size_t)kN2 * 1280 / 2);
    float* h1             = alloc((size_t)kN1 * 256);
    unsigned short* h1b   = (unsigned short*)alloc((size_t)kN1 * 256 / 2);
    float* h2             = alloc((size_t)kN2 * 256);
    unsigned short* h2b   = (unsigned short*)alloc((size_t)kN2 * 256 / 2);
    float* h3             = alloc((size_t)kN2 * 256);
    unsigned short* Wcat1t = (unsigned short*)alloc(256 * 640 / 2);
    unsigned short* Wcat2t = (unsigned short*)alloc(256 * 1280 / 2);
    unsigned short* Wm1t   = (unsigned short*)alloc(256 * 256 / 2);
    unsigned short* v1t    = (unsigned short*)alloc(16 * 128 / 2);
    unsigned short* v2t    = (unsigned short*)alloc(16 * 256 / 2);
    float* als1 = alloc((size_t)kN0 * 4);
    float* ald1 = alloc((size_t)kN1 * 4);
    float* als2 = alloc((size_t)kN1 * 4);
    float* ald2 = alloc((size_t)kN2 * 4);
    float* zreg = alloc(1536 + kN1 + kN1 + kN2 + kN2);
    float* stats1 = zreg, *stats2 = zreg + 512, *stats3 = zreg + 1024;
    int* cnt1 = (int*)(zreg + 1536);
    int* cur1 = cnt1 + kN1;
    int* cnt2 = cur1 + kN1;
    int* cur2 = cnt2 + kN2;
    const int nzreg = 1536 + 2 * kN1 + 2 * kN2;
    int* srcs1  = (int*)alloc(kE1);
    int* offs1  = (int*)alloc(kN1 + 4);
    int* bsum1  = (int*)alloc(128);
    int* bscan1 = (int*)alloc(128);
    int* srcs2  = (int*)alloc(kE2);
    int* offs2  = (int*)alloc(kN2 + 4);
    int* bsum2  = (int*)alloc(128);
    int* bscan2 = (int*)alloc(128);

    hipStream_t st = stream;
    const int nb1 = (kN1 + 1023) / 1024;
    const int nb2 = (kN2 + 1023) / 1024;

    // ---- tiny precomputes ----
    build_vt<<<(16 * 128 + 255) / 256, 256, 0, st>>>(W1, a_src1, a_dst1, v1t, 128);
    build_vt<<<(16 * 256 + 255) / 256, 256, 0, st>>>(W2, a_src2, a_dst2, v2t, 256);
    build_wcat1<<<(256 * 640 + 255) / 256, 256, 0, st>>>(W1, Wsk1, Wcat1t);
    build_wcat2<<<(256 * 1280 + 255) / 256, 256, 0, st>>>(W2, Wsk2, Wcat2t);
    transp_w_par<<<(256 * 256 + 255) / 256, 256, 0, st>>>(Wm1, Wm1t, 8, 256);
    zero_f32<<<512, 256, 0, st>>>(zreg, nzreg);

    // ---- x -> bf16 + layer-1 attention dots (MFMA-fused) ----
    conv_als_mfma<<<2048, 256, 0, st>>>(x, v1t, xb, als1, ald1);

    // ---- CSR builds ----
    hist_dst<<<(kE1 + 255) / 256, 256, 0, st>>>(dst1, cnt1, kE1);
    scan_block<<<nb1, 256, 0, st>>>(cnt1, kN1, offs1, bsum1);
    scan_bsums<<<1, 256, 0, st>>>(bsum1, bscan1, nb1);
    scan_add<<<(kN1 + 255) / 256, 256, 0, st>>>(offs1, bscan1, cnt1, kN1);
    csr_scatter<<<(kE1 + 255) / 256, 256, 0, st>>>(dst1, src1, offs1, cur1, srcs1, kE1);

    hist_dst<<<(kE2 + 255) / 256, 256, 0, st>>>(dst2, cnt2, kE2);
    scan_block<<<nb2, 256, 0, st>>>(cnt2, kN2, offs2, bsum2);
    scan_bsums<<<1, 256, 0, st>>>(bsum2, bscan2, nb2);
    scan_add<<<(kN2 + 255) / 256, 256, 0, st>>>(offs2, bscan2, cnt2, kN2);
    csr_scatter<<<(kE2 + 255) / 256, 256, 0, st>>>(dst2, src2, offs2, cur2, srcs2, kE2);

    // ================= layer 1 =================
    fused_agg1<<<(kN1 + 3) / 4, 256, 0, st>>>(xb, als1, ald1, srcs1, offs1, Acat1, kN1);
    gemm_pipe<false, true><<<dim3(2, (kN1 + 127) / 128), 256, 0, st>>>(
        Acat1, Wcat1t, h1, b1, bsk1, stats1, kN1, 256, 640);
    bn_mfma<<<1024, 256, 0, st>>>(h1, stats1, g1, be1, h1b, v2t, als2, ald2, kN1, kN2);

    // ================= layer 2 =================
    fused_agg2<<<(kN2 + 3) / 4, 256, 0, st>>>(h1b, als2, ald2, srcs2, offs2, Acat2, kN2);
    gemm_pipe<false, true><<<dim3(2, (kN2 + 127) / 128), 256, 0, st>>>(
        Acat2, Wcat2t, h2, b2, bsk2, stats2, kN2, 256, 1280);
    bn_rows<0, true><<<2048, 256, 0, st>>>(h2, stats2, g2, be2, h2b, kN2);

    // ================= MLP head =================
    gemm_pipe<false, true><<<dim3(2, (kN2 + 127) / 128), 256, 0, st>>>(
        h2b, Wm1t, h3, bm1, nullptr, stats3, kN2, 256, 256);
    bn_rows<1, false><<<2048, 256, 0, st>>>(h3, stats3, gm, bem, h3, kN2);
    gemm64<false><<<dim3(1, (kN2 + 63) / 64), 256, 0, st>>>(
        h3, Wm2, (float*)d_out, bm2, nullptr, kN2, kOUT, 256);
}

// Round 9
// 644.791 us; speedup vs baseline: 1.4108x; 1.0957x over previous
//
#include <hip/hip_runtime.h>
#include <math.h>

// Problem constants (fixed by the reference)
constexpr int kN0 = 400000, kN1 = 100000, kN2 = 20000;
constexpr int kE1 = 1000000, kE2 = 200000;
constexpr int kIN = 128, kHID = 256, kOUT = 47;
constexpr float kEPS = 1e-5f, kNEG = 0.2f;

#define DEV static __device__ __forceinline__

typedef __attribute__((ext_vector_type(8))) short short8;
typedef __attribute__((ext_vector_type(4))) float f32x4;

DEV float b2f(unsigned short u) { return __uint_as_float(((unsigned)u) << 16); }
DEV unsigned short f2bf(float f) {
    unsigned u = __float_as_uint(f);
    unsigned r = (u + 0x7fffu + ((u >> 16) & 1u)) >> 16;   // RNE
    return (unsigned short)r;
}
DEV float lrelu(float v) { return v > 0.f ? v : kNEG * v; }

DEV void gload_lds16(const void* g, void* l) {
    __builtin_amdgcn_global_load_lds(
        (const __attribute__((address_space(1))) void*)g,
        (__attribute__((address_space(3))) void*)l, 16, 0, 0);
}

// ---------------- utility ----------------
__global__ void zero_f32(float* __restrict__ p, int n) {
    int i = blockIdx.x * blockDim.x + threadIdx.x;
    int st = gridDim.x * blockDim.x;
    for (; i < n; i += st) p[i] = 0.f;
}

// ---- tiny weight precomputes ----
__global__ void build_vt(const float* __restrict__ W, const float* __restrict__ as_,
                         const float* __restrict__ ad_, unsigned short* __restrict__ vt, int K) {
    int i = blockIdx.x * blockDim.x + threadIdx.x;
    if (i >= 16 * K) return;
    int j = i / K, k = i - j * K;
    float s = 0.f;
    if (j < 8) {
        int h = j & 3;
        const float* a = (j >= 4) ? ad_ : as_;
        for (int c = 0; c < 64; ++c) s += W[(size_t)k * 256 + h * 64 + c] * a[h * 64 + c];
    }
    vt[i] = f2bf(s);
}

// Wcat1t[256][640] bf16: k<512 -> blockdiag W1 (head h=k>>7, kin=k&127); k>=512 -> Wsk1[k-512]
__global__ void build_wcat1(const float* __restrict__ W1, const float* __restrict__ Wsk1,
                            unsigned short* __restrict__ Bt) {
    int i = blockIdx.x * blockDim.x + threadIdx.x;
    if (i >= 256 * 640) return;
    int n = i / 640, k = i % 640;
    float v;
    if (k < 512) { int h = k >> 7, kin = k & 127; v = ((n >> 6) == h) ? W1[(size_t)kin * 256 + n] : 0.f; }
    else v = Wsk1[(size_t)(k - 512) * 256 + n];
    Bt[i] = f2bf(v);
}

// Wcat2t[256][1280] bf16
__global__ void build_wcat2(const float* __restrict__ W2, const float* __restrict__ Wsk2,
                            unsigned short* __restrict__ Bt) {
    int i = blockIdx.x * blockDim.x + threadIdx.x;
    if (i >= 256 * 1280) return;
    int n = i / 1280, k = i % 1280;
    float v;
    if (k < 1024) { int h = k >> 8, kin = k & 255; v = ((n >> 6) == h) ? W2[(size_t)kin * 256 + n] : 0.f; }
    else v = Wsk2[(size_t)(k - 1024) * 256 + n];
    Bt[i] = f2bf(v);
}

// W[K][N] f32 -> Wt[N][K] bf16 (for Wm1)
__global__ void transp_w_par(const float* __restrict__ W, unsigned short* __restrict__ Wt,
                             int kshift, int N) {
    int i = blockIdx.x * blockDim.x + threadIdx.x;
    int K = 1 << kshift;
    if (i >= N * K) return;
    int n = i >> kshift, k = i & (K - 1);
    Wt[i] = f2bf(W[(size_t)k * N + n]);
}

// ---- fused x->bf16 convert + layer-1 attention dots via MFMA (wave per 16 nodes) ----
__global__ __launch_bounds__(256) void conv_als_mfma(const float* __restrict__ x,
                                                     const unsigned short* __restrict__ v1t,
                                                     unsigned short* __restrict__ xb,
                                                     float* __restrict__ als,
                                                     float* __restrict__ ald) {
    int wid = threadIdx.x >> 6, lane = threadIdx.x & 63;
    int l15 = lane & 15, l4 = lane >> 4;
    short8 bfr[4];
    #pragma unroll
    for (int ks = 0; ks < 4; ++ks)
        bfr[ks] = *reinterpret_cast<const short8*>(&v1t[l15 * 128 + ks * 32 + l4 * 8]);

    const int ntile = kN0 / 16;
    int nw = gridDim.x * 4;
    for (int t = blockIdx.x * 4 + wid; t < ntile; t += nw) {
        int base = t * 16;
        int r = base + l15;
        f32x4 acc = (f32x4){0.f, 0.f, 0.f, 0.f};
        #pragma unroll
        for (int ks = 0; ks < 4; ++ks) {
            size_t o = (size_t)r * 128 + ks * 32 + l4 * 8;
            float4 xa = *reinterpret_cast<const float4*>(&x[o]);
            float4 xc = *reinterpret_cast<const float4*>(&x[o + 4]);
            short8 af;
            af[0] = (short)f2bf(xa.x); af[1] = (short)f2bf(xa.y);
            af[2] = (short)f2bf(xa.z); af[3] = (short)f2bf(xa.w);
            af[4] = (short)f2bf(xc.x); af[5] = (short)f2bf(xc.y);
            af[6] = (short)f2bf(xc.z); af[7] = (short)f2bf(xc.w);
            *reinterpret_cast<short8*>(&xb[o]) = af;
            acc = __builtin_amdgcn_mfma_f32_16x16x32_bf16(af, bfr[ks], acc, 0, 0, 0);
        }
        if (l15 < 8) {
            #pragma unroll
            for (int i = 0; i < 4; ++i) {
                int node = base + l4 * 4 + i;
                if (l15 < 4) als[(size_t)node * 4 + l15] = acc[i];
                else if (node < kN1) ald[(size_t)node * 4 + (l15 - 4)] = acc[i];
            }
        }
    }
}

// ---- fused BN(ELU) -> bf16 + layer-2 attention dots via MFMA (wave per 16 rows) ----
__global__ __launch_bounds__(256) void bn_mfma(const float* __restrict__ X,
                                               const float* __restrict__ stats,
                                               const float* __restrict__ gamma,
                                               const float* __restrict__ beta,
                                               unsigned short* __restrict__ outb,
                                               const unsigned short* __restrict__ v2t,
                                               float* __restrict__ als,
                                               float* __restrict__ ald,
                                               int M, int Ndst) {
    __shared__ float smu[256], ssc[256], ssh[256];
    {
        int c = threadIdx.x;
        float invM = 1.f / (float)M;
        float mu = stats[c] * invM;
        float var = stats[256 + c] * invM - mu * mu;
        smu[c] = mu;
        ssc[c] = rsqrtf(var + kEPS) * gamma[c];
        ssh[c] = beta[c];
    }
    __syncthreads();

    int wid = threadIdx.x >> 6, lane = threadIdx.x & 63;
    int l15 = lane & 15, l4 = lane >> 4;
    short8 bfr[8];
    #pragma unroll
    for (int ks = 0; ks < 8; ++ks)
        bfr[ks] = *reinterpret_cast<const short8*>(&v2t[l15 * 256 + ks * 32 + l4 * 8]);

    const int ntile = M / 16;
    int nw = gridDim.x * 4;
    for (int t = blockIdx.x * 4 + wid; t < ntile; t += nw) {
        int base = t * 16;
        int r = base + l15;
        f32x4 acc = (f32x4){0.f, 0.f, 0.f, 0.f};
        #pragma unroll
        for (int ks = 0; ks < 8; ++ks) {
            int c0 = ks * 32 + l4 * 8;
            size_t o = (size_t)r * 256 + c0;
            float4 xa = *reinterpret_cast<const float4*>(&X[o]);
            float4 xc = *reinterpret_cast<const float4*>(&X[o + 4]);
            float4 mua = *reinterpret_cast<const float4*>(&smu[c0]);
            float4 muc = *reinterpret_cast<const float4*>(&smu[c0 + 4]);
            float4 sca = *reinterpret_cast<const float4*>(&ssc[c0]);
            float4 scc = *reinterpret_cast<const float4*>(&ssc[c0 + 4]);
            float4 sha = *reinterpret_cast<const float4*>(&ssh[c0]);
            float4 shc = *reinterpret_cast<const float4*>(&ssh[c0 + 4]);
            float v[8];
            v[0] = (xa.x - mua.x) * sca.x + sha.x;
            v[1] = (xa.y - mua.y) * sca.y + sha.y;
            v[2] = (xa.z - mua.z) * sca.z + sha.z;
            v[3] = (xa.w - mua.w) * sca.w + sha.w;
            v[4] = (xc.x - muc.x) * scc.x + shc.x;
            v[5] = (xc.y - muc.y) * scc.y + shc.y;
            v[6] = (xc.z - muc.z) * scc.z + shc.z;
            v[7] = (xc.w - muc.w) * scc.w + shc.w;
            short8 af;
            #pragma unroll
            for (int i = 0; i < 8; ++i) {
                float tv = v[i] > 0.f ? v[i] : expm1f(v[i]);
                af[i] = (short)f2bf(tv);
            }
            *reinterpret_cast<short8*>(&outb[o]) = af;
            acc = __builtin_amdgcn_mfma_f32_16x16x32_bf16(af, bfr[ks], acc, 0, 0, 0);
        }
        if (l15 < 8) {
            #pragma unroll
            for (int i = 0; i < 4; ++i) {
                int node = base + l4 * 4 + i;
                if (l15 < 4) als[(size_t)node * 4 + l15] = acc[i];
                else if (node < Ndst) ald[(size_t)node * 4 + (l15 - 4)] = acc[i];
            }
        }
    }
}

// ================= CSR build =================
__global__ void hist_dst(const int* __restrict__ dst, int* __restrict__ counts, int E) {
    int e = blockIdx.x * blockDim.x + threadIdx.x;
    if (e < E) atomicAdd(&counts[dst[e]], 1);
}

__global__ __launch_bounds__(256) void scan_block(const int* __restrict__ counts, int n,
                                                  int* __restrict__ offs, int* __restrict__ bsum) {
    __shared__ int sh[256];
    int tid = threadIdx.x;
    int base = blockIdx.x * 1024 + tid * 4;
    int c0 = (base + 0 < n) ? counts[base + 0] : 0;
    int c1 = (base + 1 < n) ? counts[base + 1] : 0;
    int c2 = (base + 2 < n) ? counts[base + 2] : 0;
    int c3 = (base + 3 < n) ? counts[base + 3] : 0;
    int tot = c0 + c1 + c2 + c3;
    sh[tid] = tot;
    __syncthreads();
    for (int o = 1; o < 256; o <<= 1) {
        int t = (tid >= o) ? sh[tid - o] : 0;
        __syncthreads();
        sh[tid] += t;
        __syncthreads();
    }
    int excl = sh[tid] - tot;
    if (base + 0 < n) offs[base + 0] = excl;
    if (base + 1 < n) offs[base + 1] = excl + c0;
    if (base + 2 < n) offs[base + 2] = excl + c0 + c1;
    if (base + 3 < n) offs[base + 3] = excl + c0 + c1 + c2;
    if (tid == 255) bsum[blockIdx.x] = sh[255];
}

__global__ __launch_bounds__(256) void scan_bsums(const int* __restrict__ bsum,
                                                  int* __restrict__ bscan, int nb) {
    __shared__ int sh[256];
    int tid = threadIdx.x;
    int v = (tid < nb) ? bsum[tid] : 0;
    sh[tid] = v;
    __syncthreads();
    for (int o = 1; o < 256; o <<= 1) {
        int t = (tid >= o) ? sh[tid - o] : 0;
        __syncthreads();
        sh[tid] += t;
        __syncthreads();
    }
    if (tid < nb) bscan[tid] = sh[tid] - v;
}

__global__ void scan_add(int* __restrict__ offs, const int* __restrict__ bscan,
                         const int* __restrict__ counts, int n) {
    int i = blockIdx.x * blockDim.x + threadIdx.x;
    if (i < n) {
        int v = offs[i] + bscan[i >> 10];
        offs[i] = v;
        if (i == n - 1) offs[n] = v + counts[i];
    }
}

// scatter src id + per-edge softmax numerators w[h] = exp(lrelu(als[s]+ald[d]))
__global__ void csr_scatter_w(const int* __restrict__ dst, const int* __restrict__ src,
                              const int* __restrict__ offs,
                              const float* __restrict__ als, const float* __restrict__ ald,
                              int* __restrict__ cur, int* __restrict__ srcs,
                              float4* __restrict__ wbuf, int E) {
    int e = blockIdx.x * blockDim.x + threadIdx.x;
    if (e >= E) return;
    int d = dst[e], s = src[e];
    int pos = offs[d] + atomicAdd(&cur[d], 1);
    srcs[pos] = s;
    float4 a = *reinterpret_cast<const float4*>(&als[(size_t)s * 4]);
    float4 b = *reinterpret_cast<const float4*>(&ald[(size_t)d * 4]);
    float4 w;
    w.x = expf(lrelu(a.x + b.x));
    w.y = expf(lrelu(a.y + b.y));
    w.z = expf(lrelu(a.z + b.z));
    w.w = expf(lrelu(a.w + b.w));
    wbuf[pos] = w;
}

// ================= pipelined bf16 MFMA GEMM (2-phase double-buffer) =================
template <bool OUTBF, bool STATS>
__global__ __launch_bounds__(256) void gemm_pipe(const unsigned short* __restrict__ A,
                                                 const unsigned short* __restrict__ Bt,
                                                 void* __restrict__ Cv,
                                                 const float* __restrict__ bias1,
                                                 const float* __restrict__ bias2,
                                                 float* __restrict__ stats,
                                                 int M, int N, int K) {
    __shared__ unsigned short SH[4][128 * 64];
    const int tid = threadIdx.x;
    const int wid = tid >> 6, lane = tid & 63;
    const int wr = wid >> 1, wc = wid & 1;
    const int l15 = lane & 15, l4 = lane >> 4;
    const int m0 = blockIdx.y * 128, n0 = blockIdx.x * 128;
    const int rsub = lane >> 3;
    const int kslot = (lane & 7) ^ rsub;

    auto stage = [&](int buf, int k0) {
        #pragma unroll
        for (int c = 0; c < 4; ++c) {
            int q = wid * 4 + c;
            int rowA = m0 + q * 8 + rsub; if (rowA > M - 1) rowA = M - 1;
            gload_lds16(A + (size_t)rowA * K + k0 + kslot * 8, &SH[buf][q * 512]);
            int rowB = n0 + q * 8 + rsub;
            gload_lds16(Bt + (size_t)rowB * K + k0 + kslot * 8, &SH[2 + buf][q * 512]);
        }
    };

    f32x4 acc[4][4];
    #pragma unroll
    for (int i = 0; i < 4; ++i)
        #pragma unroll
        for (int j = 0; j < 4; ++j) acc[i][j] = (f32x4){0.f, 0.f, 0.f, 0.f};

    stage(0, 0);
    __syncthreads();
    const int nt = K >> 6;
    for (int t = 0; t < nt; ++t) {
        if (t + 1 < nt) stage((t + 1) & 1, (t + 1) << 6);
        int b = t & 1;
        short8 af[2][4], bf[2][4];
        #pragma unroll
        for (int kk = 0; kk < 2; ++kk) {
            #pragma unroll
            for (int mi = 0; mi < 4; ++mi) {
                int row = wr * 64 + mi * 16 + l15;
                af[kk][mi] = *reinterpret_cast<const short8*>(
                    &SH[b][row * 64 + (((kk * 4 + l4) ^ (row & 7)) << 3)]);
            }
            #pragma unroll
            for (int ni = 0; ni < 4; ++ni) {
                int row = wc * 64 + ni * 16 + l15;
                bf[kk][ni] = *reinterpret_cast<const short8*>(
                    &SH[2 + b][row * 64 + (((kk * 4 + l4) ^ (row & 7)) << 3)]);
            }
        }
        #pragma unroll
        for (int kk = 0; kk < 2; ++kk)
            #pragma unroll
            for (int mi = 0; mi < 4; ++mi)
                #pragma unroll
                for (int ni = 0; ni < 4; ++ni)
                    acc[mi][ni] = __builtin_amdgcn_mfma_f32_16x16x32_bf16(
                        af[kk][mi], bf[kk][ni], acc[mi][ni], 0, 0, 0);
        __syncthreads();
    }

    float csum[4] = {0.f, 0.f, 0.f, 0.f}, csq[4] = {0.f, 0.f, 0.f, 0.f};
    unsigned short* LB = (unsigned short*)SH;
    float* LF = (float*)SH;
    #pragma unroll
    for (int mi = 0; mi < 4; ++mi) {
        int lrow0 = wr * 64 + mi * 16 + l4 * 4;
        #pragma unroll
        for (int ni = 0; ni < 4; ++ni) {
            int lcol = wc * 64 + ni * 16 + l15;
            int col = n0 + lcol;
            float badd = 0.f;
            if (bias1) badd += bias1[col];
            if (bias2) badd += bias2[col];
            f32x4 v = acc[mi][ni];
            #pragma unroll
            for (int i = 0; i < 4; ++i) {
                float o = v[i] + badd;
                if (STATS && (m0 + lrow0 + i) < M) { csum[ni] += o; csq[ni] += o * o; }
                if (OUTBF) LB[(lrow0 + i) * 128 + lcol] = f2bf(o);
                else LF[(lrow0 + i) * 128 + lcol] = o;
            }
        }
    }
    if (STATS) {
        #pragma unroll
        for (int ni = 0; ni < 4; ++ni) {
            float s = csum[ni], q = csq[ni];
            s += __shfl_xor(s, 16, 64); q += __shfl_xor(q, 16, 64);
            s += __shfl_xor(s, 32, 64); q += __shfl_xor(q, 32, 64);
            if (l4 == 0) {
                int col = n0 + wc * 64 + ni * 16 + l15;
                atomicAdd(&stats[col], s);
                atomicAdd(&stats[256 + col], q);
            }
        }
    }
    __syncthreads();
    if (OUTBF) {
        unsigned short* Cb = (unsigned short*)Cv;
        #pragma unroll
        for (int it = 0; it < 8; ++it) {
            int lin = (it * 256 + tid) * 8;
            int r = lin >> 7, c0 = lin & 127;
            int gr = m0 + r;
            if (gr < M)
                *reinterpret_cast<short8*>(&Cb[(size_t)gr * N + n0 + c0]) =
                    *reinterpret_cast<const short8*>(&LB[lin]);
        }
    } else {
        float* Cf = (float*)Cv;
        #pragma unroll
        for (int it = 0; it < 16; ++it) {
            int lin = (it * 256 + tid) * 4;
            int r = lin >> 7, c0 = lin & 127;
            int gr = m0 + r;
            if (gr < M)
                *reinterpret_cast<float4*>(&Cf[(size_t)gr * N + n0 + c0]) =
                    *reinterpret_cast<const float4*>(&LF[lin]);
        }
    }
}

// ---------------- layer-1 aggregate with precomputed edge weights (wave per dst) ----------------
__global__ __launch_bounds__(256) void fused_agg1(const unsigned short* __restrict__ xb,
                                                  const float4* __restrict__ wbuf,
                                                  const int* __restrict__ srcs,
                                                  const int* __restrict__ offs,
                                                  unsigned short* __restrict__ Acat, int Ndst) {
    int d = blockIdx.x * 4 + (threadIdx.x >> 6);
    if (d >= Ndst) return;
    int lane = threadIdx.x & 63;
    int beg = offs[d], end = offs[d + 1];
    float ac[4][2] = {};
    float se0 = 0.f, se1 = 0.f, se2 = 0.f, se3 = 0.f;

    auto edge = [&](int i) {
        int s = srcs[i];
        float4 w = wbuf[i];
        unsigned xv = *reinterpret_cast<const unsigned*>(&xb[(size_t)s * 128 + lane * 2]);
        se0 += w.x; se1 += w.y; se2 += w.z; se3 += w.w;
        float fx = b2f((unsigned short)(xv & 0xffff));
        float fy = b2f((unsigned short)(xv >> 16));
        ac[0][0] = fmaf(w.x, fx, ac[0][0]); ac[0][1] = fmaf(w.x, fy, ac[0][1]);
        ac[1][0] = fmaf(w.y, fx, ac[1][0]); ac[1][1] = fmaf(w.y, fy, ac[1][1]);
        ac[2][0] = fmaf(w.z, fx, ac[2][0]); ac[2][1] = fmaf(w.z, fy, ac[2][1]);
        ac[3][0] = fmaf(w.w, fx, ac[3][0]); ac[3][1] = fmaf(w.w, fy, ac[3][1]);
    };
    int i = beg;
    for (; i + 4 <= end; i += 4) { edge(i); edge(i + 1); edge(i + 2); edge(i + 3); }
    for (; i < end; ++i) edge(i);

    float inv0 = 1.f / (se0 + 1e-16f), inv1 = 1.f / (se1 + 1e-16f);
    float inv2 = 1.f / (se2 + 1e-16f), inv3 = 1.f / (se3 + 1e-16f);
    unsigned short* row = Acat + (size_t)d * 640;
    ushort2 o;
    o.x = f2bf(ac[0][0] * inv0); o.y = f2bf(ac[0][1] * inv0);
    *reinterpret_cast<ushort2*>(&row[0 * 128 + lane * 2]) = o;
    o.x = f2bf(ac[1][0] * inv1); o.y = f2bf(ac[1][1] * inv1);
    *reinterpret_cast<ushort2*>(&row[1 * 128 + lane * 2]) = o;
    o.x = f2bf(ac[2][0] * inv2); o.y = f2bf(ac[2][1] * inv2);
    *reinterpret_cast<ushort2*>(&row[2 * 128 + lane * 2]) = o;
    o.x = f2bf(ac[3][0] * inv3); o.y = f2bf(ac[3][1] * inv3);
    *reinterpret_cast<ushort2*>(&row[3 * 128 + lane * 2]) = o;
    *reinterpret_cast<ushort2*>(&row[512 + lane * 2]) =
        *reinterpret_cast<const ushort2*>(&xb[(size_t)d * 128 + lane * 2]);
}

// ---------------- layer-2 aggregate with precomputed edge weights (256 ch, lane=4ch) ----------------
__global__ __launch_bounds__(256) void fused_agg2(const unsigned short* __restrict__ hb,
                                                  const float4* __restrict__ wbuf,
                                                  const int* __restrict__ srcs,
                                                  const int* __restrict__ offs,
                                                  unsigned short* __restrict__ Acat, int Ndst) {
    int d = blockIdx.x * 4 + (threadIdx.x >> 6);
    if (d >= Ndst) return;
    int lane = threadIdx.x & 63;
    int beg = offs[d], end = offs[d + 1];
    float ac[4][4] = {};
    float se0 = 0.f, se1 = 0.f, se2 = 0.f, se3 = 0.f;

    auto edge = [&](int i) {
        int s = srcs[i];
        float4 w = wbuf[i];
        ushort4 xv = *reinterpret_cast<const ushort4*>(&hb[(size_t)s * 256 + lane * 4]);
        se0 += w.x; se1 += w.y; se2 += w.z; se3 += w.w;
        float f0 = b2f(xv.x), f1 = b2f(xv.y), f2 = b2f(xv.z), f3 = b2f(xv.w);
        ac[0][0] = fmaf(w.x, f0, ac[0][0]); ac[0][1] = fmaf(w.x, f1, ac[0][1]);
        ac[0][2] = fmaf(w.x, f2, ac[0][2]); ac[0][3] = fmaf(w.x, f3, ac[0][3]);
        ac[1][0] = fmaf(w.y, f0, ac[1][0]); ac[1][1] = fmaf(w.y, f1, ac[1][1]);
        ac[1][2] = fmaf(w.y, f2, ac[1][2]); ac[1][3] = fmaf(w.y, f3, ac[1][3]);
        ac[2][0] = fmaf(w.z, f0, ac[2][0]); ac[2][1] = fmaf(w.z, f1, ac[2][1]);
        ac[2][2] = fmaf(w.z, f2, ac[2][2]); ac[2][3] = fmaf(w.z, f3, ac[2][3]);
        ac[3][0] = fmaf(w.w, f0, ac[3][0]); ac[3][1] = fmaf(w.w, f1, ac[3][1]);
        ac[3][2] = fmaf(w.w, f2, ac[3][2]); ac[3][3] = fmaf(w.w, f3, ac[3][3]);
    };
    int i = beg;
    for (; i + 2 <= end; i += 2) { edge(i); edge(i + 1); }
    for (; i < end; ++i) edge(i);

    float inv[4] = {1.f / (se0 + 1e-16f), 1.f / (se1 + 1e-16f),
                    1.f / (se2 + 1e-16f), 1.f / (se3 + 1e-16f)};
    unsigned short* row = Acat + (size_t)d * 1280;
    #pragma unroll
    for (int h = 0; h < 4; ++h) {
        ushort4 o;
        o.x = f2bf(ac[h][0] * inv[h]); o.y = f2bf(ac[h][1] * inv[h]);
        o.z = f2bf(ac[h][2] * inv[h]); o.w = f2bf(ac[h][3] * inv[h]);
        *reinterpret_cast<ushort4*>(&row[h * 256 + lane * 4]) = o;
    }
    *reinterpret_cast<ushort4*>(&row[1024 + lane * 4]) =
        *reinterpret_cast<const ushort4*>(&hb[(size_t)d * 256 + lane * 4]);
}

// ---------------- BN apply per row (no AL) ----------------
template <int ACT, bool OUTBF>
__global__ __launch_bounds__(256) void bn_rows(const float* __restrict__ X,
                                               const float* __restrict__ stats,
                                               const float* __restrict__ gamma,
                                               const float* __restrict__ beta,
                                               void* __restrict__ out, int M) {
    int wid = threadIdx.x >> 6, lane = threadIdx.x & 63;
    int nw = gridDim.x * 4;
    float4 s4 = *reinterpret_cast<const float4*>(&stats[lane * 4]);
    float4 q4 = *reinterpret_cast<const float4*>(&stats[256 + lane * 4]);
    float4 g4 = *reinterpret_cast<const float4*>(&gamma[lane * 4]);
    float4 b4 = *reinterpret_cast<const float4*>(&beta[lane * 4]);
    float invM = 1.f / (float)M;
    float mu[4] = {s4.x * invM, s4.y * invM, s4.z * invM, s4.w * invM};
    float sc[4], sh_[4] = {b4.x, b4.y, b4.z, b4.w};
    {
        float g[4] = {g4.x, g4.y, g4.z, g4.w};
        float q[4] = {q4.x, q4.y, q4.z, q4.w};
        #pragma unroll
        for (int c = 0; c < 4; ++c) {
            float var = q[c] * invM - mu[c] * mu[c];
            sc[c] = rsqrtf(var + kEPS) * g[c];
        }
    }
    for (int row = blockIdx.x * 4 + wid; row < M; row += nw) {
        float4 xv = *reinterpret_cast<const float4*>(&X[(size_t)row * 256 + lane * 4]);
        float v[4] = {xv.x, xv.y, xv.z, xv.w};
        #pragma unroll
        for (int c = 0; c < 4; ++c) {
            float t = (v[c] - mu[c]) * sc[c] + sh_[c];
            if (ACT == 0) t = t > 0.f ? t : expm1f(t);
            else t = fmaxf(t, 0.f);
            v[c] = t;
        }
        if (OUTBF) {
            ushort4 o; o.x = f2bf(v[0]); o.y = f2bf(v[1]); o.z = f2bf(v[2]); o.w = f2bf(v[3]);
            *reinterpret_cast<ushort4*>(&((unsigned short*)out)[(size_t)row * 256 + lane * 4]) = o;
        } else {
            *reinterpret_cast<float4*>(&((float*)out)[(size_t)row * 256 + lane * 4]) =
                make_float4(v[0], v[1], v[2], v[3]);
        }
    }
}

// ---------------- fp32 tiled GEMM (final N=47 head) ----------------
template <bool ACCUM>
__global__ __launch_bounds__(256) void gemm64(const float* __restrict__ A,
                                              const float* __restrict__ B,
                                              float* __restrict__ Cmat,
                                              const float* __restrict__ bias1,
                                              const float* __restrict__ bias2,
                                              int M, int N, int K) {
    __shared__ float As[32][68];
    __shared__ float Bs[32][68];
    const int tid = threadIdx.x;
    const int tx = tid & 15, ty = tid >> 4;
    const int m0 = blockIdx.y * 64, n0 = blockIdx.x * 64;
    float acc[4][4] = {};

    for (int k0 = 0; k0 < K; k0 += 32) {
        #pragma unroll
        for (int t = 0; t < 2; ++t) {
            int i = tid + t * 256;
            int row = i >> 3;
            int kq = (i & 7) << 2;
            float4 v = make_float4(0.f, 0.f, 0.f, 0.f);
            int gr = m0 + row;
            if (gr < M) v = *reinterpret_cast<const float4*>(&A[(size_t)gr * K + k0 + kq]);
            As[kq + 0][row] = v.x; As[kq + 1][row] = v.y;
            As[kq + 2][row] = v.z; As[kq + 3][row] = v.w;
        }
        #pragma unroll
        for (int t = 0; t < 2; ++t) {
            int i = tid + t * 256;
            int kr = i >> 4;
            int cq = (i & 15) << 2;
            #pragma unroll
            for (int j = 0; j < 4; ++j) {
                int gc = n0 + cq + j;
                Bs[kr][cq + j] = (gc < N) ? B[(size_t)(k0 + kr) * N + gc] : 0.f;
            }
        }
        __syncthreads();
        #pragma unroll
        for (int kk = 0; kk < 32; ++kk) {
            float4 a4 = *reinterpret_cast<const float4*>(&As[kk][ty << 2]);
            float4 b4 = *reinterpret_cast<const float4*>(&Bs[kk][tx << 2]);
            float a[4] = {a4.x, a4.y, a4.z, a4.w};
            float b[4] = {b4.x, b4.y, b4.z, b4.w};
            #pragma unroll
            for (int i2 = 0; i2 < 4; ++i2)
                #pragma unroll
                for (int j = 0; j < 4; ++j)
                    acc[i2][j] = fmaf(a[i2], b[j], acc[i2][j]);
        }
        __syncthreads();
    }

    #pragma unroll
    for (int i2 = 0; i2 < 4; ++i2) {
        int row = m0 + (ty << 2) + i2;
        if (row >= M) continue;
        #pragma unroll
        for (int j = 0; j < 4; ++j) {
            int col = n0 + (tx << 2) + j;
            if (col >= N) continue;
            float v = acc[i2][j];
            if (bias1) v += bias1[col];
            if (bias2) v += bias2[col];
            size_t idx = (size_t)row * N + col;
            if (ACCUM) v += Cmat[idx];
            Cmat[idx] = v;
        }
    }
}

extern "C" void kernel_launch(void* const* d_in, const int* in_sizes, int n_in,
                              void* d_out, int out_size, void* d_ws, size_t ws_size,
                              hipStream_t stream) {
    (void)in_sizes; (void)n_in; (void)out_size; (void)ws_size;

    const float* x      = (const float*)d_in[0];
    const int*   src1   = (const int*)d_in[1];
    const int*   dst1   = (const int*)d_in[2];
    const int*   src2   = (const int*)d_in[3];
    const int*   dst2   = (const int*)d_in[4];
    const float* W1     = (const float*)d_in[5];
    const float* a_src1 = (const float*)d_in[6];
    const float* a_dst1 = (const float*)d_in[7];
    const float* b1     = (const float*)d_in[8];
    const float* Wsk1   = (const float*)d_in[9];
    const float* bsk1   = (const float*)d_in[10];
    const float* g1     = (const float*)d_in[11];
    const float* be1    = (const float*)d_in[12];
    const float* W2     = (const float*)d_in[13];
    const float* a_src2 = (const float*)d_in[14];
    const float* a_dst2 = (const float*)d_in[15];
    const float* b2     = (const float*)d_in[16];
    const float* Wsk2   = (const float*)d_in[17];
    const float* bsk2   = (const float*)d_in[18];
    const float* g2     = (const float*)d_in[19];
    const float* be2    = (const float*)d_in[20];
    const float* Wm1    = (const float*)d_in[21];
    const float* bm1    = (const float*)d_in[22];
    const float* gm     = (const float*)d_in[23];
    const float* bem    = (const float*)d_in[24];
    const float* Wm2    = (const float*)d_in[25];
    const float* bm2    = (const float*)d_in[26];

    // ---- workspace layout (float units; all chunks 16B-aligned) ----
    float* ws = (float*)d_ws;
    size_t off = 0;
    auto alloc = [&](size_t n) { float* p = ws + off; off += n; return p; };
    unsigned short* xb    = (unsigned short*)alloc((size_t)kN0 * 128 / 2);
    unsigned short* Acat1 = (unsigned short*)alloc((size_t)kN1 * 640 / 2);
    unsigned short* Acat2 = (unsigned short*)alloc((size_t)kN2 * 1280 / 2);
    float* h1             = alloc((size_t)kN1 * 256);
    unsigned short* h1b   = (unsigned short*)alloc((size_t)kN1 * 256 / 2);
    float* h2             = alloc((size_t)kN2 * 256);
    unsigned short* h2b   = (unsigned short*)alloc((size_t)kN2 * 256 / 2);
    float* h3             = alloc((size_t)kN2 * 256);
    unsigned short* Wcat1t = (unsigned short*)alloc(256 * 640 / 2);
    unsigned short* Wcat2t = (unsigned short*)alloc(256 * 1280 / 2);
    unsigned short* Wm1t   = (unsigned short*)alloc(256 * 256 / 2);
    unsigned short* v1t    = (unsigned short*)alloc(16 * 128 / 2);
    unsigned short* v2t    = (unsigned short*)alloc(16 * 256 / 2);
    float4* w1buf = (float4*)alloc((size_t)kE1 * 4);
    float4* w2buf = (float4*)alloc((size_t)kE2 * 4);
    float* als1 = alloc((size_t)kN0 * 4);
    float* ald1 = alloc((size_t)kN1 * 4);
    float* als2 = alloc((size_t)kN1 * 4);
    float* ald2 = alloc((size_t)kN2 * 4);
    float* zreg = alloc(1536 + kN1 + kN1 + kN2 + kN2);
    float* stats1 = zreg, *stats2 = zreg + 512, *stats3 = zreg + 1024;
    int* cnt1 = (int*)(zreg + 1536);
    int* cur1 = cnt1 + kN1;
    int* cnt2 = cur1 + kN1;
    int* cur2 = cnt2 + kN2;
    const int nzreg = 1536 + 2 * kN1 + 2 * kN2;
    int* srcs1  = (int*)alloc(kE1);
    int* offs1  = (int*)alloc(kN1 + 4);
    int* bsum1  = (int*)alloc(128);
    int* bscan1 = (int*)alloc(128);
    int* srcs2  = (int*)alloc(kE2);
    int* offs2  = (int*)alloc(kN2 + 4);
    int* bsum2  = (int*)alloc(128);
    int* bscan2 = (int*)alloc(128);

    hipStream_t st = stream;
    const int nb1 = (kN1 + 1023) / 1024;
    const int nb2 = (kN2 + 1023) / 1024;

    // ---- tiny precomputes ----
    build_vt<<<(16 * 128 + 255) / 256, 256, 0, st>>>(W1, a_src1, a_dst1, v1t, 128);
    build_vt<<<(16 * 256 + 255) / 256, 256, 0, st>>>(W2, a_src2, a_dst2, v2t, 256);
    build_wcat1<<<(256 * 640 + 255) / 256, 256, 0, st>>>(W1, Wsk1, Wcat1t);
    build_wcat2<<<(256 * 1280 + 255) / 256, 256, 0, st>>>(W2, Wsk2, Wcat2t);
    transp_w_par<<<(256 * 256 + 255) / 256, 256, 0, st>>>(Wm1, Wm1t, 8, 256);
    zero_f32<<<512, 256, 0, st>>>(zreg, nzreg);

    // ---- x -> bf16 + layer-1 attention dots (MFMA-fused) ----
    conv_als_mfma<<<2048, 256, 0, st>>>(x, v1t, xb, als1, ald1);

    // ---- CSR builds (hist/scan both layers; scatter1 with edge weights) ----
    hist_dst<<<(kE1 + 255) / 256, 256, 0, st>>>(dst1, cnt1, kE1);
    scan_block<<<nb1, 256, 0, st>>>(cnt1, kN1, offs1, bsum1);
    scan_bsums<<<1, 256, 0, st>>>(bsum1, bscan1, nb1);
    scan_add<<<(kN1 + 255) / 256, 256, 0, st>>>(offs1, bscan1, cnt1, kN1);
    csr_scatter_w<<<(kE1 + 255) / 256, 256, 0, st>>>(dst1, src1, offs1, als1, ald1,
                                                     cur1, srcs1, w1buf, kE1);

    hist_dst<<<(kE2 + 255) / 256, 256, 0, st>>>(dst2, cnt2, kE2);
    scan_block<<<nb2, 256, 0, st>>>(cnt2, kN2, offs2, bsum2);
    scan_bsums<<<1, 256, 0, st>>>(bsum2, bscan2, nb2);
    scan_add<<<(kN2 + 255) / 256, 256, 0, st>>>(offs2, bscan2, cnt2, kN2);

    // ================= layer 1 =================
    fused_agg1<<<(kN1 + 3) / 4, 256, 0, st>>>(xb, w1buf, srcs1, offs1, Acat1, kN1);
    gemm_pipe<false, true><<<dim3(2, (kN1 + 127) / 128), 256, 0, st>>>(
        Acat1, Wcat1t, h1, b1, bsk1, stats1, kN1, 256, 640);
    bn_mfma<<<1024, 256, 0, st>>>(h1, stats1, g1, be1, h1b, v2t, als2, ald2, kN1, kN2);

    // ================= layer 2 =================
    csr_scatter_w<<<(kE2 + 255) / 256, 256, 0, st>>>(dst2, src2, offs2, als2, ald2,
                                                     cur2, srcs2, w2buf, kE2);
    fused_agg2<<<(kN2 + 3) / 4, 256, 0, st>>>(h1b, w2buf, srcs2, offs2, Acat2, kN2);
    gemm_pipe<false, true><<<dim3(2, (kN2 + 127) / 128), 256, 0, st>>>(
        Acat2, Wcat2t, h2, b2, bsk2, stats2, kN2, 256, 1280);
    bn_rows<0, true><<<2048, 256, 0, st>>>(h2, stats2, g2, be2, h2b, kN2);

    // ================= MLP head =================
    gemm_pipe<false, true><<<dim3(2, (kN2 + 127) / 128), 256, 0, st>>>(
        h2b, Wm1t, h3, bm1, nullptr, stats3, kN2, 256, 256);
    bn_rows<1, false><<<2048, 256, 0, st>>>(h3, stats3, gm, bem, h3, kN2);
    gemm64<false><<<dim3(1, (kN2 + 63) / 64), 256, 0, st>>>(
        h3, Wm2, (float*)d_out, bm2, nullptr, kN2, kOUT, 256);
}

// Round 10
// 591.968 us; speedup vs baseline: 1.5367x; 1.0892x over previous
//
#include <hip/hip_runtime.h>
#include <math.h>

// Problem constants (fixed by the reference)
constexpr int kN0 = 400000, kN1 = 100000, kN2 = 20000;
constexpr int kE1 = 1000000, kE2 = 200000;
constexpr int kIN = 128, kHID = 256, kOUT = 47;
constexpr float kEPS = 1e-5f, kNEG = 0.2f;

#define DEV static __device__ __forceinline__

typedef __attribute__((ext_vector_type(8))) short short8;
typedef __attribute__((ext_vector_type(4))) float f32x4;

DEV float b2f(unsigned short u) { return __uint_as_float(((unsigned)u) << 16); }
DEV unsigned short f2bf(float f) {
    unsigned u = __float_as_uint(f);
    unsigned r = (u + 0x7fffu + ((u >> 16) & 1u)) >> 16;   // RNE
    return (unsigned short)r;
}
DEV float lrelu(float v) { return v > 0.f ? v : kNEG * v; }

DEV void gload_lds16(const void* g, void* l) {
    __builtin_amdgcn_global_load_lds(
        (const __attribute__((address_space(1))) void*)g,
        (__attribute__((address_space(3))) void*)l, 16, 0, 0);
}

// ---------------- utility ----------------
__global__ void zero_f32(float* __restrict__ p, int n) {
    int i = blockIdx.x * blockDim.x + threadIdx.x;
    int st = gridDim.x * blockDim.x;
    for (; i < n; i += st) p[i] = 0.f;
}

// ---- merged weight precompute: v1t, v2t, Wcat1t, Wcat2t, Wm1t in one launch ----
// region sizes: 2048 | 4096 | 163840 | 327680 | 65536  (total 563200)
__global__ void prep_weights(const float* __restrict__ W1, const float* __restrict__ as1,
                             const float* __restrict__ ad1,
                             const float* __restrict__ W2, const float* __restrict__ as2,
                             const float* __restrict__ ad2,
                             const float* __restrict__ Wsk1, const float* __restrict__ Wsk2,
                             const float* __restrict__ Wm1,
                             unsigned short* __restrict__ v1t, unsigned short* __restrict__ v2t,
                             unsigned short* __restrict__ Wcat1t,
                             unsigned short* __restrict__ Wcat2t,
                             unsigned short* __restrict__ Wm1t) {
    int i = blockIdx.x * blockDim.x + threadIdx.x;
    if (i < 2048) {                       // v1t[16][128]
        int j = i >> 7, k = i & 127;
        float s = 0.f;
        if (j < 8) {
            int h = j & 3;
            const float* a = (j >= 4) ? ad1 : as1;
            for (int c = 0; c < 64; ++c) s += W1[(size_t)k * 256 + h * 64 + c] * a[h * 64 + c];
        }
        v1t[i] = f2bf(s);
        return;
    }
    i -= 2048;
    if (i < 4096) {                       // v2t[16][256]
        int j = i >> 8, k = i & 255;
        float s = 0.f;
        if (j < 8) {
            int h = j & 3;
            const float* a = (j >= 4) ? ad2 : as2;
            for (int c = 0; c < 64; ++c) s += W2[(size_t)k * 256 + h * 64 + c] * a[h * 64 + c];
        }
        v2t[i] = f2bf(s);
        return;
    }
    i -= 4096;
    if (i < 163840) {                     // Wcat1t[256][640]
        int n = i / 640, k = i % 640;
        float v;
        if (k < 512) { int h = k >> 7, kin = k & 127; v = ((n >> 6) == h) ? W1[(size_t)kin * 256 + n] : 0.f; }
        else v = Wsk1[(size_t)(k - 512) * 256 + n];
        Wcat1t[i] = f2bf(v);
        return;
    }
    i -= 163840;
    if (i < 327680) {                     // Wcat2t[256][1280]
        int n = i / 1280, k = i % 1280;
        float v;
        if (k < 1024) { int h = k >> 8, kin = k & 255; v = ((n >> 6) == h) ? W2[(size_t)kin * 256 + n] : 0.f; }
        else v = Wsk2[(size_t)(k - 1024) * 256 + n];
        Wcat2t[i] = f2bf(v);
        return;
    }
    i -= 327680;
    if (i < 65536) {                      // Wm1t[256][256]
        int n = i >> 8, k = i & 255;
        Wm1t[i] = f2bf(Wm1[(size_t)k * 256 + n]);
    }
}

// ---- fused x->bf16 convert + layer-1 attention dots via MFMA (wave per 16 nodes) ----
__global__ __launch_bounds__(256) void conv_als_mfma(const float* __restrict__ x,
                                                     const unsigned short* __restrict__ v1t,
                                                     unsigned short* __restrict__ xb,
                                                     float* __restrict__ als,
                                                     float* __restrict__ ald) {
    int wid = threadIdx.x >> 6, lane = threadIdx.x & 63;
    int l15 = lane & 15, l4 = lane >> 4;
    short8 bfr[4];
    #pragma unroll
    for (int ks = 0; ks < 4; ++ks)
        bfr[ks] = *reinterpret_cast<const short8*>(&v1t[l15 * 128 + ks * 32 + l4 * 8]);

    const int ntile = kN0 / 16;
    int nw = gridDim.x * 4;
    for (int t = blockIdx.x * 4 + wid; t < ntile; t += nw) {
        int base = t * 16;
        int r = base + l15;
        f32x4 acc = (f32x4){0.f, 0.f, 0.f, 0.f};
        #pragma unroll
        for (int ks = 0; ks < 4; ++ks) {
            size_t o = (size_t)r * 128 + ks * 32 + l4 * 8;
            float4 xa = *reinterpret_cast<const float4*>(&x[o]);
            float4 xc = *reinterpret_cast<const float4*>(&x[o + 4]);
            short8 af;
            af[0] = (short)f2bf(xa.x); af[1] = (short)f2bf(xa.y);
            af[2] = (short)f2bf(xa.z); af[3] = (short)f2bf(xa.w);
            af[4] = (short)f2bf(xc.x); af[5] = (short)f2bf(xc.y);
            af[6] = (short)f2bf(xc.z); af[7] = (short)f2bf(xc.w);
            *reinterpret_cast<short8*>(&xb[o]) = af;
            acc = __builtin_amdgcn_mfma_f32_16x16x32_bf16(af, bfr[ks], acc, 0, 0, 0);
        }
        if (l15 < 8) {
            #pragma unroll
            for (int i = 0; i < 4; ++i) {
                int node = base + l4 * 4 + i;
                if (l15 < 4) als[(size_t)node * 4 + l15] = acc[i];
                else if (node < kN1) ald[(size_t)node * 4 + (l15 - 4)] = acc[i];
            }
        }
    }
}

// ---- fused BN(ELU) bf16->bf16 + layer-2 attention dots via MFMA (wave per 16 rows) ----
__global__ __launch_bounds__(256) void bn_mfma(const unsigned short* __restrict__ X,
                                               const float* __restrict__ stats,
                                               const float* __restrict__ gamma,
                                               const float* __restrict__ beta,
                                               unsigned short* __restrict__ outb,
                                               const unsigned short* __restrict__ v2t,
                                               float* __restrict__ als,
                                               float* __restrict__ ald,
                                               int M, int Ndst) {
    __shared__ float smu[256], ssc[256], ssh[256];
    {
        int c = threadIdx.x;
        float invM = 1.f / (float)M;
        float mu = stats[c] * invM;
        float var = stats[256 + c] * invM - mu * mu;
        smu[c] = mu;
        ssc[c] = rsqrtf(var + kEPS) * gamma[c];
        ssh[c] = beta[c];
    }
    __syncthreads();

    int wid = threadIdx.x >> 6, lane = threadIdx.x & 63;
    int l15 = lane & 15, l4 = lane >> 4;
    short8 bfr[8];
    #pragma unroll
    for (int ks = 0; ks < 8; ++ks)
        bfr[ks] = *reinterpret_cast<const short8*>(&v2t[l15 * 256 + ks * 32 + l4 * 8]);

    const int ntile = M / 16;
    int nw = gridDim.x * 4;
    for (int t = blockIdx.x * 4 + wid; t < ntile; t += nw) {
        int base = t * 16;
        int r = base + l15;
        f32x4 acc = (f32x4){0.f, 0.f, 0.f, 0.f};
        #pragma unroll
        for (int ks = 0; ks < 8; ++ks) {
            int c0 = ks * 32 + l4 * 8;
            size_t o = (size_t)r * 256 + c0;
            short8 xr = *reinterpret_cast<const short8*>(&X[o]);
            float4 mua = *reinterpret_cast<const float4*>(&smu[c0]);
            float4 muc = *reinterpret_cast<const float4*>(&smu[c0 + 4]);
            float4 sca = *reinterpret_cast<const float4*>(&ssc[c0]);
            float4 scc = *reinterpret_cast<const float4*>(&ssc[c0 + 4]);
            float4 sha = *reinterpret_cast<const float4*>(&ssh[c0]);
            float4 shc = *reinterpret_cast<const float4*>(&ssh[c0 + 4]);
            float v[8];
            v[0] = (b2f((unsigned short)xr[0]) - mua.x) * sca.x + sha.x;
            v[1] = (b2f((unsigned short)xr[1]) - mua.y) * sca.y + sha.y;
            v[2] = (b2f((unsigned short)xr[2]) - mua.z) * sca.z + sha.z;
            v[3] = (b2f((unsigned short)xr[3]) - mua.w) * sca.w + sha.w;
            v[4] = (b2f((unsigned short)xr[4]) - muc.x) * scc.x + shc.x;
            v[5] = (b2f((unsigned short)xr[5]) - muc.y) * scc.y + shc.y;
            v[6] = (b2f((unsigned short)xr[6]) - muc.z) * scc.z + shc.z;
            v[7] = (b2f((unsigned short)xr[7]) - muc.w) * scc.w + shc.w;
            short8 af;
            #pragma unroll
            for (int i = 0; i < 8; ++i) {
                float tv = v[i] > 0.f ? v[i] : expm1f(v[i]);
                af[i] = (short)f2bf(tv);
            }
            *reinterpret_cast<short8*>(&outb[o]) = af;
            acc = __builtin_amdgcn_mfma_f32_16x16x32_bf16(af, bfr[ks], acc, 0, 0, 0);
        }
        if (l15 < 8) {
            #pragma unroll
            for (int i = 0; i < 4; ++i) {
                int node = base + l4 * 4 + i;
                if (l15 < 4) als[(size_t)node * 4 + l15] = acc[i];
                else if (node < Ndst) ald[(size_t)node * 4 + (l15 - 4)] = acc[i];
            }
        }
    }
}

// ================= CSR build (merged both layers) =================
__global__ void hist_both(const int* __restrict__ dst1, int* __restrict__ cnt1, int E1,
                          const int* __restrict__ dst2, int* __restrict__ cnt2, int E2) {
    int e = blockIdx.x * blockDim.x + threadIdx.x;
    if (e < E1) atomicAdd(&cnt1[dst1[e]], 1);
    else if (e - E1 < E2) atomicAdd(&cnt2[dst2[e - E1]], 1);
}

__global__ __launch_bounds__(256) void scan_block_both(const int* __restrict__ cnt1, int n1,
                                                       int* __restrict__ offs1, int* __restrict__ bsum1, int nb1,
                                                       const int* __restrict__ cnt2, int n2,
                                                       int* __restrict__ offs2, int* __restrict__ bsum2) {
    const int* counts; int n; int* offs; int* bsum; int b;
    if ((int)blockIdx.x < nb1) { counts = cnt1; n = n1; offs = offs1; bsum = bsum1; b = blockIdx.x; }
    else { counts = cnt2; n = n2; offs = offs2; bsum = bsum2; b = blockIdx.x - nb1; }
    __shared__ int sh[256];
    int tid = threadIdx.x;
    int base = b * 1024 + tid * 4;
    int c0 = (base + 0 < n) ? counts[base + 0] : 0;
    int c1 = (base + 1 < n) ? counts[base + 1] : 0;
    int c2 = (base + 2 < n) ? counts[base + 2] : 0;
    int c3 = (base + 3 < n) ? counts[base + 3] : 0;
    int tot = c0 + c1 + c2 + c3;
    sh[tid] = tot;
    __syncthreads();
    for (int o = 1; o < 256; o <<= 1) {
        int t = (tid >= o) ? sh[tid - o] : 0;
        __syncthreads();
        sh[tid] += t;
        __syncthreads();
    }
    int excl = sh[tid] - tot;
    if (base + 0 < n) offs[base + 0] = excl;
    if (base + 1 < n) offs[base + 1] = excl + c0;
    if (base + 2 < n) offs[base + 2] = excl + c0 + c1;
    if (base + 3 < n) offs[base + 3] = excl + c0 + c1 + c2;
    if (tid == 255) bsum[b] = sh[255];
}

__global__ __launch_bounds__(256) void scan_bsums_both(const int* __restrict__ bsum1,
                                                       int* __restrict__ bscan1, int nb1,
                                                       const int* __restrict__ bsum2,
                                                       int* __restrict__ bscan2, int nb2) {
    __shared__ int sh[256];
    int tid = threadIdx.x;
    int v = (tid < nb1) ? bsum1[tid] : 0;
    sh[tid] = v;
    __syncthreads();
    for (int o = 1; o < 256; o <<= 1) {
        int t = (tid >= o) ? sh[tid - o] : 0;
        __syncthreads();
        sh[tid] += t;
        __syncthreads();
    }
    if (tid < nb1) bscan1[tid] = sh[tid] - v;
    __syncthreads();
    int v2 = (tid < nb2) ? bsum2[tid] : 0;
    sh[tid] = v2;
    __syncthreads();
    for (int o = 1; o < 256; o <<= 1) {
        int t = (tid >= o) ? sh[tid - o] : 0;
        __syncthreads();
        sh[tid] += t;
        __syncthreads();
    }
    if (tid < nb2) bscan2[tid] = sh[tid] - v2;
}

__global__ void scan_add_both(int* __restrict__ offs1, const int* __restrict__ bscan1,
                              const int* __restrict__ cnt1, int n1,
                              int* __restrict__ offs2, const int* __restrict__ bscan2,
                              const int* __restrict__ cnt2, int n2) {
    int i = blockIdx.x * blockDim.x + threadIdx.x;
    if (i < n1) {
        int v = offs1[i] + bscan1[i >> 10];
        offs1[i] = v;
        if (i == n1 - 1) offs1[n1] = v + cnt1[i];
    } else {
        int j = i - n1;
        if (j < n2) {
            int v = offs2[j] + bscan2[j >> 10];
            offs2[j] = v;
            if (j == n2 - 1) offs2[n2] = v + cnt2[j];
        }
    }
}

// scatter src id + per-edge softmax numerators w[h] = exp(lrelu(als[s]+ald[d]))
__global__ void csr_scatter_w(const int* __restrict__ dst, const int* __restrict__ src,
                              const int* __restrict__ offs,
                              const float* __restrict__ als, const float* __restrict__ ald,
                              int* __restrict__ cur, int* __restrict__ srcs,
                              float4* __restrict__ wbuf, int E) {
    int e = blockIdx.x * blockDim.x + threadIdx.x;
    if (e >= E) return;
    int d = dst[e], s = src[e];
    int pos = offs[d] + atomicAdd(&cur[d], 1);
    srcs[pos] = s;
    float4 a = *reinterpret_cast<const float4*>(&als[(size_t)s * 4]);
    float4 b = *reinterpret_cast<const float4*>(&ald[(size_t)d * 4]);
    float4 w;
    w.x = expf(lrelu(a.x + b.x));
    w.y = expf(lrelu(a.y + b.y));
    w.z = expf(lrelu(a.z + b.z));
    w.w = expf(lrelu(a.w + b.w));
    wbuf[pos] = w;
}

// ================= pipelined bf16 MFMA GEMM, split-A (2-phase double-buffer) =================
// C[M][N] = [A1 | A2][M][K1+K2] @ Bt[N][K1+K2]^T + bias1 + bias2.
// BM=BN=128, BK=64, 4 waves. LDS-staged coalesced epilogue. K1,K2 multiples of 64 (K2 may be 0).
template <bool OUTBF, bool STATS>
__global__ __launch_bounds__(256) void gemm_pipe(const unsigned short* __restrict__ A1, int K1,
                                                 const unsigned short* __restrict__ A2, int K2,
                                                 const unsigned short* __restrict__ Bt,
                                                 void* __restrict__ Cv,
                                                 const float* __restrict__ bias1,
                                                 const float* __restrict__ bias2,
                                                 float* __restrict__ stats,
                                                 int M, int N) {
    __shared__ unsigned short SH[4][128 * 64];
    const int tid = threadIdx.x;
    const int wid = tid >> 6, lane = tid & 63;
    const int wr = wid >> 1, wc = wid & 1;
    const int l15 = lane & 15, l4 = lane >> 4;
    const int m0 = blockIdx.y * 128, n0 = blockIdx.x * 128;
    const int rsub = lane >> 3;
    const int kslot = (lane & 7) ^ rsub;
    const int KB = K1 + K2;

    auto stage = [&](int buf, int k0) {
        const unsigned short* Asrc; int ka, lda;
        if (k0 < K1) { Asrc = A1; ka = k0; lda = K1; }
        else { Asrc = A2; ka = k0 - K1; lda = K2; }
        #pragma unroll
        for (int c = 0; c < 4; ++c) {
            int q = wid * 4 + c;
            int rowA = m0 + q * 8 + rsub; if (rowA > M - 1) rowA = M - 1;
            gload_lds16(Asrc + (size_t)rowA * lda + ka + kslot * 8, &SH[buf][q * 512]);
            int rowB = n0 + q * 8 + rsub;
            gload_lds16(Bt + (size_t)rowB * KB + k0 + kslot * 8, &SH[2 + buf][q * 512]);
        }
    };

    f32x4 acc[4][4];
    #pragma unroll
    for (int i = 0; i < 4; ++i)
        #pragma unroll
        for (int j = 0; j < 4; ++j) acc[i][j] = (f32x4){0.f, 0.f, 0.f, 0.f};

    stage(0, 0);
    __syncthreads();
    const int nt = KB >> 6;
    for (int t = 0; t < nt; ++t) {
        if (t + 1 < nt) stage((t + 1) & 1, (t + 1) << 6);
        int b = t & 1;
        short8 af[2][4], bf[2][4];
        #pragma unroll
        for (int kk = 0; kk < 2; ++kk) {
            #pragma unroll
            for (int mi = 0; mi < 4; ++mi) {
                int row = wr * 64 + mi * 16 + l15;
                af[kk][mi] = *reinterpret_cast<const short8*>(
                    &SH[b][row * 64 + (((kk * 4 + l4) ^ (row & 7)) << 3)]);
            }
            #pragma unroll
            for (int ni = 0; ni < 4; ++ni) {
                int row = wc * 64 + ni * 16 + l15;
                bf[kk][ni] = *reinterpret_cast<const short8*>(
                    &SH[2 + b][row * 64 + (((kk * 4 + l4) ^ (row & 7)) << 3)]);
            }
        }
        #pragma unroll
        for (int kk = 0; kk < 2; ++kk)
            #pragma unroll
            for (int mi = 0; mi < 4; ++mi)
                #pragma unroll
                for (int ni = 0; ni < 4; ++ni)
                    acc[mi][ni] = __builtin_amdgcn_mfma_f32_16x16x32_bf16(
                        af[kk][mi], bf[kk][ni], acc[mi][ni], 0, 0, 0);
        __syncthreads();
    }

    float csum[4] = {0.f, 0.f, 0.f, 0.f}, csq[4] = {0.f, 0.f, 0.f, 0.f};
    unsigned short* LB = (unsigned short*)SH;
    float* LF = (float*)SH;
    #pragma unroll
    for (int mi = 0; mi < 4; ++mi) {
        int lrow0 = wr * 64 + mi * 16 + l4 * 4;
        #pragma unroll
        for (int ni = 0; ni < 4; ++ni) {
            int lcol = wc * 64 + ni * 16 + l15;
            int col = n0 + lcol;
            float badd = 0.f;
            if (bias1) badd += bias1[col];
            if (bias2) badd += bias2[col];
            f32x4 v = acc[mi][ni];
            #pragma unroll
            for (int i = 0; i < 4; ++i) {
                float o = v[i] + badd;
                if (STATS && (m0 + lrow0 + i) < M) { csum[ni] += o; csq[ni] += o * o; }
                if (OUTBF) LB[(lrow0 + i) * 128 + lcol] = f2bf(o);
                else LF[(lrow0 + i) * 128 + lcol] = o;
            }
        }
    }
    if (STATS) {
        #pragma unroll
        for (int ni = 0; ni < 4; ++ni) {
            float s = csum[ni], q = csq[ni];
            s += __shfl_xor(s, 16, 64); q += __shfl_xor(q, 16, 64);
            s += __shfl_xor(s, 32, 64); q += __shfl_xor(q, 32, 64);
            if (l4 == 0) {
                int col = n0 + wc * 64 + ni * 16 + l15;
                atomicAdd(&stats[col], s);
                atomicAdd(&stats[256 + col], q);
            }
        }
    }
    __syncthreads();
    if (OUTBF) {
        unsigned short* Cb = (unsigned short*)Cv;
        #pragma unroll
        for (int it = 0; it < 8; ++it) {
            int lin = (it * 256 + tid) * 8;
            int r = lin >> 7, c0 = lin & 127;
            int gr = m0 + r;
            if (gr < M)
                *reinterpret_cast<short8*>(&Cb[(size_t)gr * N + n0 + c0]) =
                    *reinterpret_cast<const short8*>(&LB[lin]);
        }
    } else {
        float* Cf = (float*)Cv;
        #pragma unroll
        for (int it = 0; it < 16; ++it) {
            int lin = (it * 256 + tid) * 4;
            int r = lin >> 7, c0 = lin & 127;
            int gr = m0 + r;
            if (gr < M)
                *reinterpret_cast<float4*>(&Cf[(size_t)gr * N + n0 + c0]) =
                    *reinterpret_cast<const float4*>(&LF[lin]);
        }
    }
}

// ---------------- layer-1 aggregate with precomputed edge weights (wave per dst) ----------------
// writes Agg1[d][512] (head-major 128/head); skip operand handled by split-A GEMM.
__global__ __launch_bounds__(256) void fused_agg1(const unsigned short* __restrict__ xb,
                                                  const float4* __restrict__ wbuf,
                                                  const int* __restrict__ srcs,
                                                  const int* __restrict__ offs,
                                                  unsigned short* __restrict__ Agg, int Ndst) {
    int d = blockIdx.x * 4 + (threadIdx.x >> 6);
    if (d >= Ndst) return;
    int lane = threadIdx.x & 63;
    int beg = offs[d], end = offs[d + 1];
    float ac[4][2] = {};
    float se0 = 0.f, se1 = 0.f, se2 = 0.f, se3 = 0.f;

    auto edge = [&](int i) {
        int s = srcs[i];
        float4 w = wbuf[i];
        unsigned xv = *reinterpret_cast<const unsigned*>(&xb[(size_t)s * 128 + lane * 2]);
        se0 += w.x; se1 += w.y; se2 += w.z; se3 += w.w;
        float fx = b2f((unsigned short)(xv & 0xffff));
        float fy = b2f((unsigned short)(xv >> 16));
        ac[0][0] = fmaf(w.x, fx, ac[0][0]); ac[0][1] = fmaf(w.x, fy, ac[0][1]);
        ac[1][0] = fmaf(w.y, fx, ac[1][0]); ac[1][1] = fmaf(w.y, fy, ac[1][1]);
        ac[2][0] = fmaf(w.z, fx, ac[2][0]); ac[2][1] = fmaf(w.z, fy, ac[2][1]);
        ac[3][0] = fmaf(w.w, fx, ac[3][0]); ac[3][1] = fmaf(w.w, fy, ac[3][1]);
    };
    int i = beg;
    for (; i + 4 <= end; i += 4) { edge(i); edge(i + 1); edge(i + 2); edge(i + 3); }
    for (; i < end; ++i) edge(i);

    float inv0 = 1.f / (se0 + 1e-16f), inv1 = 1.f / (se1 + 1e-16f);
    float inv2 = 1.f / (se2 + 1e-16f), inv3 = 1.f / (se3 + 1e-16f);
    unsigned short* row = Agg + (size_t)d * 512;
    ushort2 o;
    o.x = f2bf(ac[0][0] * inv0); o.y = f2bf(ac[0][1] * inv0);
    *reinterpret_cast<ushort2*>(&row[0 * 128 + lane * 2]) = o;
    o.x = f2bf(ac[1][0] * inv1); o.y = f2bf(ac[1][1] * inv1);
    *reinterpret_cast<ushort2*>(&row[1 * 128 + lane * 2]) = o;
    o.x = f2bf(ac[2][0] * inv2); o.y = f2bf(ac[2][1] * inv2);
    *reinterpret_cast<ushort2*>(&row[2 * 128 + lane * 2]) = o;
    o.x = f2bf(ac[3][0] * inv3); o.y = f2bf(ac[3][1] * inv3);
    *reinterpret_cast<ushort2*>(&row[3 * 128 + lane * 2]) = o;
}

// ---------------- layer-2 aggregate (256 ch, lane=4ch); writes Agg2[d][1024] ----------------
__global__ __launch_bounds__(256) void fused_agg2(const unsigned short* __restrict__ hb,
                                                  const float4* __restrict__ wbuf,
                                                  const int* __restrict__ srcs,
                                                  const int* __restrict__ offs,
                                                  unsigned short* __restrict__ Agg, int Ndst) {
    int d = blockIdx.x * 4 + (threadIdx.x >> 6);
    if (d >= Ndst) return;
    int lane = threadIdx.x & 63;
    int beg = offs[d], end = offs[d + 1];
    float ac[4][4] = {};
    float se0 = 0.f, se1 = 0.f, se2 = 0.f, se3 = 0.f;

    auto edge = [&](int i) {
        int s = srcs[i];
        float4 w = wbuf[i];
        ushort4 xv = *reinterpret_cast<const ushort4*>(&hb[(size_t)s * 256 + lane * 4]);
        se0 += w.x; se1 += w.y; se2 += w.z; se3 += w.w;
        float f0 = b2f(xv.x), f1 = b2f(xv.y), f2 = b2f(xv.z), f3 = b2f(xv.w);
        ac[0][0] = fmaf(w.x, f0, ac[0][0]); ac[0][1] = fmaf(w.x, f1, ac[0][1]);
        ac[0][2] = fmaf(w.x, f2, ac[0][2]); ac[0][3] = fmaf(w.x, f3, ac[0][3]);
        ac[1][0] = fmaf(w.y, f0, ac[1][0]); ac[1][1] = fmaf(w.y, f1, ac[1][1]);
        ac[1][2] = fmaf(w.y, f2, ac[1][2]); ac[1][3] = fmaf(w.y, f3, ac[1][3]);
        ac[2][0] = fmaf(w.z, f0, ac[2][0]); ac[2][1] = fmaf(w.z, f1, ac[2][1]);
        ac[2][2] = fmaf(w.z, f2, ac[2][2]); ac[2][3] = fmaf(w.z, f3, ac[2][3]);
        ac[3][0] = fmaf(w.w, f0, ac[3][0]); ac[3][1] = fmaf(w.w, f1, ac[3][1]);
        ac[3][2] = fmaf(w.w, f2, ac[3][2]); ac[3][3] = fmaf(w.w, f3, ac[3][3]);
    };
    int i = beg;
    for (; i + 2 <= end; i += 2) { edge(i); edge(i + 1); }
    for (; i < end; ++i) edge(i);

    float inv[4] = {1.f / (se0 + 1e-16f), 1.f / (se1 + 1e-16f),
                    1.f / (se2 + 1e-16f), 1.f / (se3 + 1e-16f)};
    unsigned short* row = Agg + (size_t)d * 1024;
    #pragma unroll
    for (int h = 0; h < 4; ++h) {
        ushort4 o;
        o.x = f2bf(ac[h][0] * inv[h]); o.y = f2bf(ac[h][1] * inv[h]);
        o.z = f2bf(ac[h][2] * inv[h]); o.w = f2bf(ac[h][3] * inv[h]);
        *reinterpret_cast<ushort4*>(&row[h * 256 + lane * 4]) = o;
    }
}

// ---------------- BN apply per row (f32 in) ----------------
template <int ACT, bool OUTBF>
__global__ __launch_bounds__(256) void bn_rows(const float* __restrict__ X,
                                               const float* __restrict__ stats,
                                               const float* __restrict__ gamma,
                                               const float* __restrict__ beta,
                                               void* __restrict__ out, int M) {
    int wid = threadIdx.x >> 6, lane = threadIdx.x & 63;
    int nw = gridDim.x * 4;
    float4 s4 = *reinterpret_cast<const float4*>(&stats[lane * 4]);
    float4 q4 = *reinterpret_cast<const float4*>(&stats[256 + lane * 4]);
    float4 g4 = *reinterpret_cast<const float4*>(&gamma[lane * 4]);
    float4 b4 = *reinterpret_cast<const float4*>(&beta[lane * 4]);
    float invM = 1.f / (float)M;
    float mu[4] = {s4.x * invM, s4.y * invM, s4.z * invM, s4.w * invM};
    float sc[4], sh_[4] = {b4.x, b4.y, b4.z, b4.w};
    {
        float g[4] = {g4.x, g4.y, g4.z, g4.w};
        float q[4] = {q4.x, q4.y, q4.z, q4.w};
        #pragma unroll
        for (int c = 0; c < 4; ++c) {
            float var = q[c] * invM - mu[c] * mu[c];
            sc[c] = rsqrtf(var + kEPS) * g[c];
        }
    }
    for (int row = blockIdx.x * 4 + wid; row < M; row += nw) {
        float4 xv = *reinterpret_cast<const float4*>(&X[(size_t)row * 256 + lane * 4]);
        float v[4] = {xv.x, xv.y, xv.z, xv.w};
        #pragma unroll
        for (int c = 0; c < 4; ++c) {
            float t = (v[c] - mu[c]) * sc[c] + sh_[c];
            if (ACT == 0) t = t > 0.f ? t : expm1f(t);
            else t = fmaxf(t, 0.f);
            v[c] = t;
        }
        if (OUTBF) {
            ushort4 o; o.x = f2bf(v[0]); o.y = f2bf(v[1]); o.z = f2bf(v[2]); o.w = f2bf(v[3]);
            *reinterpret_cast<ushort4*>(&((unsigned short*)out)[(size_t)row * 256 + lane * 4]) = o;
        } else {
            *reinterpret_cast<float4*>(&((float*)out)[(size_t)row * 256 + lane * 4]) =
                make_float4(v[0], v[1], v[2], v[3]);
        }
    }
}

// ---------------- fp32 tiled GEMM (final N=47 head) ----------------
template <bool ACCUM>
__global__ __launch_bounds__(256) void gemm64(const float* __restrict__ A,
                                              const float* __restrict__ B,
                                              float* __restrict__ Cmat,
                                              const float* __restrict__ bias1,
                                              const float* __restrict__ bias2,
                                              int M, int N, int K) {
    __shared__ float As[32][68];
    __shared__ float Bs[32][68];
    const int tid = threadIdx.x;
    const int tx = tid & 15, ty = tid >> 4;
    const int m0 = blockIdx.y * 64, n0 = blockIdx.x * 64;
    float acc[4][4] = {};

    for (int k0 = 0; k0 < K; k0 += 32) {
        #pragma unroll
        for (int t = 0; t < 2; ++t) {
            int i = tid + t * 256;
            int row = i >> 3;
            int kq = (i & 7) << 2;
            float4 v = make_float4(0.f, 0.f, 0.f, 0.f);
            int gr = m0 + row;
            if (gr < M) v = *reinterpret_cast<const float4*>(&A[(size_t)gr * K + k0 + kq]);
            As[kq + 0][row] = v.x; As[kq + 1][row] = v.y;
            As[kq + 2][row] = v.z; As[kq + 3][row] = v.w;
        }
        #pragma unroll
        for (int t = 0; t < 2; ++t) {
            int i = tid + t * 256;
            int kr = i >> 4;
            int cq = (i & 15) << 2;
            #pragma unroll
            for (int j = 0; j < 4; ++j) {
                int gc = n0 + cq + j;
                Bs[kr][cq + j] = (gc < N) ? B[(size_t)(k0 + kr) * N + gc] : 0.f;
            }
        }
        __syncthreads();
        #pragma unroll
        for (int kk = 0; kk < 32; ++kk) {
            float4 a4 = *reinterpret_cast<const float4*>(&As[kk][ty << 2]);
            float4 b4 = *reinterpret_cast<const float4*>(&Bs[kk][tx << 2]);
            float a[4] = {a4.x, a4.y, a4.z, a4.w};
            float b[4] = {b4.x, b4.y, b4.z, b4.w};
            #pragma unroll
            for (int i2 = 0; i2 < 4; ++i2)
                #pragma unroll
                for (int j = 0; j < 4; ++j)
                    acc[i2][j] = fmaf(a[i2], b[j], acc[i2][j]);
        }
        __syncthreads();
    }

    #pragma unroll
    for (int i2 = 0; i2 < 4; ++i2) {
        int row = m0 + (ty << 2) + i2;
        if (row >= M) continue;
        #pragma unroll
        for (int j = 0; j < 4; ++j) {
            int col = n0 + (tx << 2) + j;
            if (col >= N) continue;
            float v = acc[i2][j];
            if (bias1) v += bias1[col];
            if (bias2) v += bias2[col];
            size_t idx = (size_t)row * N + col;
            if (ACCUM) v += Cmat[idx];
            Cmat[idx] = v;
        }
    }
}

extern "C" void kernel_launch(void* const* d_in, const int* in_sizes, int n_in,
                              void* d_out, int out_size, void* d_ws, size_t ws_size,
                              hipStream_t stream) {
    (void)in_sizes; (void)n_in; (void)out_size; (void)ws_size;

    const float* x      = (const float*)d_in[0];
    const int*   src1   = (const int*)d_in[1];
    const int*   dst1   = (const int*)d_in[2];
    const int*   src2   = (const int*)d_in[3];
    const int*   dst2   = (const int*)d_in[4];
    const float* W1     = (const float*)d_in[5];
    const float* a_src1 = (const float*)d_in[6];
    const float* a_dst1 = (const float*)d_in[7];
    const float* b1     = (const float*)d_in[8];
    const float* Wsk1   = (const float*)d_in[9];
    const float* bsk1   = (const float*)d_in[10];
    const float* g1     = (const float*)d_in[11];
    const float* be1    = (const float*)d_in[12];
    const float* W2     = (const float*)d_in[13];
    const float* a_src2 = (const float*)d_in[14];
    const float* a_dst2 = (const float*)d_in[15];
    const float* b2     = (const float*)d_in[16];
    const float* Wsk2   = (const float*)d_in[17];
    const float* bsk2   = (const float*)d_in[18];
    const float* g2     = (const float*)d_in[19];
    const float* be2    = (const float*)d_in[20];
    const float* Wm1    = (const float*)d_in[21];
    const float* bm1    = (const float*)d_in[22];
    const float* gm     = (const float*)d_in[23];
    const float* bem    = (const float*)d_in[24];
    const float* Wm2    = (const float*)d_in[25];
    const float* bm2    = (const float*)d_in[26];

    // ---- workspace layout (float units; all chunks 16B-aligned) ----
    float* ws = (float*)d_ws;
    size_t off = 0;
    auto alloc = [&](size_t n) { float* p = ws + off; off += n; return p; };
    unsigned short* xb    = (unsigned short*)alloc((size_t)kN0 * 128 / 2);   // bf16 x
    unsigned short* Agg1  = (unsigned short*)alloc((size_t)kN1 * 512 / 2);   // [N1][512] bf16
    unsigned short* Agg2  = (unsigned short*)alloc((size_t)kN2 * 1024 / 2);  // [N2][1024] bf16
    unsigned short* h1pre = (unsigned short*)alloc((size_t)kN1 * 256 / 2);   // pre-BN L1 (bf16)
    unsigned short* h1b   = (unsigned short*)alloc((size_t)kN1 * 256 / 2);
    float* h2             = alloc((size_t)kN2 * 256);
    unsigned short* h2b   = (unsigned short*)alloc((size_t)kN2 * 256 / 2);
    float* h3             = alloc((size_t)kN2 * 256);
    unsigned short* Wcat1t = (unsigned short*)alloc(256 * 640 / 2);
    unsigned short* Wcat2t = (unsigned short*)alloc(256 * 1280 / 2);
    unsigned short* Wm1t   = (unsigned short*)alloc(256 * 256 / 2);
    unsigned short* v1t    = (unsigned short*)alloc(16 * 128 / 2);
    unsigned short* v2t    = (unsigned short*)alloc(16 * 256 / 2);
    float4* w1buf = (float4*)alloc((size_t)kE1 * 4);
    float4* w2buf = (float4*)alloc((size_t)kE2 * 4);
    float* als1 = alloc((size_t)kN0 * 4);
    float* ald1 = alloc((size_t)kN1 * 4);
    float* als2 = alloc((size_t)kN1 * 4);
    float* ald2 = alloc((size_t)kN2 * 4);
    float* zreg = alloc(1536 + kN1 + kN1 + kN2 + kN2);
    float* stats1 = zreg, *stats2 = zreg + 512, *stats3 = zreg + 1024;
    int* cnt1 = (int*)(zreg + 1536);
    int* cur1 = cnt1 + kN1;
    int* cnt2 = cur1 + kN1;
    int* cur2 = cnt2 + kN2;
    const int nzreg = 1536 + 2 * kN1 + 2 * kN2;
    int* srcs1  = (int*)alloc(kE1);
    int* offs1  = (int*)alloc(kN1 + 4);
    int* bsum1  = (int*)alloc(128);
    int* bscan1 = (int*)alloc(128);
    int* srcs2  = (int*)alloc(kE2);
    int* offs2  = (int*)alloc(kN2 + 4);
    int* bsum2  = (int*)alloc(128);
    int* bscan2 = (int*)alloc(128);

    hipStream_t st = stream;
    const int nb1 = (kN1 + 1023) / 1024;   // 98
    const int nb2 = (kN2 + 1023) / 1024;   // 20

    // ---- precomputes + init ----
    prep_weights<<<(563200 + 255) / 256, 256, 0, st>>>(W1, a_src1, a_dst1, W2, a_src2, a_dst2,
                                                       Wsk1, Wsk2, Wm1,
                                                       v1t, v2t, Wcat1t, Wcat2t, Wm1t);
    zero_f32<<<512, 256, 0, st>>>(zreg, nzreg);

    // ---- x -> bf16 + layer-1 attention dots (MFMA-fused) ----
    conv_als_mfma<<<2048, 256, 0, st>>>(x, v1t, xb, als1, ald1);

    // ---- CSR builds (merged) ----
    hist_both<<<(kE1 + kE2 + 255) / 256, 256, 0, st>>>(dst1, cnt1, kE1, dst2, cnt2, kE2);
    scan_block_both<<<nb1 + nb2, 256, 0, st>>>(cnt1, kN1, offs1, bsum1, nb1, cnt2, kN2, offs2, bsum2);
    scan_bsums_both<<<1, 256, 0, st>>>(bsum1, bscan1, nb1, bsum2, bscan2, nb2);
    scan_add_both<<<(kN1 + kN2 + 255) / 256, 256, 0, st>>>(offs1, bscan1, cnt1, kN1,
                                                           offs2, bscan2, cnt2, kN2);
    csr_scatter_w<<<(kE1 + 255) / 256, 256, 0, st>>>(dst1, src1, offs1, als1, ald1,
                                                     cur1, srcs1, w1buf, kE1);

    // ================= layer 1 =================
    fused_agg1<<<(kN1 + 3) / 4, 256, 0, st>>>(xb, w1buf, srcs1, offs1, Agg1, kN1);
    gemm_pipe<true, true><<<dim3(2, (kN1 + 127) / 128), 256, 0, st>>>(
        Agg1, 512, xb, 128, Wcat1t, h1pre, b1, bsk1, stats1, kN1, 256);
    bn_mfma<<<1024, 256, 0, st>>>(h1pre, stats1, g1, be1, h1b, v2t, als2, ald2, kN1, kN2);

    // ================= layer 2 =================
    csr_scatter_w<<<(kE2 + 255) / 256, 256, 0, st>>>(dst2, src2, offs2, als2, ald2,
                                                     cur2, srcs2, w2buf, kE2);
    fused_agg2<<<(kN2 + 3) / 4, 256, 0, st>>>(h1b, w2buf, srcs2, offs2, Agg2, kN2);
    gemm_pipe<false, true><<<dim3(2, (kN2 + 127) / 128), 256, 0, st>>>(
        Agg2, 1024, h1b, 256, Wcat2t, h2, b2, bsk2, stats2, kN2, 256);
    bn_rows<0, true><<<2048, 256, 0, st>>>(h2, stats2, g2, be2, h2b, kN2);

    // ================= MLP head =================
    gemm_pipe<false, true><<<dim3(2, (kN2 + 127) / 128), 256, 0, st>>>(
        h2b, 256, nullptr, 0, Wm1t, h3, bm1, nullptr, stats3, kN2, 256);
    bn_rows<1, false><<<2048, 256, 0, st>>>(h3, stats3, gm, bem, h3, kN2);
    gemm64<false><<<dim3(1, (kN2 + 63) / 64), 256, 0, st>>>(
        h3, Wm2, (float*)d_out, bm2, nullptr, kN2, kOUT, 256);
}

// Round 11
// 568.708 us; speedup vs baseline: 1.5995x; 1.0409x over previous
//
#include <hip/hip_runtime.h>
#include <math.h>

// Problem constants (fixed by the reference)
constexpr int kN0 = 400000, kN1 = 100000, kN2 = 20000;
constexpr int kE1 = 1000000, kE2 = 200000;
constexpr int kIN = 128, kHID = 256, kOUT = 47;
constexpr float kEPS = 1e-5f, kNEG = 0.2f;

#define DEV static __device__ __forceinline__

typedef __attribute__((ext_vector_type(8))) short short8;
typedef __attribute__((ext_vector_type(4))) float f32x4;

DEV float b2f(unsigned short u) { return __uint_as_float(((unsigned)u) << 16); }
DEV unsigned short f2bf(float f) {
    unsigned u = __float_as_uint(f);
    unsigned r = (u + 0x7fffu + ((u >> 16) & 1u)) >> 16;   // RNE
    return (unsigned short)r;
}
DEV float lrelu(float v) { return v > 0.f ? v : kNEG * v; }

DEV void gload_lds16(const void* g, void* l) {
    __builtin_amdgcn_global_load_lds(
        (const __attribute__((address_space(1))) void*)g,
        (__attribute__((address_space(3))) void*)l, 16, 0, 0);
}

// ---------------- utility ----------------
__global__ void zero_f32(float* __restrict__ p, int n) {
    int i = blockIdx.x * blockDim.x + threadIdx.x;
    int st = gridDim.x * blockDim.x;
    for (; i < n; i += st) p[i] = 0.f;
}

// ---- merged weight precompute: v1t, v2t, Wcat1t, Wcat2t, Wm1t in one launch ----
__global__ void prep_weights(const float* __restrict__ W1, const float* __restrict__ as1,
                             const float* __restrict__ ad1,
                             const float* __restrict__ W2, const float* __restrict__ as2,
                             const float* __restrict__ ad2,
                             const float* __restrict__ Wsk1, const float* __restrict__ Wsk2,
                             const float* __restrict__ Wm1,
                             unsigned short* __restrict__ v1t, unsigned short* __restrict__ v2t,
                             unsigned short* __restrict__ Wcat1t,
                             unsigned short* __restrict__ Wcat2t,
                             unsigned short* __restrict__ Wm1t) {
    int i = blockIdx.x * blockDim.x + threadIdx.x;
    if (i < 2048) {                       // v1t[16][128]
        int j = i >> 7, k = i & 127;
        float s = 0.f;
        if (j < 8) {
            int h = j & 3;
            const float* a = (j >= 4) ? ad1 : as1;
            for (int c = 0; c < 64; ++c) s += W1[(size_t)k * 256 + h * 64 + c] * a[h * 64 + c];
        }
        v1t[i] = f2bf(s);
        return;
    }
    i -= 2048;
    if (i < 4096) {                       // v2t[16][256]
        int j = i >> 8, k = i & 255;
        float s = 0.f;
        if (j < 8) {
            int h = j & 3;
            const float* a = (j >= 4) ? ad2 : as2;
            for (int c = 0; c < 64; ++c) s += W2[(size_t)k * 256 + h * 64 + c] * a[h * 64 + c];
        }
        v2t[i] = f2bf(s);
        return;
    }
    i -= 4096;
    if (i < 163840) {                     // Wcat1t[256][640]
        int n = i / 640, k = i % 640;
        float v;
        if (k < 512) { int h = k >> 7, kin = k & 127; v = ((n >> 6) == h) ? W1[(size_t)kin * 256 + n] : 0.f; }
        else v = Wsk1[(size_t)(k - 512) * 256 + n];
        Wcat1t[i] = f2bf(v);
        return;
    }
    i -= 163840;
    if (i < 327680) {                     // Wcat2t[256][1280]
        int n = i / 1280, k = i % 1280;
        float v;
        if (k < 1024) { int h = k >> 8, kin = k & 255; v = ((n >> 6) == h) ? W2[(size_t)kin * 256 + n] : 0.f; }
        else v = Wsk2[(size_t)(k - 1024) * 256 + n];
        Wcat2t[i] = f2bf(v);
        return;
    }
    i -= 327680;
    if (i < 65536) {                      // Wm1t[256][256]
        int n = i >> 8, k = i & 255;
        Wm1t[i] = f2bf(Wm1[(size_t)k * 256 + n]);
    }
}

// ---- fused x->bf16 convert + layer-1 attention dots via MFMA (wave per 16 nodes) ----
__global__ __launch_bounds__(256) void conv_als_mfma(const float* __restrict__ x,
                                                     const unsigned short* __restrict__ v1t,
                                                     unsigned short* __restrict__ xb,
                                                     float* __restrict__ als,
                                                     float* __restrict__ ald) {
    int wid = threadIdx.x >> 6, lane = threadIdx.x & 63;
    int l15 = lane & 15, l4 = lane >> 4;
    short8 bfr[4];
    #pragma unroll
    for (int ks = 0; ks < 4; ++ks)
        bfr[ks] = *reinterpret_cast<const short8*>(&v1t[l15 * 128 + ks * 32 + l4 * 8]);

    const int ntile = kN0 / 16;
    int nw = gridDim.x * 4;
    for (int t = blockIdx.x * 4 + wid; t < ntile; t += nw) {
        int base = t * 16;
        int r = base + l15;
        f32x4 acc = (f32x4){0.f, 0.f, 0.f, 0.f};
        #pragma unroll
        for (int ks = 0; ks < 4; ++ks) {
            size_t o = (size_t)r * 128 + ks * 32 + l4 * 8;
            float4 xa = *reinterpret_cast<const float4*>(&x[o]);
            float4 xc = *reinterpret_cast<const float4*>(&x[o + 4]);
            short8 af;
            af[0] = (short)f2bf(xa.x); af[1] = (short)f2bf(xa.y);
            af[2] = (short)f2bf(xa.z); af[3] = (short)f2bf(xa.w);
            af[4] = (short)f2bf(xc.x); af[5] = (short)f2bf(xc.y);
            af[6] = (short)f2bf(xc.z); af[7] = (short)f2bf(xc.w);
            *reinterpret_cast<short8*>(&xb[o]) = af;
            acc = __builtin_amdgcn_mfma_f32_16x16x32_bf16(af, bfr[ks], acc, 0, 0, 0);
        }
        if (l15 < 8) {
            #pragma unroll
            for (int i = 0; i < 4; ++i) {
                int node = base + l4 * 4 + i;
                if (l15 < 4) als[(size_t)node * 4 + l15] = acc[i];
                else if (node < kN1) ald[(size_t)node * 4 + (l15 - 4)] = acc[i];
            }
        }
    }
}

// ---- fused BN(ELU) bf16->bf16 + layer-2 attention dots via MFMA (wave per 16 rows) ----
__global__ __launch_bounds__(256) void bn_mfma(const unsigned short* __restrict__ X,
                                               const float* __restrict__ stats,
                                               const float* __restrict__ gamma,
                                               const float* __restrict__ beta,
                                               unsigned short* __restrict__ outb,
                                               const unsigned short* __restrict__ v2t,
                                               float* __restrict__ als,
                                               float* __restrict__ ald,
                                               int M, int Ndst) {
    __shared__ float smu[256], ssc[256], ssh[256];
    {
        int c = threadIdx.x;
        float invM = 1.f / (float)M;
        float mu = stats[c] * invM;
        float var = stats[256 + c] * invM - mu * mu;
        smu[c] = mu;
        ssc[c] = rsqrtf(var + kEPS) * gamma[c];
        ssh[c] = beta[c];
    }
    __syncthreads();

    int wid = threadIdx.x >> 6, lane = threadIdx.x & 63;
    int l15 = lane & 15, l4 = lane >> 4;
    short8 bfr[8];
    #pragma unroll
    for (int ks = 0; ks < 8; ++ks)
        bfr[ks] = *reinterpret_cast<const short8*>(&v2t[l15 * 256 + ks * 32 + l4 * 8]);

    const int ntile = M / 16;
    int nw = gridDim.x * 4;
    for (int t = blockIdx.x * 4 + wid; t < ntile; t += nw) {
        int base = t * 16;
        int r = base + l15;
        f32x4 acc = (f32x4){0.f, 0.f, 0.f, 0.f};
        #pragma unroll
        for (int ks = 0; ks < 8; ++ks) {
            int c0 = ks * 32 + l4 * 8;
            size_t o = (size_t)r * 256 + c0;
            short8 xr = *reinterpret_cast<const short8*>(&X[o]);
            float4 mua = *reinterpret_cast<const float4*>(&smu[c0]);
            float4 muc = *reinterpret_cast<const float4*>(&smu[c0 + 4]);
            float4 sca = *reinterpret_cast<const float4*>(&ssc[c0]);
            float4 scc = *reinterpret_cast<const float4*>(&ssc[c0 + 4]);
            float4 sha = *reinterpret_cast<const float4*>(&ssh[c0]);
            float4 shc = *reinterpret_cast<const float4*>(&ssh[c0 + 4]);
            float v[8];
            v[0] = (b2f((unsigned short)xr[0]) - mua.x) * sca.x + sha.x;
            v[1] = (b2f((unsigned short)xr[1]) - mua.y) * sca.y + sha.y;
            v[2] = (b2f((unsigned short)xr[2]) - mua.z) * sca.z + sha.z;
            v[3] = (b2f((unsigned short)xr[3]) - mua.w) * sca.w + sha.w;
            v[4] = (b2f((unsigned short)xr[4]) - muc.x) * scc.x + shc.x;
            v[5] = (b2f((unsigned short)xr[5]) - muc.y) * scc.y + shc.y;
            v[6] = (b2f((unsigned short)xr[6]) - muc.z) * scc.z + shc.z;
            v[7] = (b2f((unsigned short)xr[7]) - muc.w) * scc.w + shc.w;
            short8 af;
            #pragma unroll
            for (int i = 0; i < 8; ++i) {
                float tv = v[i] > 0.f ? v[i] : expm1f(v[i]);
                af[i] = (short)f2bf(tv);
            }
            *reinterpret_cast<short8*>(&outb[o]) = af;
            acc = __builtin_amdgcn_mfma_f32_16x16x32_bf16(af, bfr[ks], acc, 0, 0, 0);
        }
        if (l15 < 8) {
            #pragma unroll
            for (int i = 0; i < 4; ++i) {
                int node = base + l4 * 4 + i;
                if (l15 < 4) als[(size_t)node * 4 + l15] = acc[i];
                else if (node < Ndst) ald[(size_t)node * 4 + (l15 - 4)] = acc[i];
            }
        }
    }
}

// ================= CSR build (merged both layers) =================
__global__ void hist_both(const int* __restrict__ dst1, int* __restrict__ cnt1, int E1,
                          const int* __restrict__ dst2, int* __restrict__ cnt2, int E2) {
    int e = blockIdx.x * blockDim.x + threadIdx.x;
    if (e < E1) atomicAdd(&cnt1[dst1[e]], 1);
    else if (e - E1 < E2) atomicAdd(&cnt2[dst2[e - E1]], 1);
}

__global__ __launch_bounds__(256) void scan_block_both(const int* __restrict__ cnt1, int n1,
                                                       int* __restrict__ offs1, int* __restrict__ bsum1, int nb1,
                                                       const int* __restrict__ cnt2, int n2,
                                                       int* __restrict__ offs2, int* __restrict__ bsum2) {
    const int* counts; int n; int* offs; int* bsum; int b;
    if ((int)blockIdx.x < nb1) { counts = cnt1; n = n1; offs = offs1; bsum = bsum1; b = blockIdx.x; }
    else { counts = cnt2; n = n2; offs = offs2; bsum = bsum2; b = blockIdx.x - nb1; }
    __shared__ int sh[256];
    int tid = threadIdx.x;
    int base = b * 1024 + tid * 4;
    int c0 = (base + 0 < n) ? counts[base + 0] : 0;
    int c1 = (base + 1 < n) ? counts[base + 1] : 0;
    int c2 = (base + 2 < n) ? counts[base + 2] : 0;
    int c3 = (base + 3 < n) ? counts[base + 3] : 0;
    int tot = c0 + c1 + c2 + c3;
    sh[tid] = tot;
    __syncthreads();
    for (int o = 1; o < 256; o <<= 1) {
        int t = (tid >= o) ? sh[tid - o] : 0;
        __syncthreads();
        sh[tid] += t;
        __syncthreads();
    }
    int excl = sh[tid] - tot;
    if (base + 0 < n) offs[base + 0] = excl;
    if (base + 1 < n) offs[base + 1] = excl + c0;
    if (base + 2 < n) offs[base + 2] = excl + c0 + c1;
    if (base + 3 < n) offs[base + 3] = excl + c0 + c1 + c2;
    if (tid == 255) bsum[b] = sh[255];
}

__global__ __launch_bounds__(256) void scan_bsums_both(const int* __restrict__ bsum1,
                                                       int* __restrict__ bscan1, int nb1,
                                                       const int* __restrict__ bsum2,
                                                       int* __restrict__ bscan2, int nb2) {
    __shared__ int sh[256];
    int tid = threadIdx.x;
    int v = (tid < nb1) ? bsum1[tid] : 0;
    sh[tid] = v;
    __syncthreads();
    for (int o = 1; o < 256; o <<= 1) {
        int t = (tid >= o) ? sh[tid - o] : 0;
        __syncthreads();
        sh[tid] += t;
        __syncthreads();
    }
    if (tid < nb1) bscan1[tid] = sh[tid] - v;
    __syncthreads();
    int v2 = (tid < nb2) ? bsum2[tid] : 0;
    sh[tid] = v2;
    __syncthreads();
    for (int o = 1; o < 256; o <<= 1) {
        int t = (tid >= o) ? sh[tid - o] : 0;
        __syncthreads();
        sh[tid] += t;
        __syncthreads();
    }
    if (tid < nb2) bscan2[tid] = sh[tid] - v2;
}

__global__ void scan_add_both(int* __restrict__ offs1, const int* __restrict__ bscan1,
                              const int* __restrict__ cnt1, int n1,
                              int* __restrict__ offs2, const int* __restrict__ bscan2,
                              const int* __restrict__ cnt2, int n2) {
    int i = blockIdx.x * blockDim.x + threadIdx.x;
    if (i < n1) {
        int v = offs1[i] + bscan1[i >> 10];
        offs1[i] = v;
        if (i == n1 - 1) offs1[n1] = v + cnt1[i];
    } else {
        int j = i - n1;
        if (j < n2) {
            int v = offs2[j] + bscan2[j >> 10];
            offs2[j] = v;
            if (j == n2 - 1) offs2[n2] = v + cnt2[j];
        }
    }
}

// scatter src id + per-edge softmax numerators w[h] = exp(lrelu(als[s]+ald[d]))
__global__ void csr_scatter_w(const int* __restrict__ dst, const int* __restrict__ src,
                              const int* __restrict__ offs,
                              const float* __restrict__ als, const float* __restrict__ ald,
                              int* __restrict__ cur, int* __restrict__ srcs,
                              float4* __restrict__ wbuf, int E) {
    int e = blockIdx.x * blockDim.x + threadIdx.x;
    if (e >= E) return;
    int d = dst[e], s = src[e];
    int pos = offs[d] + atomicAdd(&cur[d], 1);
    srcs[pos] = s;
    float4 a = *reinterpret_cast<const float4*>(&als[(size_t)s * 4]);
    float4 b = *reinterpret_cast<const float4*>(&ald[(size_t)d * 4]);
    float4 w;
    w.x = expf(lrelu(a.x + b.x));
    w.y = expf(lrelu(a.y + b.y));
    w.z = expf(lrelu(a.z + b.z));
    w.w = expf(lrelu(a.w + b.w));
    wbuf[pos] = w;
}

// ================= pipelined bf16 MFMA GEMM, split-A + per-colblock K-window =================
// C[M][N] = [A1|A2] @ Bt^T + biases. A1's useful K for output col-block n0 is the window
// [n0*rs, n0*rs + kwin)  (block-diagonal Wcat; rs=0 -> plain full-K1 window kwin=K1).
// A2 (skip operand, may be null/K2=0) always contributes its full K2.
template <bool OUTBF, bool STATS>
__global__ __launch_bounds__(256) void gemm_pipe(const unsigned short* __restrict__ A1, int K1,
                                                 const unsigned short* __restrict__ A2, int K2,
                                                 const unsigned short* __restrict__ Bt,
                                                 void* __restrict__ Cv,
                                                 const float* __restrict__ bias1,
                                                 const float* __restrict__ bias2,
                                                 float* __restrict__ stats,
                                                 int M, int N, int rs, int kwin) {
    __shared__ unsigned short SH[4][128 * 64];
    const int tid = threadIdx.x;
    const int wid = tid >> 6, lane = tid & 63;
    const int wr = wid >> 1, wc = wid & 1;
    const int l15 = lane & 15, l4 = lane >> 4;
    const int m0 = blockIdx.y * 128, n0 = blockIdx.x * 128;
    const int rsub = lane >> 3;
    const int kslot = (lane & 7) ^ rsub;
    const int KB = K1 + K2;
    const int nwin = kwin >> 6;
    const int nt = nwin + (K2 >> 6);
    const int wbase = n0 * rs;           // A1 K-window start for this col-block

    auto stage = [&](int buf, int t) {
        const unsigned short* Asrc; int ka, lda, gk;
        if (t < nwin) { gk = wbase + (t << 6); Asrc = A1; ka = gk; lda = K1; }
        else { int t2 = t - nwin; gk = K1 + (t2 << 6); Asrc = A2; ka = t2 << 6; lda = K2; }
        #pragma unroll
        for (int c = 0; c < 4; ++c) {
            int q = wid * 4 + c;
            int rowA = m0 + q * 8 + rsub; if (rowA > M - 1) rowA = M - 1;
            gload_lds16(Asrc + (size_t)rowA * lda + ka + kslot * 8, &SH[buf][q * 512]);
            int rowB = n0 + q * 8 + rsub;
            gload_lds16(Bt + (size_t)rowB * KB + gk + kslot * 8, &SH[2 + buf][q * 512]);
        }
    };

    f32x4 acc[4][4];
    #pragma unroll
    for (int i = 0; i < 4; ++i)
        #pragma unroll
        for (int j = 0; j < 4; ++j) acc[i][j] = (f32x4){0.f, 0.f, 0.f, 0.f};

    stage(0, 0);
    __syncthreads();
    for (int t = 0; t < nt; ++t) {
        if (t + 1 < nt) stage((t + 1) & 1, t + 1);
        int b = t & 1;
        short8 af[2][4], bf[2][4];
        #pragma unroll
        for (int kk = 0; kk < 2; ++kk) {
            #pragma unroll
            for (int mi = 0; mi < 4; ++mi) {
                int row = wr * 64 + mi * 16 + l15;
                af[kk][mi] = *reinterpret_cast<const short8*>(
                    &SH[b][row * 64 + (((kk * 4 + l4) ^ (row & 7)) << 3)]);
            }
            #pragma unroll
            for (int ni = 0; ni < 4; ++ni) {
                int row = wc * 64 + ni * 16 + l15;
                bf[kk][ni] = *reinterpret_cast<const short8*>(
                    &SH[2 + b][row * 64 + (((kk * 4 + l4) ^ (row & 7)) << 3)]);
            }
        }
        #pragma unroll
        for (int kk = 0; kk < 2; ++kk)
            #pragma unroll
            for (int mi = 0; mi < 4; ++mi)
                #pragma unroll
                for (int ni = 0; ni < 4; ++ni)
                    acc[mi][ni] = __builtin_amdgcn_mfma_f32_16x16x32_bf16(
                        af[kk][mi], bf[kk][ni], acc[mi][ni], 0, 0, 0);
        __syncthreads();
    }

    float csum[4] = {0.f, 0.f, 0.f, 0.f}, csq[4] = {0.f, 0.f, 0.f, 0.f};
    unsigned short* LB = (unsigned short*)SH;
    float* LF = (float*)SH;
    #pragma unroll
    for (int mi = 0; mi < 4; ++mi) {
        int lrow0 = wr * 64 + mi * 16 + l4 * 4;
        #pragma unroll
        for (int ni = 0; ni < 4; ++ni) {
            int lcol = wc * 64 + ni * 16 + l15;
            int col = n0 + lcol;
            float badd = 0.f;
            if (bias1) badd += bias1[col];
            if (bias2) badd += bias2[col];
            f32x4 v = acc[mi][ni];
            #pragma unroll
            for (int i = 0; i < 4; ++i) {
                float o = v[i] + badd;
                if (STATS && (m0 + lrow0 + i) < M) { csum[ni] += o; csq[ni] += o * o; }
                if (OUTBF) LB[(lrow0 + i) * 128 + lcol] = f2bf(o);
                else LF[(lrow0 + i) * 128 + lcol] = o;
            }
        }
    }
    if (STATS) {
        #pragma unroll
        for (int ni = 0; ni < 4; ++ni) {
            float s = csum[ni], q = csq[ni];
            s += __shfl_xor(s, 16, 64); q += __shfl_xor(q, 16, 64);
            s += __shfl_xor(s, 32, 64); q += __shfl_xor(q, 32, 64);
            if (l4 == 0) {
                int col = n0 + wc * 64 + ni * 16 + l15;
                atomicAdd(&stats[col], s);
                atomicAdd(&stats[256 + col], q);
            }
        }
    }
    __syncthreads();
    if (OUTBF) {
        unsigned short* Cb = (unsigned short*)Cv;
        #pragma unroll
        for (int it = 0; it < 8; ++it) {
            int lin = (it * 256 + tid) * 8;
            int r = lin >> 7, c0 = lin & 127;
            int gr = m0 + r;
            if (gr < M)
                *reinterpret_cast<short8*>(&Cb[(size_t)gr * N + n0 + c0]) =
                    *reinterpret_cast<const short8*>(&LB[lin]);
        }
    } else {
        float* Cf = (float*)Cv;
        #pragma unroll
        for (int it = 0; it < 16; ++it) {
            int lin = (it * 256 + tid) * 4;
            int r = lin >> 7, c0 = lin & 127;
            int gr = m0 + r;
            if (gr < M)
                *reinterpret_cast<float4*>(&Cf[(size_t)gr * N + n0 + c0]) =
                    *reinterpret_cast<const float4*>(&LF[lin]);
        }
    }
}

// ---------------- layer-1 aggregate with precomputed edge weights (wave per dst) ----------------
__global__ __launch_bounds__(256) void fused_agg1(const unsigned short* __restrict__ xb,
                                                  const float4* __restrict__ wbuf,
                                                  const int* __restrict__ srcs,
                                                  const int* __restrict__ offs,
                                                  unsigned short* __restrict__ Agg, int Ndst) {
    int d = blockIdx.x * 4 + (threadIdx.x >> 6);
    if (d >= Ndst) return;
    int lane = threadIdx.x & 63;
    int beg = offs[d], end = offs[d + 1];
    float ac[4][2] = {};
    float se0 = 0.f, se1 = 0.f, se2 = 0.f, se3 = 0.f;

    auto edge = [&](int i) {
        int s = srcs[i];
        float4 w = wbuf[i];
        unsigned xv = *reinterpret_cast<const unsigned*>(&xb[(size_t)s * 128 + lane * 2]);
        se0 += w.x; se1 += w.y; se2 += w.z; se3 += w.w;
        float fx = b2f((unsigned short)(xv & 0xffff));
        float fy = b2f((unsigned short)(xv >> 16));
        ac[0][0] = fmaf(w.x, fx, ac[0][0]); ac[0][1] = fmaf(w.x, fy, ac[0][1]);
        ac[1][0] = fmaf(w.y, fx, ac[1][0]); ac[1][1] = fmaf(w.y, fy, ac[1][1]);
        ac[2][0] = fmaf(w.z, fx, ac[2][0]); ac[2][1] = fmaf(w.z, fy, ac[2][1]);
        ac[3][0] = fmaf(w.w, fx, ac[3][0]); ac[3][1] = fmaf(w.w, fy, ac[3][1]);
    };
    int i = beg;
    for (; i + 4 <= end; i += 4) { edge(i); edge(i + 1); edge(i + 2); edge(i + 3); }
    for (; i < end; ++i) edge(i);

    float inv0 = 1.f / (se0 + 1e-16f), inv1 = 1.f / (se1 + 1e-16f);
    float inv2 = 1.f / (se2 + 1e-16f), inv3 = 1.f / (se3 + 1e-16f);
    unsigned short* row = Agg + (size_t)d * 512;
    ushort2 o;
    o.x = f2bf(ac[0][0] * inv0); o.y = f2bf(ac[0][1] * inv0);
    *reinterpret_cast<ushort2*>(&row[0 * 128 + lane * 2]) = o;
    o.x = f2bf(ac[1][0] * inv1); o.y = f2bf(ac[1][1] * inv1);
    *reinterpret_cast<ushort2*>(&row[1 * 128 + lane * 2]) = o;
    o.x = f2bf(ac[2][0] * inv2); o.y = f2bf(ac[2][1] * inv2);
    *reinterpret_cast<ushort2*>(&row[2 * 128 + lane * 2]) = o;
    o.x = f2bf(ac[3][0] * inv3); o.y = f2bf(ac[3][1] * inv3);
    *reinterpret_cast<ushort2*>(&row[3 * 128 + lane * 2]) = o;
}

// ---------------- layer-2 aggregate (256 ch, lane=4ch); writes Agg2[d][1024] ----------------
__global__ __launch_bounds__(256) void fused_agg2(const unsigned short* __restrict__ hb,
                                                  const float4* __restrict__ wbuf,
                                                  const int* __restrict__ srcs,
                                                  const int* __restrict__ offs,
                                                  unsigned short* __restrict__ Agg, int Ndst) {
    int d = blockIdx.x * 4 + (threadIdx.x >> 6);
    if (d >= Ndst) return;
    int lane = threadIdx.x & 63;
    int beg = offs[d], end = offs[d + 1];
    float ac[4][4] = {};
    float se0 = 0.f, se1 = 0.f, se2 = 0.f, se3 = 0.f;

    auto edge = [&](int i) {
        int s = srcs[i];
        float4 w = wbuf[i];
        ushort4 xv = *reinterpret_cast<const ushort4*>(&hb[(size_t)s * 256 + lane * 4]);
        se0 += w.x; se1 += w.y; se2 += w.z; se3 += w.w;
        float f0 = b2f(xv.x), f1 = b2f(xv.y), f2 = b2f(xv.z), f3 = b2f(xv.w);
        ac[0][0] = fmaf(w.x, f0, ac[0][0]); ac[0][1] = fmaf(w.x, f1, ac[0][1]);
        ac[0][2] = fmaf(w.x, f2, ac[0][2]); ac[0][3] = fmaf(w.x, f3, ac[0][3]);
        ac[1][0] = fmaf(w.y, f0, ac[1][0]); ac[1][1] = fmaf(w.y, f1, ac[1][1]);
        ac[1][2] = fmaf(w.y, f2, ac[1][2]); ac[1][3] = fmaf(w.y, f3, ac[1][3]);
        ac[2][0] = fmaf(w.z, f0, ac[2][0]); ac[2][1] = fmaf(w.z, f1, ac[2][1]);
        ac[2][2] = fmaf(w.z, f2, ac[2][2]); ac[2][3] = fmaf(w.z, f3, ac[2][3]);
        ac[3][0] = fmaf(w.w, f0, ac[3][0]); ac[3][1] = fmaf(w.w, f1, ac[3][1]);
        ac[3][2] = fmaf(w.w, f2, ac[3][2]); ac[3][3] = fmaf(w.w, f3, ac[3][3]);
    };
    int i = beg;
    for (; i + 2 <= end; i += 2) { edge(i); edge(i + 1); }
    for (; i < end; ++i) edge(i);

    float inv[4] = {1.f / (se0 + 1e-16f), 1.f / (se1 + 1e-16f),
                    1.f / (se2 + 1e-16f), 1.f / (se3 + 1e-16f)};
    unsigned short* row = Agg + (size_t)d * 1024;
    #pragma unroll
    for (int h = 0; h < 4; ++h) {
        ushort4 o;
        o.x = f2bf(ac[h][0] * inv[h]); o.y = f2bf(ac[h][1] * inv[h]);
        o.z = f2bf(ac[h][2] * inv[h]); o.w = f2bf(ac[h][3] * inv[h]);
        *reinterpret_cast<ushort4*>(&row[h * 256 + lane * 4]) = o;
    }
}

// ---------------- BN apply per row (f32 in) ----------------
template <int ACT, bool OUTBF>
__global__ __launch_bounds__(256) void bn_rows(const float* __restrict__ X,
                                               const float* __restrict__ stats,
                                               const float* __restrict__ gamma,
                                               const float* __restrict__ beta,
                                               void* __restrict__ out, int M) {
    int wid = threadIdx.x >> 6, lane = threadIdx.x & 63;
    int nw = gridDim.x * 4;
    float4 s4 = *reinterpret_cast<const float4*>(&stats[lane * 4]);
    float4 q4 = *reinterpret_cast<const float4*>(&stats[256 + lane * 4]);
    float4 g4 = *reinterpret_cast<const float4*>(&gamma[lane * 4]);
    float4 b4 = *reinterpret_cast<const float4*>(&beta[lane * 4]);
    float invM = 1.f / (float)M;
    float mu[4] = {s4.x * invM, s4.y * invM, s4.z * invM, s4.w * invM};
    float sc[4], sh_[4] = {b4.x, b4.y, b4.z, b4.w};
    {
        float g[4] = {g4.x, g4.y, g4.z, g4.w};
        float q[4] = {q4.x, q4.y, q4.z, q4.w};
        #pragma unroll
        for (int c = 0; c < 4; ++c) {
            float var = q[c] * invM - mu[c] * mu[c];
            sc[c] = rsqrtf(var + kEPS) * g[c];
        }
    }
    for (int row = blockIdx.x * 4 + wid; row < M; row += nw) {
        float4 xv = *reinterpret_cast<const float4*>(&X[(size_t)row * 256 + lane * 4]);
        float v[4] = {xv.x, xv.y, xv.z, xv.w};
        #pragma unroll
        for (int c = 0; c < 4; ++c) {
            float t = (v[c] - mu[c]) * sc[c] + sh_[c];
            if (ACT == 0) t = t > 0.f ? t : expm1f(t);
            else t = fmaxf(t, 0.f);
            v[c] = t;
        }
        if (OUTBF) {
            ushort4 o; o.x = f2bf(v[0]); o.y = f2bf(v[1]); o.z = f2bf(v[2]); o.w = f2bf(v[3]);
            *reinterpret_cast<ushort4*>(&((unsigned short*)out)[(size_t)row * 256 + lane * 4]) = o;
        } else {
            *reinterpret_cast<float4*>(&((float*)out)[(size_t)row * 256 + lane * 4]) =
                make_float4(v[0], v[1], v[2], v[3]);
        }
    }
}

// ---------------- fp32 tiled GEMM (final N=47 head) ----------------
template <bool ACCUM>
__global__ __launch_bounds__(256) void gemm64(const float* __restrict__ A,
                                              const float* __restrict__ B,
                                              float* __restrict__ Cmat,
                                              const float* __restrict__ bias1,
                                              const float* __restrict__ bias2,
                                              int M, int N, int K) {
    __shared__ float As[32][68];
    __shared__ float Bs[32][68];
    const int tid = threadIdx.x;
    const int tx = tid & 15, ty = tid >> 4;
    const int m0 = blockIdx.y * 64, n0 = blockIdx.x * 64;
    float acc[4][4] = {};

    for (int k0 = 0; k0 < K; k0 += 32) {
        #pragma unroll
        for (int t = 0; t < 2; ++t) {
            int i = tid + t * 256;
            int row = i >> 3;
            int kq = (i & 7) << 2;
            float4 v = make_float4(0.f, 0.f, 0.f, 0.f);
            int gr = m0 + row;
            if (gr < M) v = *reinterpret_cast<const float4*>(&A[(size_t)gr * K + k0 + kq]);
            As[kq + 0][row] = v.x; As[kq + 1][row] = v.y;
            As[kq + 2][row] = v.z; As[kq + 3][row] = v.w;
        }
        #pragma unroll
        for (int t = 0; t < 2; ++t) {
            int i = tid + t * 256;
            int kr = i >> 4;
            int cq = (i & 15) << 2;
            #pragma unroll
            for (int j = 0; j < 4; ++j) {
                int gc = n0 + cq + j;
                Bs[kr][cq + j] = (gc < N) ? B[(size_t)(k0 + kr) * N + gc] : 0.f;
            }
        }
        __syncthreads();
        #pragma unroll
        for (int kk = 0; kk < 32; ++kk) {
            float4 a4 = *reinterpret_cast<const float4*>(&As[kk][ty << 2]);
            float4 b4 = *reinterpret_cast<const float4*>(&Bs[kk][tx << 2]);
            float a[4] = {a4.x, a4.y, a4.z, a4.w};
            float b[4] = {b4.x, b4.y, b4.z, b4.w};
            #pragma unroll
            for (int i2 = 0; i2 < 4; ++i2)
                #pragma unroll
                for (int j = 0; j < 4; ++j)
                    acc[i2][j] = fmaf(a[i2], b[j], acc[i2][j]);
        }
        __syncthreads();
    }

    #pragma unroll
    for (int i2 = 0; i2 < 4; ++i2) {
        int row = m0 + (ty << 2) + i2;
        if (row >= M) continue;
        #pragma unroll
        for (int j = 0; j < 4; ++j) {
            int col = n0 + (tx << 2) + j;
            if (col >= N) continue;
            float v = acc[i2][j];
            if (bias1) v += bias1[col];
            if (bias2) v += bias2[col];
            size_t idx = (size_t)row * N + col;
            if (ACCUM) v += Cmat[idx];
            Cmat[idx] = v;
        }
    }
}

extern "C" void kernel_launch(void* const* d_in, const int* in_sizes, int n_in,
                              void* d_out, int out_size, void* d_ws, size_t ws_size,
                              hipStream_t stream) {
    (void)in_sizes; (void)n_in; (void)out_size; (void)ws_size;

    const float* x      = (const float*)d_in[0];
    const int*   src1   = (const int*)d_in[1];
    const int*   dst1   = (const int*)d_in[2];
    const int*   src2   = (const int*)d_in[3];
    const int*   dst2   = (const int*)d_in[4];
    const float* W1     = (const float*)d_in[5];
    const float* a_src1 = (const float*)d_in[6];
    const float* a_dst1 = (const float*)d_in[7];
    const float* b1     = (const float*)d_in[8];
    const float* Wsk1   = (const float*)d_in[9];
    const float* bsk1   = (const float*)d_in[10];
    const float* g1     = (const float*)d_in[11];
    const float* be1    = (const float*)d_in[12];
    const float* W2     = (const float*)d_in[13];
    const float* a_src2 = (const float*)d_in[14];
    const float* a_dst2 = (const float*)d_in[15];
    const float* b2     = (const float*)d_in[16];
    const float* Wsk2   = (const float*)d_in[17];
    const float* bsk2   = (const float*)d_in[18];
    const float* g2     = (const float*)d_in[19];
    const float* be2    = (const float*)d_in[20];
    const float* Wm1    = (const float*)d_in[21];
    const float* bm1    = (const float*)d_in[22];
    const float* gm     = (const float*)d_in[23];
    const float* bem    = (const float*)d_in[24];
    const float* Wm2    = (const float*)d_in[25];
    const float* bm2    = (const float*)d_in[26];

    // ---- workspace layout (float units; all chunks 16B-aligned) ----
    float* ws = (float*)d_ws;
    size_t off = 0;
    auto alloc = [&](size_t n) { float* p = ws + off; off += n; return p; };
    unsigned short* xb    = (unsigned short*)alloc((size_t)kN0 * 128 / 2);
    unsigned short* Agg1  = (unsigned short*)alloc((size_t)kN1 * 512 / 2);
    unsigned short* Agg2  = (unsigned short*)alloc((size_t)kN2 * 1024 / 2);
    unsigned short* h1pre = (unsigned short*)alloc((size_t)kN1 * 256 / 2);
    unsigned short* h1b   = (unsigned short*)alloc((size_t)kN1 * 256 / 2);
    float* h2             = alloc((size_t)kN2 * 256);
    unsigned short* h2b   = (unsigned short*)alloc((size_t)kN2 * 256 / 2);
    float* h3             = alloc((size_t)kN2 * 256);
    unsigned short* Wcat1t = (unsigned short*)alloc(256 * 640 / 2);
    unsigned short* Wcat2t = (unsigned short*)alloc(256 * 1280 / 2);
    unsigned short* Wm1t   = (unsigned short*)alloc(256 * 256 / 2);
    unsigned short* v1t    = (unsigned short*)alloc(16 * 128 / 2);
    unsigned short* v2t    = (unsigned short*)alloc(16 * 256 / 2);
    float4* w1buf = (float4*)alloc((size_t)kE1 * 4);
    float4* w2buf = (float4*)alloc((size_t)kE2 * 4);
    float* als1 = alloc((size_t)kN0 * 4);
    float* ald1 = alloc((size_t)kN1 * 4);
    float* als2 = alloc((size_t)kN1 * 4);
    float* ald2 = alloc((size_t)kN2 * 4);
    float* zreg = alloc(1536 + kN1 + kN1 + kN2 + kN2);
    float* stats1 = zreg, *stats2 = zreg + 512, *stats3 = zreg + 1024;
    int* cnt1 = (int*)(zreg + 1536);
    int* cur1 = cnt1 + kN1;
    int* cnt2 = cur1 + kN1;
    int* cur2 = cnt2 + kN2;
    const int nzreg = 1536 + 2 * kN1 + 2 * kN2;
    int* srcs1  = (int*)alloc(kE1);
    int* offs1  = (int*)alloc(kN1 + 4);
    int* bsum1  = (int*)alloc(128);
    int* bscan1 = (int*)alloc(128);
    int* srcs2  = (int*)alloc(kE2);
    int* offs2  = (int*)alloc(kN2 + 4);
    int* bsum2  = (int*)alloc(128);
    int* bscan2 = (int*)alloc(128);

    hipStream_t st = stream;
    const int nb1 = (kN1 + 1023) / 1024;   // 98
    const int nb2 = (kN2 + 1023) / 1024;   // 20

    // ---- precomputes + init ----
    prep_weights<<<(563200 + 255) / 256, 256, 0, st>>>(W1, a_src1, a_dst1, W2, a_src2, a_dst2,
                                                       Wsk1, Wsk2, Wm1,
                                                       v1t, v2t, Wcat1t, Wcat2t, Wm1t);
    zero_f32<<<512, 256, 0, st>>>(zreg, nzreg);

    // ---- x -> bf16 + layer-1 attention dots (MFMA-fused) ----
    conv_als_mfma<<<2048, 256, 0, st>>>(x, v1t, xb, als1, ald1);

    // ---- CSR builds (merged) ----
    hist_both<<<(kE1 + kE2 + 255) / 256, 256, 0, st>>>(dst1, cnt1, kE1, dst2, cnt2, kE2);
    scan_block_both<<<nb1 + nb2, 256, 0, st>>>(cnt1, kN1, offs1, bsum1, nb1, cnt2, kN2, offs2, bsum2);
    scan_bsums_both<<<1, 256, 0, st>>>(bsum1, bscan1, nb1, bsum2, bscan2, nb2);
    scan_add_both<<<(kN1 + kN2 + 255) / 256, 256, 0, st>>>(offs1, bscan1, cnt1, kN1,
                                                           offs2, bscan2, cnt2, kN2);
    csr_scatter_w<<<(kE1 + 255) / 256, 256, 0, st>>>(dst1, src1, offs1, als1, ald1,
                                                     cur1, srcs1, w1buf, kE1);

    // ================= layer 1 =================
    fused_agg1<<<(kN1 + 3) / 4, 256, 0, st>>>(xb, w1buf, srcs1, offs1, Agg1, kN1);
    gemm_pipe<true, true><<<dim3(2, (kN1 + 127) / 128), 256, 0, st>>>(
        Agg1, 512, xb, 128, Wcat1t, h1pre, b1, bsk1, stats1, kN1, 256, /*rs=*/2, /*kwin=*/256);
    bn_mfma<<<1024, 256, 0, st>>>(h1pre, stats1, g1, be1, h1b, v2t, als2, ald2, kN1, kN2);

    // ================= layer 2 =================
    csr_scatter_w<<<(kE2 + 255) / 256, 256, 0, st>>>(dst2, src2, offs2, als2, ald2,
                                                     cur2, srcs2, w2buf, kE2);
    fused_agg2<<<(kN2 + 3) / 4, 256, 0, st>>>(h1b, w2buf, srcs2, offs2, Agg2, kN2);
    gemm_pipe<false, true><<<dim3(2, (kN2 + 127) / 128), 256, 0, st>>>(
        Agg2, 1024, h1b, 256, Wcat2t, h2, b2, bsk2, stats2, kN2, 256, /*rs=*/4, /*kwin=*/512);
    bn_rows<0, true><<<2048, 256, 0, st>>>(h2, stats2, g2, be2, h2b, kN2);

    // ================= MLP head =================
    gemm_pipe<false, true><<<dim3(2, (kN2 + 127) / 128), 256, 0, st>>>(
        h2b, 256, nullptr, 0, Wm1t, h3, bm1, nullptr, stats3, kN2, 256, /*rs=*/0, /*kwin=*/256);
    bn_rows<1, false><<<2048, 256, 0, st>>>(h3, stats3, gm, bem, h3, kN2);
    gemm64<false><<<dim3(1, (kN2 + 63) / 64), 256, 0, st>>>(
        h3, Wm2, (float*)d_out, bm2, nullptr, kN2, kOUT, 256);
}

// Round 12
// 542.189 us; speedup vs baseline: 1.6777x; 1.0489x over previous
//
#include <hip/hip_runtime.h>
#include <math.h>

// Problem constants (fixed by the reference)
constexpr int kN0 = 400000, kN1 = 100000, kN2 = 20000;
constexpr int kE1 = 1000000, kE2 = 200000;
constexpr int kIN = 128, kHID = 256, kOUT = 47;
constexpr float kEPS = 1e-5f, kNEG = 0.2f;

#define DEV static __device__ __forceinline__

typedef __attribute__((ext_vector_type(8))) short short8;
typedef __attribute__((ext_vector_type(4))) float f32x4;

DEV float b2f(unsigned short u) { return __uint_as_float(((unsigned)u) << 16); }
DEV unsigned short f2bf(float f) {
    unsigned u = __float_as_uint(f);
    unsigned r = (u + 0x7fffu + ((u >> 16) & 1u)) >> 16;   // RNE
    return (unsigned short)r;
}
DEV float lrelu(float v) { return v > 0.f ? v : kNEG * v; }

DEV void gload_lds16(const void* g, void* l) {
    __builtin_amdgcn_global_load_lds(
        (const __attribute__((address_space(1))) void*)g,
        (__attribute__((address_space(3))) void*)l, 16, 0, 0);
}

// ---- merged init: zero zreg + weight precompute (v1t, v2t, Wcat1t, Wcat2t, Wm1t) ----
constexpr int kNZreg = 1536 + 2 * kN1 + 2 * kN2;   // 241536
__global__ void prep_all(const float* __restrict__ W1, const float* __restrict__ as1,
                         const float* __restrict__ ad1,
                         const float* __restrict__ W2, const float* __restrict__ as2,
                         const float* __restrict__ ad2,
                         const float* __restrict__ Wsk1, const float* __restrict__ Wsk2,
                         const float* __restrict__ Wm1,
                         float* __restrict__ zreg,
                         unsigned short* __restrict__ v1t, unsigned short* __restrict__ v2t,
                         unsigned short* __restrict__ Wcat1t,
                         unsigned short* __restrict__ Wcat2t,
                         unsigned short* __restrict__ Wm1t) {
    int i = blockIdx.x * blockDim.x + threadIdx.x;
    if (i < kNZreg) { zreg[i] = 0.f; return; }
    i -= kNZreg;
    if (i < 2048) {                       // v1t[16][128]
        int j = i >> 7, k = i & 127;
        float s = 0.f;
        if (j < 8) {
            int h = j & 3;
            const float* a = (j >= 4) ? ad1 : as1;
            for (int c = 0; c < 64; ++c) s += W1[(size_t)k * 256 + h * 64 + c] * a[h * 64 + c];
        }
        v1t[i] = f2bf(s);
        return;
    }
    i -= 2048;
    if (i < 4096) {                       // v2t[16][256]
        int j = i >> 8, k = i & 255;
        float s = 0.f;
        if (j < 8) {
            int h = j & 3;
            const float* a = (j >= 4) ? ad2 : as2;
            for (int c = 0; c < 64; ++c) s += W2[(size_t)k * 256 + h * 64 + c] * a[h * 64 + c];
        }
        v2t[i] = f2bf(s);
        return;
    }
    i -= 4096;
    if (i < 163840) {                     // Wcat1t[256][640]
        int n = i / 640, k = i % 640;
        float v;
        if (k < 512) { int h = k >> 7, kin = k & 127; v = ((n >> 6) == h) ? W1[(size_t)kin * 256 + n] : 0.f; }
        else v = Wsk1[(size_t)(k - 512) * 256 + n];
        Wcat1t[i] = f2bf(v);
        return;
    }
    i -= 163840;
    if (i < 327680) {                     // Wcat2t[256][1280]
        int n = i / 1280, k = i % 1280;
        float v;
        if (k < 1024) { int h = k >> 8, kin = k & 255; v = ((n >> 6) == h) ? W2[(size_t)kin * 256 + n] : 0.f; }
        else v = Wsk2[(size_t)(k - 1024) * 256 + n];
        Wcat2t[i] = f2bf(v);
        return;
    }
    i -= 327680;
    if (i < 65536) {                      // Wm1t[256][256]
        int n = i >> 8, k = i & 255;
        Wm1t[i] = f2bf(Wm1[(size_t)k * 256 + n]);
    }
}

// ---- fused x->bf16 convert + layer-1 attention dots via MFMA (wave per 16 nodes) ----
__global__ __launch_bounds__(256) void conv_als_mfma(const float* __restrict__ x,
                                                     const unsigned short* __restrict__ v1t,
                                                     unsigned short* __restrict__ xb,
                                                     float* __restrict__ als,
                                                     float* __restrict__ ald) {
    int wid = threadIdx.x >> 6, lane = threadIdx.x & 63;
    int l15 = lane & 15, l4 = lane >> 4;
    short8 bfr[4];
    #pragma unroll
    for (int ks = 0; ks < 4; ++ks)
        bfr[ks] = *reinterpret_cast<const short8*>(&v1t[l15 * 128 + ks * 32 + l4 * 8]);

    const int ntile = kN0 / 16;
    int nw = gridDim.x * 4;
    for (int t = blockIdx.x * 4 + wid; t < ntile; t += nw) {
        int base = t * 16;
        int r = base + l15;
        f32x4 acc = (f32x4){0.f, 0.f, 0.f, 0.f};
        #pragma unroll
        for (int ks = 0; ks < 4; ++ks) {
            size_t o = (size_t)r * 128 + ks * 32 + l4 * 8;
            float4 xa = *reinterpret_cast<const float4*>(&x[o]);
            float4 xc = *reinterpret_cast<const float4*>(&x[o + 4]);
            short8 af;
            af[0] = (short)f2bf(xa.x); af[1] = (short)f2bf(xa.y);
            af[2] = (short)f2bf(xa.z); af[3] = (short)f2bf(xa.w);
            af[4] = (short)f2bf(xc.x); af[5] = (short)f2bf(xc.y);
            af[6] = (short)f2bf(xc.z); af[7] = (short)f2bf(xc.w);
            *reinterpret_cast<short8*>(&xb[o]) = af;
            acc = __builtin_amdgcn_mfma_f32_16x16x32_bf16(af, bfr[ks], acc, 0, 0, 0);
        }
        if (l15 < 8) {
            #pragma unroll
            for (int i = 0; i < 4; ++i) {
                int node = base + l4 * 4 + i;
                if (l15 < 4) als[(size_t)node * 4 + l15] = acc[i];
                else if (node < kN1) ald[(size_t)node * 4 + (l15 - 4)] = acc[i];
            }
        }
    }
}

// ---- fused BN(ELU) bf16->bf16 (+ optional layer-2 attention dots via MFMA) ----
template <bool AL>
__global__ __launch_bounds__(256) void bn_mfma(const unsigned short* __restrict__ X,
                                               const float* __restrict__ stats,
                                               const float* __restrict__ gamma,
                                               const float* __restrict__ beta,
                                               unsigned short* __restrict__ outb,
                                               const unsigned short* __restrict__ v2t,
                                               float* __restrict__ als,
                                               float* __restrict__ ald,
                                               int M, int Ndst) {
    __shared__ float smu[256], ssc[256], ssh[256];
    {
        int c = threadIdx.x;
        float invM = 1.f / (float)M;
        float mu = stats[c] * invM;
        float var = stats[256 + c] * invM - mu * mu;
        smu[c] = mu;
        ssc[c] = rsqrtf(var + kEPS) * gamma[c];
        ssh[c] = beta[c];
    }
    __syncthreads();

    int wid = threadIdx.x >> 6, lane = threadIdx.x & 63;
    int l15 = lane & 15, l4 = lane >> 4;
    short8 bfr[8];
    if (AL) {
        #pragma unroll
        for (int ks = 0; ks < 8; ++ks)
            bfr[ks] = *reinterpret_cast<const short8*>(&v2t[l15 * 256 + ks * 32 + l4 * 8]);
    }

    const int ntile = M / 16;
    int nw = gridDim.x * 4;
    for (int t = blockIdx.x * 4 + wid; t < ntile; t += nw) {
        int base = t * 16;
        int r = base + l15;
        f32x4 acc = (f32x4){0.f, 0.f, 0.f, 0.f};
        #pragma unroll
        for (int ks = 0; ks < 8; ++ks) {
            int c0 = ks * 32 + l4 * 8;
            size_t o = (size_t)r * 256 + c0;
            short8 xr = *reinterpret_cast<const short8*>(&X[o]);
            float4 mua = *reinterpret_cast<const float4*>(&smu[c0]);
            float4 muc = *reinterpret_cast<const float4*>(&smu[c0 + 4]);
            float4 sca = *reinterpret_cast<const float4*>(&ssc[c0]);
            float4 scc = *reinterpret_cast<const float4*>(&ssc[c0 + 4]);
            float4 sha = *reinterpret_cast<const float4*>(&ssh[c0]);
            float4 shc = *reinterpret_cast<const float4*>(&ssh[c0 + 4]);
            float v[8];
            v[0] = (b2f((unsigned short)xr[0]) - mua.x) * sca.x + sha.x;
            v[1] = (b2f((unsigned short)xr[1]) - mua.y) * sca.y + sha.y;
            v[2] = (b2f((unsigned short)xr[2]) - mua.z) * sca.z + sha.z;
            v[3] = (b2f((unsigned short)xr[3]) - mua.w) * sca.w + sha.w;
            v[4] = (b2f((unsigned short)xr[4]) - muc.x) * scc.x + shc.x;
            v[5] = (b2f((unsigned short)xr[5]) - muc.y) * scc.y + shc.y;
            v[6] = (b2f((unsigned short)xr[6]) - muc.z) * scc.z + shc.z;
            v[7] = (b2f((unsigned short)xr[7]) - muc.w) * scc.w + shc.w;
            short8 af;
            #pragma unroll
            for (int i = 0; i < 8; ++i) {
                float tv = v[i] > 0.f ? v[i] : expm1f(v[i]);
                af[i] = (short)f2bf(tv);
            }
            *reinterpret_cast<short8*>(&outb[o]) = af;
            if (AL) acc = __builtin_amdgcn_mfma_f32_16x16x32_bf16(af, bfr[ks], acc, 0, 0, 0);
        }
        if (AL && l15 < 8) {
            #pragma unroll
            for (int i = 0; i < 4; ++i) {
                int node = base + l4 * 4 + i;
                if (l15 < 4) als[(size_t)node * 4 + l15] = acc[i];
                else if (node < Ndst) ald[(size_t)node * 4 + (l15 - 4)] = acc[i];
            }
        }
    }
}

// ================= CSR build (merged both layers) =================
__global__ void hist_both(const int* __restrict__ dst1, int* __restrict__ cnt1, int E1,
                          const int* __restrict__ dst2, int* __restrict__ cnt2, int E2) {
    int e = blockIdx.x * blockDim.x + threadIdx.x;
    if (e < E1) atomicAdd(&cnt1[dst1[e]], 1);
    else if (e - E1 < E2) atomicAdd(&cnt2[dst2[e - E1]], 1);
}

__global__ __launch_bounds__(256) void scan_block_both(const int* __restrict__ cnt1, int n1,
                                                       int* __restrict__ offs1, int* __restrict__ bsum1, int nb1,
                                                       const int* __restrict__ cnt2, int n2,
                                                       int* __restrict__ offs2, int* __restrict__ bsum2) {
    const int* counts; int n; int* offs; int* bsum; int b;
    if ((int)blockIdx.x < nb1) { counts = cnt1; n = n1; offs = offs1; bsum = bsum1; b = blockIdx.x; }
    else { counts = cnt2; n = n2; offs = offs2; bsum = bsum2; b = blockIdx.x - nb1; }
    __shared__ int sh[256];
    int tid = threadIdx.x;
    int base = b * 1024 + tid * 4;
    int c0 = (base + 0 < n) ? counts[base + 0] : 0;
    int c1 = (base + 1 < n) ? counts[base + 1] : 0;
    int c2 = (base + 2 < n) ? counts[base + 2] : 0;
    int c3 = (base + 3 < n) ? counts[base + 3] : 0;
    int tot = c0 + c1 + c2 + c3;
    sh[tid] = tot;
    __syncthreads();
    for (int o = 1; o < 256; o <<= 1) {
        int t = (tid >= o) ? sh[tid - o] : 0;
        __syncthreads();
        sh[tid] += t;
        __syncthreads();
    }
    int excl = sh[tid] - tot;
    if (base + 0 < n) offs[base + 0] = excl;
    if (base + 1 < n) offs[base + 1] = excl + c0;
    if (base + 2 < n) offs[base + 2] = excl + c0 + c1;
    if (base + 3 < n) offs[base + 3] = excl + c0 + c1 + c2;
    if (tid == 255) bsum[b] = sh[255];
}

__global__ __launch_bounds__(256) void scan_bsums_both(const int* __restrict__ bsum1,
                                                       int* __restrict__ bscan1, int nb1,
                                                       const int* __restrict__ bsum2,
                                                       int* __restrict__ bscan2, int nb2) {
    __shared__ int sh[256];
    int tid = threadIdx.x;
    int v = (tid < nb1) ? bsum1[tid] : 0;
    sh[tid] = v;
    __syncthreads();
    for (int o = 1; o < 256; o <<= 1) {
        int t = (tid >= o) ? sh[tid - o] : 0;
        __syncthreads();
        sh[tid] += t;
        __syncthreads();
    }
    if (tid < nb1) bscan1[tid] = sh[tid] - v;
    __syncthreads();
    int v2 = (tid < nb2) ? bsum2[tid] : 0;
    sh[tid] = v2;
    __syncthreads();
    for (int o = 1; o < 256; o <<= 1) {
        int t = (tid >= o) ? sh[tid - o] : 0;
        __syncthreads();
        sh[tid] += t;
        __syncthreads();
    }
    if (tid < nb2) bscan2[tid] = sh[tid] - v2;
}

__global__ void scan_add_both(int* __restrict__ offs1, const int* __restrict__ bscan1,
                              const int* __restrict__ cnt1, int n1,
                              int* __restrict__ offs2, const int* __restrict__ bscan2,
                              const int* __restrict__ cnt2, int n2) {
    int i = blockIdx.x * blockDim.x + threadIdx.x;
    if (i < n1) {
        int v = offs1[i] + bscan1[i >> 10];
        offs1[i] = v;
        if (i == n1 - 1) offs1[n1] = v + cnt1[i];
    } else {
        int j = i - n1;
        if (j < n2) {
            int v = offs2[j] + bscan2[j >> 10];
            offs2[j] = v;
            if (j == n2 - 1) offs2[n2] = v + cnt2[j];
        }
    }
}

// scatter src id + per-edge softmax numerators w[h] = exp(lrelu(als[s]+ald[d]))
__global__ void csr_scatter_w(const int* __restrict__ dst, const int* __restrict__ src,
                              const int* __restrict__ offs,
                              const float* __restrict__ als, const float* __restrict__ ald,
                              int* __restrict__ cur, int* __restrict__ srcs,
                              float4* __restrict__ wbuf, int E) {
    int e = blockIdx.x * blockDim.x + threadIdx.x;
    if (e >= E) return;
    int d = dst[e], s = src[e];
    int pos = offs[d] + atomicAdd(&cur[d], 1);
    srcs[pos] = s;
    float4 a = *reinterpret_cast<const float4*>(&als[(size_t)s * 4]);
    float4 b = *reinterpret_cast<const float4*>(&ald[(size_t)d * 4]);
    float4 w;
    w.x = expf(lrelu(a.x + b.x));
    w.y = expf(lrelu(a.y + b.y));
    w.z = expf(lrelu(a.z + b.z));
    w.w = expf(lrelu(a.w + b.w));
    wbuf[pos] = w;
}

// ================= pipelined bf16 MFMA GEMM, 8 waves, split-A + K-window =================
// C[M][N] = [A1|A2] @ Bt^T + biases. A1's K-window for col-block n0 is [n0*rs*64... ] of width kwin.
// 512 threads = 8 waves (2 row x 4 col), wave output 64x32. BM=BN=128, BK=64, LDS dbuf 64KB.
template <bool OUTBF, bool STATS>
__global__ __launch_bounds__(512) void gemm_pipe(const unsigned short* __restrict__ A1, int K1,
                                                 const unsigned short* __restrict__ A2, int K2,
                                                 const unsigned short* __restrict__ Bt,
                                                 void* __restrict__ Cv,
                                                 const float* __restrict__ bias1,
                                                 const float* __restrict__ bias2,
                                                 float* __restrict__ stats,
                                                 int M, int N, int rs, int kwin) {
    __shared__ unsigned short SH[4][128 * 64];
    const int tid = threadIdx.x;
    const int wid = tid >> 6, lane = tid & 63;
    const int wr = wid >> 2, wc = wid & 3;       // 2 x 4 wave grid; wave = 64 rows x 32 cols
    const int l15 = lane & 15, l4 = lane >> 4;
    const int m0 = blockIdx.y * 128, n0 = blockIdx.x * 128;
    const int rsub = lane >> 3;
    const int kslot = (lane & 7) ^ rsub;
    const int KB = K1 + K2;
    const int nwin = kwin >> 6;
    const int nt = nwin + (K2 >> 6);
    const int wbase = n0 * rs;                   // A1 K-window start for this col-block

    auto stage = [&](int buf, int t) {
        const unsigned short* Asrc; int ka, lda, gk;
        if (t < nwin) { gk = wbase + (t << 6); Asrc = A1; ka = gk; lda = K1; }
        else { int t2 = t - nwin; gk = K1 + (t2 << 6); Asrc = A2; ka = t2 << 6; lda = K2; }
        #pragma unroll
        for (int c = 0; c < 2; ++c) {
            int q = wid * 2 + c;
            int rowA = m0 + q * 8 + rsub; if (rowA > M - 1) rowA = M - 1;
            gload_lds16(Asrc + (size_t)rowA * lda + ka + kslot * 8, &SH[buf][q * 512]);
            int rowB = n0 + q * 8 + rsub;
            gload_lds16(Bt + (size_t)rowB * KB + gk + kslot * 8, &SH[2 + buf][q * 512]);
        }
    };

    f32x4 acc[4][2];
    #pragma unroll
    for (int i = 0; i < 4; ++i)
        #pragma unroll
        for (int j = 0; j < 2; ++j) acc[i][j] = (f32x4){0.f, 0.f, 0.f, 0.f};

    stage(0, 0);
    __syncthreads();
    for (int t = 0; t < nt; ++t) {
        if (t + 1 < nt) stage((t + 1) & 1, t + 1);
        int b = t & 1;
        short8 af[2][4], bf[2][2];
        #pragma unroll
        for (int kk = 0; kk < 2; ++kk) {
            #pragma unroll
            for (int mi = 0; mi < 4; ++mi) {
                int row = wr * 64 + mi * 16 + l15;
                af[kk][mi] = *reinterpret_cast<const short8*>(
                    &SH[b][row * 64 + (((kk * 4 + l4) ^ (row & 7)) << 3)]);
            }
            #pragma unroll
            for (int ni = 0; ni < 2; ++ni) {
                int row = wc * 32 + ni * 16 + l15;
                bf[kk][ni] = *reinterpret_cast<const short8*>(
                    &SH[2 + b][row * 64 + (((kk * 4 + l4) ^ (row & 7)) << 3)]);
            }
        }
        #pragma unroll
        for (int kk = 0; kk < 2; ++kk)
            #pragma unroll
            for (int mi = 0; mi < 4; ++mi)
                #pragma unroll
                for (int ni = 0; ni < 2; ++ni)
                    acc[mi][ni] = __builtin_amdgcn_mfma_f32_16x16x32_bf16(
                        af[kk][mi], bf[kk][ni], acc[mi][ni], 0, 0, 0);
        __syncthreads();
    }

    float csum[2] = {0.f, 0.f}, csq[2] = {0.f, 0.f};
    unsigned short* LB = (unsigned short*)SH;
    float* LF = (float*)SH;
    #pragma unroll
    for (int mi = 0; mi < 4; ++mi) {
        int lrow0 = wr * 64 + mi * 16 + l4 * 4;
        #pragma unroll
        for (int ni = 0; ni < 2; ++ni) {
            int lcol = wc * 32 + ni * 16 + l15;
            int col = n0 + lcol;
            float badd = 0.f;
            if (bias1) badd += bias1[col];
            if (bias2) badd += bias2[col];
            f32x4 v = acc[mi][ni];
            #pragma unroll
            for (int i = 0; i < 4; ++i) {
                float o = v[i] + badd;
                if (STATS && (m0 + lrow0 + i) < M) { csum[ni] += o; csq[ni] += o * o; }
                if (OUTBF) LB[(lrow0 + i) * 128 + lcol] = f2bf(o);
                else LF[(lrow0 + i) * 128 + lcol] = o;
            }
        }
    }
    if (STATS) {
        #pragma unroll
        for (int ni = 0; ni < 2; ++ni) {
            float s = csum[ni], q = csq[ni];
            s += __shfl_xor(s, 16, 64); q += __shfl_xor(q, 16, 64);
            s += __shfl_xor(s, 32, 64); q += __shfl_xor(q, 32, 64);
            if (l4 == 0) {
                int col = n0 + wc * 32 + ni * 16 + l15;
                atomicAdd(&stats[col], s);
                atomicAdd(&stats[256 + col], q);
            }
        }
    }
    __syncthreads();
    if (OUTBF) {
        unsigned short* Cb = (unsigned short*)Cv;
        #pragma unroll
        for (int it = 0; it < 4; ++it) {
            int lin = (it * 512 + tid) * 8;
            int r = lin >> 7, c0 = lin & 127;
            int gr = m0 + r;
            if (gr < M)
                *reinterpret_cast<short8*>(&Cb[(size_t)gr * N + n0 + c0]) =
                    *reinterpret_cast<const short8*>(&LB[lin]);
        }
    } else {
        float* Cf = (float*)Cv;
        #pragma unroll
        for (int it = 0; it < 8; ++it) {
            int lin = (it * 512 + tid) * 4;
            int r = lin >> 7, c0 = lin & 127;
            int gr = m0 + r;
            if (gr < M)
                *reinterpret_cast<float4*>(&Cf[(size_t)gr * N + n0 + c0]) =
                    *reinterpret_cast<const float4*>(&LF[lin]);
        }
    }
}

// ---------------- layer-1 aggregate with precomputed edge weights (wave per dst) ----------------
__global__ __launch_bounds__(256) void fused_agg1(const unsigned short* __restrict__ xb,
                                                  const float4* __restrict__ wbuf,
                                                  const int* __restrict__ srcs,
                                                  const int* __restrict__ offs,
                                                  unsigned short* __restrict__ Agg, int Ndst) {
    int d = blockIdx.x * 4 + (threadIdx.x >> 6);
    if (d >= Ndst) return;
    int lane = threadIdx.x & 63;
    int beg = offs[d], end = offs[d + 1];
    float ac[4][2] = {};
    float se0 = 0.f, se1 = 0.f, se2 = 0.f, se3 = 0.f;

    auto edge = [&](int i) {
        int s = srcs[i];
        float4 w = wbuf[i];
        unsigned xv = *reinterpret_cast<const unsigned*>(&xb[(size_t)s * 128 + lane * 2]);
        se0 += w.x; se1 += w.y; se2 += w.z; se3 += w.w;
        float fx = b2f((unsigned short)(xv & 0xffff));
        float fy = b2f((unsigned short)(xv >> 16));
        ac[0][0] = fmaf(w.x, fx, ac[0][0]); ac[0][1] = fmaf(w.x, fy, ac[0][1]);
        ac[1][0] = fmaf(w.y, fx, ac[1][0]); ac[1][1] = fmaf(w.y, fy, ac[1][1]);
        ac[2][0] = fmaf(w.z, fx, ac[2][0]); ac[2][1] = fmaf(w.z, fy, ac[2][1]);
        ac[3][0] = fmaf(w.w, fx, ac[3][0]); ac[3][1] = fmaf(w.w, fy, ac[3][1]);
    };
    int i = beg;
    for (; i + 4 <= end; i += 4) { edge(i); edge(i + 1); edge(i + 2); edge(i + 3); }
    for (; i < end; ++i) edge(i);

    float inv0 = 1.f / (se0 + 1e-16f), inv1 = 1.f / (se1 + 1e-16f);
    float inv2 = 1.f / (se2 + 1e-16f), inv3 = 1.f / (se3 + 1e-16f);
    unsigned short* row = Agg + (size_t)d * 512;
    ushort2 o;
    o.x = f2bf(ac[0][0] * inv0); o.y = f2bf(ac[0][1] * inv0);
    *reinterpret_cast<ushort2*>(&row[0 * 128 + lane * 2]) = o;
    o.x = f2bf(ac[1][0] * inv1); o.y = f2bf(ac[1][1] * inv1);
    *reinterpret_cast<ushort2*>(&row[1 * 128 + lane * 2]) = o;
    o.x = f2bf(ac[2][0] * inv2); o.y = f2bf(ac[2][1] * inv2);
    *reinterpret_cast<ushort2*>(&row[2 * 128 + lane * 2]) = o;
    o.x = f2bf(ac[3][0] * inv3); o.y = f2bf(ac[3][1] * inv3);
    *reinterpret_cast<ushort2*>(&row[3 * 128 + lane * 2]) = o;
}

// ---------------- layer-2 aggregate (256 ch, lane=4ch); writes Agg2[d][1024] ----------------
__global__ __launch_bounds__(256) void fused_agg2(const unsigned short* __restrict__ hb,
                                                  const float4* __restrict__ wbuf,
                                                  const int* __restrict__ srcs,
                                                  const int* __restrict__ offs,
                                                  unsigned short* __restrict__ Agg, int Ndst) {
    int d = blockIdx.x * 4 + (threadIdx.x >> 6);
    if (d >= Ndst) return;
    int lane = threadIdx.x & 63;
    int beg = offs[d], end = offs[d + 1];
    float ac[4][4] = {};
    float se0 = 0.f, se1 = 0.f, se2 = 0.f, se3 = 0.f;

    auto edge = [&](int i) {
        int s = srcs[i];
        float4 w = wbuf[i];
        ushort4 xv = *reinterpret_cast<const ushort4*>(&hb[(size_t)s * 256 + lane * 4]);
        se0 += w.x; se1 += w.y; se2 += w.z; se3 += w.w;
        float f0 = b2f(xv.x), f1 = b2f(xv.y), f2 = b2f(xv.z), f3 = b2f(xv.w);
        ac[0][0] = fmaf(w.x, f0, ac[0][0]); ac[0][1] = fmaf(w.x, f1, ac[0][1]);
        ac[0][2] = fmaf(w.x, f2, ac[0][2]); ac[0][3] = fmaf(w.x, f3, ac[0][3]);
        ac[1][0] = fmaf(w.y, f0, ac[1][0]); ac[1][1] = fmaf(w.y, f1, ac[1][1]);
        ac[1][2] = fmaf(w.y, f2, ac[1][2]); ac[1][3] = fmaf(w.y, f3, ac[1][3]);
        ac[2][0] = fmaf(w.z, f0, ac[2][0]); ac[2][1] = fmaf(w.z, f1, ac[2][1]);
        ac[2][2] = fmaf(w.z, f2, ac[2][2]); ac[2][3] = fmaf(w.z, f3, ac[2][3]);
        ac[3][0] = fmaf(w.w, f0, ac[3][0]); ac[3][1] = fmaf(w.w, f1, ac[3][1]);
        ac[3][2] = fmaf(w.w, f2, ac[3][2]); ac[3][3] = fmaf(w.w, f3, ac[3][3]);
    };
    int i = beg;
    for (; i + 2 <= end; i += 2) { edge(i); edge(i + 1); }
    for (; i < end; ++i) edge(i);

    float inv[4] = {1.f / (se0 + 1e-16f), 1.f / (se1 + 1e-16f),
                    1.f / (se2 + 1e-16f), 1.f / (se3 + 1e-16f)};
    unsigned short* row = Agg + (size_t)d * 1024;
    #pragma unroll
    for (int h = 0; h < 4; ++h) {
        ushort4 o;
        o.x = f2bf(ac[h][0] * inv[h]); o.y = f2bf(ac[h][1] * inv[h]);
        o.z = f2bf(ac[h][2] * inv[h]); o.w = f2bf(ac[h][3] * inv[h]);
        *reinterpret_cast<ushort4*>(&row[h * 256 + lane * 4]) = o;
    }
}

// ---------------- fp32 tiled GEMM with fused BN(ReLU) on bf16 A (final N=47 head) ----------------
__global__ __launch_bounds__(256) void gemm64_bn(const unsigned short* __restrict__ A,
                                                 const float* __restrict__ B,
                                                 float* __restrict__ Cmat,
                                                 const float* __restrict__ bias,
                                                 const float* __restrict__ stats,
                                                 const float* __restrict__ gamma,
                                                 const float* __restrict__ beta,
                                                 int M, int N, int K) {
    __shared__ float As[32][68];
    __shared__ float Bs[32][68];
    __shared__ float bnsc[256], bnsh[256];
    const int tid = threadIdx.x;
    {
        int c = tid;
        float invM = 1.f / (float)M;
        float mu = stats[c] * invM;
        float var = stats[256 + c] * invM - mu * mu;
        float sc = rsqrtf(var + kEPS) * gamma[c];
        bnsc[c] = sc;
        bnsh[c] = beta[c] - mu * sc;
    }
    __syncthreads();
    const int tx = tid & 15, ty = tid >> 4;
    const int m0 = blockIdx.y * 64, n0 = blockIdx.x * 64;
    float acc[4][4] = {};

    for (int k0 = 0; k0 < K; k0 += 32) {
        #pragma unroll
        for (int t = 0; t < 2; ++t) {
            int i = tid + t * 256;
            int row = i >> 3;
            int kq = (i & 7) << 2;
            ushort4 u = make_ushort4(0, 0, 0, 0);
            int gr = m0 + row;
            if (gr < M) u = *reinterpret_cast<const ushort4*>(&A[(size_t)gr * K + k0 + kq]);
            #pragma unroll
            for (int j = 0; j < 4; ++j) {
                int k = k0 + kq + j;
                unsigned short uv = (j == 0) ? u.x : (j == 1) ? u.y : (j == 2) ? u.z : u.w;
                float v = b2f(uv) * bnsc[k] + bnsh[k];
                As[kq + j][row] = fmaxf(v, 0.f);
            }
        }
        #pragma unroll
        for (int t = 0; t < 2; ++t) {
            int i = tid + t * 256;
            int kr = i >> 4;
            int cq = (i & 15) << 2;
            #pragma unroll
            for (int j = 0; j < 4; ++j) {
                int gc = n0 + cq + j;
                Bs[kr][cq + j] = (gc < N) ? B[(size_t)(k0 + kr) * N + gc] : 0.f;
            }
        }
        __syncthreads();
        #pragma unroll
        for (int kk = 0; kk < 32; ++kk) {
            float4 a4 = *reinterpret_cast<const float4*>(&As[kk][ty << 2]);
            float4 b4 = *reinterpret_cast<const float4*>(&Bs[kk][tx << 2]);
            float a[4] = {a4.x, a4.y, a4.z, a4.w};
            float b[4] = {b4.x, b4.y, b4.z, b4.w};
            #pragma unroll
            for (int i2 = 0; i2 < 4; ++i2)
                #pragma unroll
                for (int j = 0; j < 4; ++j)
                    acc[i2][j] = fmaf(a[i2], b[j], acc[i2][j]);
        }
        __syncthreads();
    }

    #pragma unroll
    for (int i2 = 0; i2 < 4; ++i2) {
        int row = m0 + (ty << 2) + i2;
        if (row >= M) continue;
        #pragma unroll
        for (int j = 0; j < 4; ++j) {
            int col = n0 + (tx << 2) + j;
            if (col >= N) continue;
            Cmat[(size_t)row * N + col] = acc[i2][j] + bias[col];
        }
    }
}

extern "C" void kernel_launch(void* const* d_in, const int* in_sizes, int n_in,
                              void* d_out, int out_size, void* d_ws, size_t ws_size,
                              hipStream_t stream) {
    (void)in_sizes; (void)n_in; (void)out_size; (void)ws_size;

    const float* x      = (const float*)d_in[0];
    const int*   src1   = (const int*)d_in[1];
    const int*   dst1   = (const int*)d_in[2];
    const int*   src2   = (const int*)d_in[3];
    const int*   dst2   = (const int*)d_in[4];
    const float* W1     = (const float*)d_in[5];
    const float* a_src1 = (const float*)d_in[6];
    const float* a_dst1 = (const float*)d_in[7];
    const float* b1     = (const float*)d_in[8];
    const float* Wsk1   = (const float*)d_in[9];
    const float* bsk1   = (const float*)d_in[10];
    const float* g1     = (const float*)d_in[11];
    const float* be1    = (const float*)d_in[12];
    const float* W2     = (const float*)d_in[13];
    const float* a_src2 = (const float*)d_in[14];
    const float* a_dst2 = (const float*)d_in[15];
    const float* b2     = (const float*)d_in[16];
    const float* Wsk2   = (const float*)d_in[17];
    const float* bsk2   = (const float*)d_in[18];
    const float* g2     = (const float*)d_in[19];
    const float* be2    = (const float*)d_in[20];
    const float* Wm1    = (const float*)d_in[21];
    const float* bm1    = (const float*)d_in[22];
    const float* gm     = (const float*)d_in[23];
    const float* bem    = (const float*)d_in[24];
    const float* Wm2    = (const float*)d_in[25];
    const float* bm2    = (const float*)d_in[26];

    // ---- workspace layout (float units; all chunks 16B-aligned) ----
    float* ws = (float*)d_ws;
    size_t off = 0;
    auto alloc = [&](size_t n) { float* p = ws + off; off += n; return p; };
    unsigned short* xb    = (unsigned short*)alloc((size_t)kN0 * 128 / 2);
    unsigned short* Agg1  = (unsigned short*)alloc((size_t)kN1 * 512 / 2);
    unsigned short* Agg2  = (unsigned short*)alloc((size_t)kN2 * 1024 / 2);
    unsigned short* h1pre = (unsigned short*)alloc((size_t)kN1 * 256 / 2);
    unsigned short* h1b   = (unsigned short*)alloc((size_t)kN1 * 256 / 2);
    unsigned short* h2pre = (unsigned short*)alloc((size_t)kN2 * 256 / 2);
    unsigned short* h2b   = (unsigned short*)alloc((size_t)kN2 * 256 / 2);
    unsigned short* h3pre = (unsigned short*)alloc((size_t)kN2 * 256 / 2);
    unsigned short* Wcat1t = (unsigned short*)alloc(256 * 640 / 2);
    unsigned short* Wcat2t = (unsigned short*)alloc(256 * 1280 / 2);
    unsigned short* Wm1t   = (unsigned short*)alloc(256 * 256 / 2);
    unsigned short* v1t    = (unsigned short*)alloc(16 * 128 / 2);
    unsigned short* v2t    = (unsigned short*)alloc(16 * 256 / 2);
    float4* w1buf = (float4*)alloc((size_t)kE1 * 4);
    float4* w2buf = (float4*)alloc((size_t)kE2 * 4);
    float* als1 = alloc((size_t)kN0 * 4);
    float* ald1 = alloc((size_t)kN1 * 4);
    float* als2 = alloc((size_t)kN1 * 4);
    float* ald2 = alloc((size_t)kN2 * 4);
    float* zreg = alloc(kNZreg);
    float* stats1 = zreg, *stats2 = zreg + 512, *stats3 = zreg + 1024;
    int* cnt1 = (int*)(zreg + 1536);
    int* cur1 = cnt1 + kN1;
    int* cnt2 = cur1 + kN1;
    int* cur2 = cnt2 + kN2;
    int* srcs1  = (int*)alloc(kE1);
    int* offs1  = (int*)alloc(kN1 + 4);
    int* bsum1  = (int*)alloc(128);
    int* bscan1 = (int*)alloc(128);
    int* srcs2  = (int*)alloc(kE2);
    int* offs2  = (int*)alloc(kN2 + 4);
    int* bsum2  = (int*)alloc(128);
    int* bscan2 = (int*)alloc(128);

    hipStream_t st = stream;
    const int nb1 = (kN1 + 1023) / 1024;   // 98
    const int nb2 = (kN2 + 1023) / 1024;   // 20

    // ---- init + precomputes (single launch) ----
    prep_all<<<(kNZreg + 563200 + 255) / 256, 256, 0, st>>>(
        W1, a_src1, a_dst1, W2, a_src2, a_dst2, Wsk1, Wsk2, Wm1,
        zreg, v1t, v2t, Wcat1t, Wcat2t, Wm1t);

    // ---- x -> bf16 + layer-1 attention dots (MFMA-fused) ----
    conv_als_mfma<<<2048, 256, 0, st>>>(x, v1t, xb, als1, ald1);

    // ---- CSR builds (merged) ----
    hist_both<<<(kE1 + kE2 + 255) / 256, 256, 0, st>>>(dst1, cnt1, kE1, dst2, cnt2, kE2);
    scan_block_both<<<nb1 + nb2, 256, 0, st>>>(cnt1, kN1, offs1, bsum1, nb1, cnt2, kN2, offs2, bsum2);
    scan_bsums_both<<<1, 256, 0, st>>>(bsum1, bscan1, nb1, bsum2, bscan2, nb2);
    scan_add_both<<<(kN1 + kN2 + 255) / 256, 256, 0, st>>>(offs1, bscan1, cnt1, kN1,
                                                           offs2, bscan2, cnt2, kN2);
    csr_scatter_w<<<(kE1 + 255) / 256, 256, 0, st>>>(dst1, src1, offs1, als1, ald1,
                                                     cur1, srcs1, w1buf, kE1);

    // ================= layer 1 =================
    fused_agg1<<<(kN1 + 3) / 4, 256, 0, st>>>(xb, w1buf, srcs1, offs1, Agg1, kN1);
    gemm_pipe<true, true><<<dim3(2, (kN1 + 127) / 128), 512, 0, st>>>(
        Agg1, 512, xb, 128, Wcat1t, h1pre, b1, bsk1, stats1, kN1, 256, /*rs=*/2, /*kwin=*/256);
    bn_mfma<true><<<1024, 256, 0, st>>>(h1pre, stats1, g1, be1, h1b, v2t, als2, ald2, kN1, kN2);

    // ================= layer 2 =================
    csr_scatter_w<<<(kE2 + 255) / 256, 256, 0, st>>>(dst2, src2, offs2, als2, ald2,
                                                     cur2, srcs2, w2buf, kE2);
    fused_agg2<<<(kN2 + 3) / 4, 256, 0, st>>>(h1b, w2buf, srcs2, offs2, Agg2, kN2);
    gemm_pipe<true, true><<<dim3(2, (kN2 + 127) / 128), 512, 0, st>>>(
        Agg2, 1024, h1b, 256, Wcat2t, h2pre, b2, bsk2, stats2, kN2, 256, /*rs=*/4, /*kwin=*/512);
    bn_mfma<false><<<1024, 256, 0, st>>>(h2pre, stats2, g2, be2, h2b, nullptr, nullptr, nullptr,
                                         kN2, 0);

    // ================= MLP head =================
    gemm_pipe<true, true><<<dim3(2, (kN2 + 127) / 128), 512, 0, st>>>(
        h2b, 256, nullptr, 0, Wm1t, h3pre, bm1, nullptr, stats3, kN2, 256, /*rs=*/0, /*kwin=*/256);
    gemm64_bn<<<dim3(1, (kN2 + 63) / 64), 256, 0, st>>>(
        h3pre, Wm2, (float*)d_out, bm2, stats3, gm, bem, kN2, kOUT, 256);
}

// Round 13
// 522.606 us; speedup vs baseline: 1.7406x; 1.0375x over previous
//
#include <hip/hip_runtime.h>
#include <math.h>

// Problem constants (fixed by the reference)
constexpr int kN0 = 400000, kN1 = 100000, kN2 = 20000;
constexpr int kE1 = 1000000, kE2 = 200000;
constexpr int kIN = 128, kHID = 256, kOUT = 47;
constexpr float kEPS = 1e-5f, kNEG = 0.2f;

#define DEV static __device__ __forceinline__

typedef __attribute__((ext_vector_type(8))) short short8;
typedef __attribute__((ext_vector_type(4))) float f32x4;

DEV float b2f(unsigned short u) { return __uint_as_float(((unsigned)u) << 16); }
DEV unsigned short f2bf(float f) {
    unsigned u = __float_as_uint(f);
    unsigned r = (u + 0x7fffu + ((u >> 16) & 1u)) >> 16;   // RNE
    return (unsigned short)r;
}
DEV float lrelu(float v) { return v > 0.f ? v : kNEG * v; }

DEV void gload_lds16(const void* g, void* l) {
    __builtin_amdgcn_global_load_lds(
        (const __attribute__((address_space(1))) void*)g,
        (__attribute__((address_space(3))) void*)l, 16, 0, 0);
}

// ---- merged init: zero zreg + weight precompute (v1t, v2t, Wcat1t, Wcat2t, Wm1t) ----
constexpr int kNZreg = 1536 + 2 * kN1 + 2 * kN2;   // 241536
__global__ void prep_all(const float* __restrict__ W1, const float* __restrict__ as1,
                         const float* __restrict__ ad1,
                         const float* __restrict__ W2, const float* __restrict__ as2,
                         const float* __restrict__ ad2,
                         const float* __restrict__ Wsk1, const float* __restrict__ Wsk2,
                         const float* __restrict__ Wm1,
                         float* __restrict__ zreg,
                         unsigned short* __restrict__ v1t, unsigned short* __restrict__ v2t,
                         unsigned short* __restrict__ Wcat1t,
                         unsigned short* __restrict__ Wcat2t,
                         unsigned short* __restrict__ Wm1t) {
    int i = blockIdx.x * blockDim.x + threadIdx.x;
    if (i < kNZreg) { zreg[i] = 0.f; return; }
    i -= kNZreg;
    if (i < 2048) {                       // v1t[16][128]
        int j = i >> 7, k = i & 127;
        float s = 0.f;
        if (j < 8) {
            int h = j & 3;
            const float* a = (j >= 4) ? ad1 : as1;
            for (int c = 0; c < 64; ++c) s += W1[(size_t)k * 256 + h * 64 + c] * a[h * 64 + c];
        }
        v1t[i] = f2bf(s);
        return;
    }
    i -= 2048;
    if (i < 4096) {                       // v2t[16][256]
        int j = i >> 8, k = i & 255;
        float s = 0.f;
        if (j < 8) {
            int h = j & 3;
            const float* a = (j >= 4) ? ad2 : as2;
            for (int c = 0; c < 64; ++c) s += W2[(size_t)k * 256 + h * 64 + c] * a[h * 64 + c];
        }
        v2t[i] = f2bf(s);
        return;
    }
    i -= 4096;
    if (i < 163840) {                     // Wcat1t[256][640]
        int n = i / 640, k = i % 640;
        float v;
        if (k < 512) { int h = k >> 7, kin = k & 127; v = ((n >> 6) == h) ? W1[(size_t)kin * 256 + n] : 0.f; }
        else v = Wsk1[(size_t)(k - 512) * 256 + n];
        Wcat1t[i] = f2bf(v);
        return;
    }
    i -= 163840;
    if (i < 327680) {                     // Wcat2t[256][1280]
        int n = i / 1280, k = i % 1280;
        float v;
        if (k < 1024) { int h = k >> 8, kin = k & 255; v = ((n >> 6) == h) ? W2[(size_t)kin * 256 + n] : 0.f; }
        else v = Wsk2[(size_t)(k - 1024) * 256 + n];
        Wcat2t[i] = f2bf(v);
        return;
    }
    i -= 327680;
    if (i < 65536) {                      // Wm1t[256][256]
        int n = i >> 8, k = i & 255;
        Wm1t[i] = f2bf(Wm1[(size_t)k * 256 + n]);
    }
}

// ---- merged: x->bf16 + layer-1 attention dots via MFMA  ||  dst histogram (both layers) ----
constexpr int kConvBlocks = 2048;
__global__ __launch_bounds__(256) void conv_als_hist(const float* __restrict__ x,
                                                     const unsigned short* __restrict__ v1t,
                                                     unsigned short* __restrict__ xb,
                                                     float* __restrict__ als,
                                                     float* __restrict__ ald,
                                                     const int* __restrict__ dst1,
                                                     int* __restrict__ cnt1,
                                                     const int* __restrict__ dst2,
                                                     int* __restrict__ cnt2) {
    if ((int)blockIdx.x >= kConvBlocks) {
        int e = ((int)blockIdx.x - kConvBlocks) * 256 + threadIdx.x;
        if (e < kE1) atomicAdd(&cnt1[dst1[e]], 1);
        else { e -= kE1; if (e < kE2) atomicAdd(&cnt2[dst2[e]], 1); }
        return;
    }
    int wid = threadIdx.x >> 6, lane = threadIdx.x & 63;
    int l15 = lane & 15, l4 = lane >> 4;
    short8 bfr[4];
    #pragma unroll
    for (int ks = 0; ks < 4; ++ks)
        bfr[ks] = *reinterpret_cast<const short8*>(&v1t[l15 * 128 + ks * 32 + l4 * 8]);

    const int ntile = kN0 / 16;
    const int nw = kConvBlocks * 4;
    for (int t = blockIdx.x * 4 + wid; t < ntile; t += nw) {
        int base = t * 16;
        int r = base + l15;
        f32x4 acc = (f32x4){0.f, 0.f, 0.f, 0.f};
        #pragma unroll
        for (int ks = 0; ks < 4; ++ks) {
            size_t o = (size_t)r * 128 + ks * 32 + l4 * 8;
            float4 xa = *reinterpret_cast<const float4*>(&x[o]);
            float4 xc = *reinterpret_cast<const float4*>(&x[o + 4]);
            short8 af;
            af[0] = (short)f2bf(xa.x); af[1] = (short)f2bf(xa.y);
            af[2] = (short)f2bf(xa.z); af[3] = (short)f2bf(xa.w);
            af[4] = (short)f2bf(xc.x); af[5] = (short)f2bf(xc.y);
            af[6] = (short)f2bf(xc.z); af[7] = (short)f2bf(xc.w);
            *reinterpret_cast<short8*>(&xb[o]) = af;
            acc = __builtin_amdgcn_mfma_f32_16x16x32_bf16(af, bfr[ks], acc, 0, 0, 0);
        }
        if (l15 < 8) {
            #pragma unroll
            for (int i = 0; i < 4; ++i) {
                int node = base + l4 * 4 + i;
                if (l15 < 4) als[(size_t)node * 4 + l15] = acc[i];
                else if (node < kN1) ald[(size_t)node * 4 + (l15 - 4)] = acc[i];
            }
        }
    }
}

// ---- fused BN(ELU) bf16->bf16 (+ optional layer-2 attention dots via MFMA) ----
template <bool AL>
__global__ __launch_bounds__(256) void bn_mfma(const unsigned short* __restrict__ X,
                                               const float* __restrict__ stats,
                                               const float* __restrict__ gamma,
                                               const float* __restrict__ beta,
                                               unsigned short* __restrict__ outb,
                                               const unsigned short* __restrict__ v2t,
                                               float* __restrict__ als,
                                               float* __restrict__ ald,
                                               int M, int Ndst) {
    __shared__ float smu[256], ssc[256], ssh[256];
    {
        int c = threadIdx.x;
        float invM = 1.f / (float)M;
        float mu = stats[c] * invM;
        float var = stats[256 + c] * invM - mu * mu;
        smu[c] = mu;
        ssc[c] = rsqrtf(var + kEPS) * gamma[c];
        ssh[c] = beta[c];
    }
    __syncthreads();

    int wid = threadIdx.x >> 6, lane = threadIdx.x & 63;
    int l15 = lane & 15, l4 = lane >> 4;
    short8 bfr[8];
    if (AL) {
        #pragma unroll
        for (int ks = 0; ks < 8; ++ks)
            bfr[ks] = *reinterpret_cast<const short8*>(&v2t[l15 * 256 + ks * 32 + l4 * 8]);
    }

    const int ntile = M / 16;
    int nw = gridDim.x * 4;
    for (int t = blockIdx.x * 4 + wid; t < ntile; t += nw) {
        int base = t * 16;
        int r = base + l15;
        f32x4 acc = (f32x4){0.f, 0.f, 0.f, 0.f};
        #pragma unroll
        for (int ks = 0; ks < 8; ++ks) {
            int c0 = ks * 32 + l4 * 8;
            size_t o = (size_t)r * 256 + c0;
            short8 xr = *reinterpret_cast<const short8*>(&X[o]);
            float4 mua = *reinterpret_cast<const float4*>(&smu[c0]);
            float4 muc = *reinterpret_cast<const float4*>(&smu[c0 + 4]);
            float4 sca = *reinterpret_cast<const float4*>(&ssc[c0]);
            float4 scc = *reinterpret_cast<const float4*>(&ssc[c0 + 4]);
            float4 sha = *reinterpret_cast<const float4*>(&ssh[c0]);
            float4 shc = *reinterpret_cast<const float4*>(&ssh[c0 + 4]);
            float v[8];
            v[0] = (b2f((unsigned short)xr[0]) - mua.x) * sca.x + sha.x;
            v[1] = (b2f((unsigned short)xr[1]) - mua.y) * sca.y + sha.y;
            v[2] = (b2f((unsigned short)xr[2]) - mua.z) * sca.z + sha.z;
            v[3] = (b2f((unsigned short)xr[3]) - mua.w) * sca.w + sha.w;
            v[4] = (b2f((unsigned short)xr[4]) - muc.x) * scc.x + shc.x;
            v[5] = (b2f((unsigned short)xr[5]) - muc.y) * scc.y + shc.y;
            v[6] = (b2f((unsigned short)xr[6]) - muc.z) * scc.z + shc.z;
            v[7] = (b2f((unsigned short)xr[7]) - muc.w) * scc.w + shc.w;
            short8 af;
            #pragma unroll
            for (int i = 0; i < 8; ++i) {
                float tv = v[i] > 0.f ? v[i] : expm1f(v[i]);
                af[i] = (short)f2bf(tv);
            }
            *reinterpret_cast<short8*>(&outb[o]) = af;
            if (AL) acc = __builtin_amdgcn_mfma_f32_16x16x32_bf16(af, bfr[ks], acc, 0, 0, 0);
        }
        if (AL && l15 < 8) {
            #pragma unroll
            for (int i = 0; i < 4; ++i) {
                int node = base + l4 * 4 + i;
                if (l15 < 4) als[(size_t)node * 4 + l15] = acc[i];
                else if (node < Ndst) ald[(size_t)node * 4 + (l15 - 4)] = acc[i];
            }
        }
    }
}

// ================= CSR scans =================
__global__ __launch_bounds__(256) void scan_block_both(const int* __restrict__ cnt1, int n1,
                                                       int* __restrict__ offs1, int* __restrict__ bsum1, int nb1,
                                                       const int* __restrict__ cnt2, int n2,
                                                       int* __restrict__ offs2, int* __restrict__ bsum2) {
    const int* counts; int n; int* offs; int* bsum; int b;
    if ((int)blockIdx.x < nb1) { counts = cnt1; n = n1; offs = offs1; bsum = bsum1; b = blockIdx.x; }
    else { counts = cnt2; n = n2; offs = offs2; bsum = bsum2; b = blockIdx.x - nb1; }
    __shared__ int sh[256];
    int tid = threadIdx.x;
    int base = b * 1024 + tid * 4;
    int c0 = (base + 0 < n) ? counts[base + 0] : 0;
    int c1 = (base + 1 < n) ? counts[base + 1] : 0;
    int c2 = (base + 2 < n) ? counts[base + 2] : 0;
    int c3 = (base + 3 < n) ? counts[base + 3] : 0;
    int tot = c0 + c1 + c2 + c3;
    sh[tid] = tot;
    __syncthreads();
    for (int o = 1; o < 256; o <<= 1) {
        int t = (tid >= o) ? sh[tid - o] : 0;
        __syncthreads();
        sh[tid] += t;
        __syncthreads();
    }
    int excl = sh[tid] - tot;
    if (base + 0 < n) offs[base + 0] = excl;
    if (base + 1 < n) offs[base + 1] = excl + c0;
    if (base + 2 < n) offs[base + 2] = excl + c0 + c1;
    if (base + 3 < n) offs[base + 3] = excl + c0 + c1 + c2;
    if (tid == 255) bsum[b] = sh[255];
}

// scan_add with inline serial scan of block sums (removes a launch)
__global__ __launch_bounds__(256) void scan_add_both(int* __restrict__ offs1,
                                                     const int* __restrict__ bsum1,
                                                     const int* __restrict__ cnt1, int n1, int nb1,
                                                     int* __restrict__ offs2,
                                                     const int* __restrict__ bsum2,
                                                     const int* __restrict__ cnt2, int n2, int nb2) {
    __shared__ int sb1[128], sb2[32];
    if (threadIdx.x == 0) {
        int acc = 0;
        for (int j = 0; j < nb1; ++j) { sb1[j] = acc; acc += bsum1[j]; }
        acc = 0;
        for (int j = 0; j < nb2; ++j) { sb2[j] = acc; acc += bsum2[j]; }
    }
    __syncthreads();
    int i = blockIdx.x * blockDim.x + threadIdx.x;
    if (i < n1) {
        int v = offs1[i] + sb1[i >> 10];
        offs1[i] = v;
        if (i == n1 - 1) offs1[n1] = v + cnt1[i];
    } else {
        int j = i - n1;
        if (j < n2) {
            int v = offs2[j] + sb2[j >> 10];
            offs2[j] = v;
            if (j == n2 - 1) offs2[n2] = v + cnt2[j];
        }
    }
}

// scatter src id + per-edge softmax numerators w[h] = exp(lrelu(als[s]+ald[d]))
__global__ void csr_scatter_w(const int* __restrict__ dst, const int* __restrict__ src,
                              const int* __restrict__ offs,
                              const float* __restrict__ als, const float* __restrict__ ald,
                              int* __restrict__ cur, int* __restrict__ srcs,
                              float4* __restrict__ wbuf, int E) {
    int e = blockIdx.x * blockDim.x + threadIdx.x;
    if (e >= E) return;
    int d = dst[e], s = src[e];
    int pos = offs[d] + atomicAdd(&cur[d], 1);
    srcs[pos] = s;
    float4 a = *reinterpret_cast<const float4*>(&als[(size_t)s * 4]);
    float4 b = *reinterpret_cast<const float4*>(&ald[(size_t)d * 4]);
    float4 w;
    w.x = expf(lrelu(a.x + b.x));
    w.y = expf(lrelu(a.y + b.y));
    w.z = expf(lrelu(a.z + b.z));
    w.w = expf(lrelu(a.w + b.w));
    wbuf[pos] = w;
}

// ================= pipelined bf16 MFMA GEMM, 8 waves, split-A + K-window =================
template <bool OUTBF, bool STATS>
__global__ __launch_bounds__(512) void gemm_pipe(const unsigned short* __restrict__ A1, int K1,
                                                 const unsigned short* __restrict__ A2, int K2,
                                                 const unsigned short* __restrict__ Bt,
                                                 void* __restrict__ Cv,
                                                 const float* __restrict__ bias1,
                                                 const float* __restrict__ bias2,
                                                 float* __restrict__ stats,
                                                 int M, int N, int rs, int kwin) {
    __shared__ unsigned short SH[4][128 * 64];
    const int tid = threadIdx.x;
    const int wid = tid >> 6, lane = tid & 63;
    const int wr = wid >> 2, wc = wid & 3;       // 2 x 4 wave grid; wave = 64 rows x 32 cols
    const int l15 = lane & 15, l4 = lane >> 4;
    const int m0 = blockIdx.y * 128, n0 = blockIdx.x * 128;
    const int rsub = lane >> 3;
    const int kslot = (lane & 7) ^ rsub;
    const int KB = K1 + K2;
    const int nwin = kwin >> 6;
    const int nt = nwin + (K2 >> 6);
    const int wbase = n0 * rs;                   // A1 K-window start for this col-block

    auto stage = [&](int buf, int t) {
        const unsigned short* Asrc; int ka, lda, gk;
        if (t < nwin) { gk = wbase + (t << 6); Asrc = A1; ka = gk; lda = K1; }
        else { int t2 = t - nwin; gk = K1 + (t2 << 6); Asrc = A2; ka = t2 << 6; lda = K2; }
        #pragma unroll
        for (int c = 0; c < 2; ++c) {
            int q = wid * 2 + c;
            int rowA = m0 + q * 8 + rsub; if (rowA > M - 1) rowA = M - 1;
            gload_lds16(Asrc + (size_t)rowA * lda + ka + kslot * 8, &SH[buf][q * 512]);
            int rowB = n0 + q * 8 + rsub;
            gload_lds16(Bt + (size_t)rowB * KB + gk + kslot * 8, &SH[2 + buf][q * 512]);
        }
    };

    f32x4 acc[4][2];
    #pragma unroll
    for (int i = 0; i < 4; ++i)
        #pragma unroll
        for (int j = 0; j < 2; ++j) acc[i][j] = (f32x4){0.f, 0.f, 0.f, 0.f};

    stage(0, 0);
    __syncthreads();
    for (int t = 0; t < nt; ++t) {
        if (t + 1 < nt) stage((t + 1) & 1, t + 1);
        int b = t & 1;
        short8 af[2][4], bf[2][2];
        #pragma unroll
        for (int kk = 0; kk < 2; ++kk) {
            #pragma unroll
            for (int mi = 0; mi < 4; ++mi) {
                int row = wr * 64 + mi * 16 + l15;
                af[kk][mi] = *reinterpret_cast<const short8*>(
                    &SH[b][row * 64 + (((kk * 4 + l4) ^ (row & 7)) << 3)]);
            }
            #pragma unroll
            for (int ni = 0; ni < 2; ++ni) {
                int row = wc * 32 + ni * 16 + l15;
                bf[kk][ni] = *reinterpret_cast<const short8*>(
                    &SH[2 + b][row * 64 + (((kk * 4 + l4) ^ (row & 7)) << 3)]);
            }
        }
        #pragma unroll
        for (int kk = 0; kk < 2; ++kk)
            #pragma unroll
            for (int mi = 0; mi < 4; ++mi)
                #pragma unroll
                for (int ni = 0; ni < 2; ++ni)
                    acc[mi][ni] = __builtin_amdgcn_mfma_f32_16x16x32_bf16(
                        af[kk][mi], bf[kk][ni], acc[mi][ni], 0, 0, 0);
        __syncthreads();
    }

    float csum[2] = {0.f, 0.f}, csq[2] = {0.f, 0.f};
    unsigned short* LB = (unsigned short*)SH;
    float* LF = (float*)SH;
    #pragma unroll
    for (int mi = 0; mi < 4; ++mi) {
        int lrow0 = wr * 64 + mi * 16 + l4 * 4;
        #pragma unroll
        for (int ni = 0; ni < 2; ++ni) {
            int lcol = wc * 32 + ni * 16 + l15;
            int col = n0 + lcol;
            float badd = 0.f;
            if (bias1) badd += bias1[col];
            if (bias2) badd += bias2[col];
            f32x4 v = acc[mi][ni];
            #pragma unroll
            for (int i = 0; i < 4; ++i) {
                float o = v[i] + badd;
                if (STATS && (m0 + lrow0 + i) < M) { csum[ni] += o; csq[ni] += o * o; }
                if (OUTBF) LB[(lrow0 + i) * 128 + lcol] = f2bf(o);
                else LF[(lrow0 + i) * 128 + lcol] = o;
            }
        }
    }
    if (STATS) {
        #pragma unroll
        for (int ni = 0; ni < 2; ++ni) {
            float s = csum[ni], q = csq[ni];
            s += __shfl_xor(s, 16, 64); q += __shfl_xor(q, 16, 64);
            s += __shfl_xor(s, 32, 64); q += __shfl_xor(q, 32, 64);
            if (l4 == 0) {
                int col = n0 + wc * 32 + ni * 16 + l15;
                atomicAdd(&stats[col], s);
                atomicAdd(&stats[256 + col], q);
            }
        }
    }
    __syncthreads();
    if (OUTBF) {
        unsigned short* Cb = (unsigned short*)Cv;
        #pragma unroll
        for (int it = 0; it < 4; ++it) {
            int lin = (it * 512 + tid) * 8;
            int r = lin >> 7, c0 = lin & 127;
            int gr = m0 + r;
            if (gr < M)
                *reinterpret_cast<short8*>(&Cb[(size_t)gr * N + n0 + c0]) =
                    *reinterpret_cast<const short8*>(&LB[lin]);
        }
    } else {
        float* Cf = (float*)Cv;
        #pragma unroll
        for (int it = 0; it < 8; ++it) {
            int lin = (it * 512 + tid) * 4;
            int r = lin >> 7, c0 = lin & 127;
            int gr = m0 + r;
            if (gr < M)
                *reinterpret_cast<float4*>(&Cf[(size_t)gr * N + n0 + c0]) =
                    *reinterpret_cast<const float4*>(&LF[lin]);
        }
    }
}

// ---------------- layer-1 aggregate: predicated 4-group pipeline (wave per dst) ----------------
__global__ __launch_bounds__(256) void fused_agg1(const unsigned short* __restrict__ xb,
                                                  const float4* __restrict__ wbuf,
                                                  const int* __restrict__ srcs,
                                                  const int* __restrict__ offs,
                                                  unsigned short* __restrict__ Agg, int Ndst) {
    int d = blockIdx.x * 4 + (threadIdx.x >> 6);
    if (d >= Ndst) return;
    int lane = threadIdx.x & 63;
    int beg = offs[d], end = offs[d + 1];
    float ac[4][2] = {};
    float se0 = 0.f, se1 = 0.f, se2 = 0.f, se3 = 0.f;

    for (int i = beg; i < end; i += 4) {
        int s[4]; float4 w[4]; unsigned xv[4];
        #pragma unroll
        for (int j = 0; j < 4; ++j) {
            int idx = i + j < end ? i + j : end - 1;
            s[j] = srcs[idx];
            if (i + j < end) w[j] = wbuf[idx];
            else w[j] = make_float4(0.f, 0.f, 0.f, 0.f);
        }
        #pragma unroll
        for (int j = 0; j < 4; ++j)
            xv[j] = *reinterpret_cast<const unsigned*>(&xb[(size_t)s[j] * 128 + lane * 2]);
        #pragma unroll
        for (int j = 0; j < 4; ++j) {
            se0 += w[j].x; se1 += w[j].y; se2 += w[j].z; se3 += w[j].w;
            float fx = b2f((unsigned short)(xv[j] & 0xffff));
            float fy = b2f((unsigned short)(xv[j] >> 16));
            ac[0][0] = fmaf(w[j].x, fx, ac[0][0]); ac[0][1] = fmaf(w[j].x, fy, ac[0][1]);
            ac[1][0] = fmaf(w[j].y, fx, ac[1][0]); ac[1][1] = fmaf(w[j].y, fy, ac[1][1]);
            ac[2][0] = fmaf(w[j].z, fx, ac[2][0]); ac[2][1] = fmaf(w[j].z, fy, ac[2][1]);
            ac[3][0] = fmaf(w[j].w, fx, ac[3][0]); ac[3][1] = fmaf(w[j].w, fy, ac[3][1]);
        }
    }

    float inv0 = 1.f / (se0 + 1e-16f), inv1 = 1.f / (se1 + 1e-16f);
    float inv2 = 1.f / (se2 + 1e-16f), inv3 = 1.f / (se3 + 1e-16f);
    unsigned short* row = Agg + (size_t)d * 512;
    ushort2 o;
    o.x = f2bf(ac[0][0] * inv0); o.y = f2bf(ac[0][1] * inv0);
    *reinterpret_cast<ushort2*>(&row[0 * 128 + lane * 2]) = o;
    o.x = f2bf(ac[1][0] * inv1); o.y = f2bf(ac[1][1] * inv1);
    *reinterpret_cast<ushort2*>(&row[1 * 128 + lane * 2]) = o;
    o.x = f2bf(ac[2][0] * inv2); o.y = f2bf(ac[2][1] * inv2);
    *reinterpret_cast<ushort2*>(&row[2 * 128 + lane * 2]) = o;
    o.x = f2bf(ac[3][0] * inv3); o.y = f2bf(ac[3][1] * inv3);
    *reinterpret_cast<ushort2*>(&row[3 * 128 + lane * 2]) = o;
}

// ---------------- layer-2 aggregate: predicated 4-group pipeline (256 ch, lane=4ch) ----------------
__global__ __launch_bounds__(256) void fused_agg2(const unsigned short* __restrict__ hb,
                                                  const float4* __restrict__ wbuf,
                                                  const int* __restrict__ srcs,
                                                  const int* __restrict__ offs,
                                                  unsigned short* __restrict__ Agg, int Ndst) {
    int d = blockIdx.x * 4 + (threadIdx.x >> 6);
    if (d >= Ndst) return;
    int lane = threadIdx.x & 63;
    int beg = offs[d], end = offs[d + 1];
    float ac[4][4] = {};
    float se0 = 0.f, se1 = 0.f, se2 = 0.f, se3 = 0.f;

    for (int i = beg; i < end; i += 4) {
        int s[4]; float4 w[4]; ushort4 xv[4];
        #pragma unroll
        for (int j = 0; j < 4; ++j) {
            int idx = i + j < end ? i + j : end - 1;
            s[j] = srcs[idx];
            if (i + j < end) w[j] = wbuf[idx];
            else w[j] = make_float4(0.f, 0.f, 0.f, 0.f);
        }
        #pragma unroll
        for (int j = 0; j < 4; ++j)
            xv[j] = *reinterpret_cast<const ushort4*>(&hb[(size_t)s[j] * 256 + lane * 4]);
        #pragma unroll
        for (int j = 0; j < 4; ++j) {
            se0 += w[j].x; se1 += w[j].y; se2 += w[j].z; se3 += w[j].w;
            float f0 = b2f(xv[j].x), f1 = b2f(xv[j].y), f2 = b2f(xv[j].z), f3 = b2f(xv[j].w);
            ac[0][0] = fmaf(w[j].x, f0, ac[0][0]); ac[0][1] = fmaf(w[j].x, f1, ac[0][1]);
            ac[0][2] = fmaf(w[j].x, f2, ac[0][2]); ac[0][3] = fmaf(w[j].x, f3, ac[0][3]);
            ac[1][0] = fmaf(w[j].y, f0, ac[1][0]); ac[1][1] = fmaf(w[j].y, f1, ac[1][1]);
            ac[1][2] = fmaf(w[j].y, f2, ac[1][2]); ac[1][3] = fmaf(w[j].y, f3, ac[1][3]);
            ac[2][0] = fmaf(w[j].z, f0, ac[2][0]); ac[2][1] = fmaf(w[j].z, f1, ac[2][1]);
            ac[2][2] = fmaf(w[j].z, f2, ac[2][2]); ac[2][3] = fmaf(w[j].z, f3, ac[2][3]);
            ac[3][0] = fmaf(w[j].w, f0, ac[3][0]); ac[3][1] = fmaf(w[j].w, f1, ac[3][1]);
            ac[3][2] = fmaf(w[j].w, f2, ac[3][2]); ac[3][3] = fmaf(w[j].w, f3, ac[3][3]);
        }
    }

    float inv[4] = {1.f / (se0 + 1e-16f), 1.f / (se1 + 1e-16f),
                    1.f / (se2 + 1e-16f), 1.f / (se3 + 1e-16f)};
    unsigned short* row = Agg + (size_t)d * 1024;
    #pragma unroll
    for (int h = 0; h < 4; ++h) {
        ushort4 o;
        o.x = f2bf(ac[h][0] * inv[h]); o.y = f2bf(ac[h][1] * inv[h]);
        o.z = f2bf(ac[h][2] * inv[h]); o.w = f2bf(ac[h][3] * inv[h]);
        *reinterpret_cast<ushort4*>(&row[h * 256 + lane * 4]) = o;
    }
}

// ---------------- fp32 tiled GEMM with fused BN(ReLU) on bf16 A (final N=47 head) ----------------
__global__ __launch_bounds__(256) void gemm64_bn(const unsigned short* __restrict__ A,
                                                 const float* __restrict__ B,
                                                 float* __restrict__ Cmat,
                                                 const float* __restrict__ bias,
                                                 const float* __restrict__ stats,
                                                 const float* __restrict__ gamma,
                                                 const float* __restrict__ beta,
                                                 int M, int N, int K) {
    __shared__ float As[32][68];
    __shared__ float Bs[32][68];
    __shared__ float bnsc[256], bnsh[256];
    const int tid = threadIdx.x;
    {
        int c = tid;
        float invM = 1.f / (float)M;
        float mu = stats[c] * invM;
        float var = stats[256 + c] * invM - mu * mu;
        float sc = rsqrtf(var + kEPS) * gamma[c];
        bnsc[c] = sc;
        bnsh[c] = beta[c] - mu * sc;
    }
    __syncthreads();
    const int tx = tid & 15, ty = tid >> 4;
    const int m0 = blockIdx.y * 64, n0 = blockIdx.x * 64;
    float acc[4][4] = {};

    for (int k0 = 0; k0 < K; k0 += 32) {
        #pragma unroll
        for (int t = 0; t < 2; ++t) {
            int i = tid + t * 256;
            int row = i >> 3;
            int kq = (i & 7) << 2;
            ushort4 u = make_ushort4(0, 0, 0, 0);
            int gr = m0 + row;
            if (gr < M) u = *reinterpret_cast<const ushort4*>(&A[(size_t)gr * K + k0 + kq]);
            #pragma unroll
            for (int j = 0; j < 4; ++j) {
                int k = k0 + kq + j;
                unsigned short uv = (j == 0) ? u.x : (j == 1) ? u.y : (j == 2) ? u.z : u.w;
                float v = b2f(uv) * bnsc[k] + bnsh[k];
                As[kq + j][row] = fmaxf(v, 0.f);
            }
        }
        #pragma unroll
        for (int t = 0; t < 2; ++t) {
            int i = tid + t * 256;
            int kr = i >> 4;
            int cq = (i & 15) << 2;
            #pragma unroll
            for (int j = 0; j < 4; ++j) {
                int gc = n0 + cq + j;
                Bs[kr][cq + j] = (gc < N) ? B[(size_t)(k0 + kr) * N + gc] : 0.f;
            }
        }
        __syncthreads();
        #pragma unroll
        for (int kk = 0; kk < 32; ++kk) {
            float4 a4 = *reinterpret_cast<const float4*>(&As[kk][ty << 2]);
            float4 b4 = *reinterpret_cast<const float4*>(&Bs[kk][tx << 2]);
            float a[4] = {a4.x, a4.y, a4.z, a4.w};
            float b[4] = {b4.x, b4.y, b4.z, b4.w};
            #pragma unroll
            for (int i2 = 0; i2 < 4; ++i2)
                #pragma unroll
                for (int j = 0; j < 4; ++j)
                    acc[i2][j] = fmaf(a[i2], b[j], acc[i2][j]);
        }
        __syncthreads();
    }

    #pragma unroll
    for (int i2 = 0; i2 < 4; ++i2) {
        int row = m0 + (ty << 2) + i2;
        if (row >= M) continue;
        #pragma unroll
        for (int j = 0; j < 4; ++j) {
            int col = n0 + (tx << 2) + j;
            if (col >= N) continue;
            Cmat[(size_t)row * N + col] = acc[i2][j] + bias[col];
        }
    }
}

extern "C" void kernel_launch(void* const* d_in, const int* in_sizes, int n_in,
                              void* d_out, int out_size, void* d_ws, size_t ws_size,
                              hipStream_t stream) {
    (void)in_sizes; (void)n_in; (void)out_size; (void)ws_size;

    const float* x      = (const float*)d_in[0];
    const int*   src1   = (const int*)d_in[1];
    const int*   dst1   = (const int*)d_in[2];
    const int*   src2   = (const int*)d_in[3];
    const int*   dst2   = (const int*)d_in[4];
    const float* W1     = (const float*)d_in[5];
    const float* a_src1 = (const float*)d_in[6];
    const float* a_dst1 = (const float*)d_in[7];
    const float* b1     = (const float*)d_in[8];
    const float* Wsk1   = (const float*)d_in[9];
    const float* bsk1   = (const float*)d_in[10];
    const float* g1     = (const float*)d_in[11];
    const float* be1    = (const float*)d_in[12];
    const float* W2     = (const float*)d_in[13];
    const float* a_src2 = (const float*)d_in[14];
    const float* a_dst2 = (const float*)d_in[15];
    const float* b2     = (const float*)d_in[16];
    const float* Wsk2   = (const float*)d_in[17];
    const float* bsk2   = (const float*)d_in[18];
    const float* g2     = (const float*)d_in[19];
    const float* be2    = (const float*)d_in[20];
    const float* Wm1    = (const float*)d_in[21];
    const float* bm1    = (const float*)d_in[22];
    const float* gm     = (const float*)d_in[23];
    const float* bem    = (const float*)d_in[24];
    const float* Wm2    = (const float*)d_in[25];
    const float* bm2    = (const float*)d_in[26];

    // ---- workspace layout (float units; all chunks 16B-aligned) ----
    float* ws = (float*)d_ws;
    size_t off = 0;
    auto alloc = [&](size_t n) { float* p = ws + off; off += n; return p; };
    unsigned short* xb    = (unsigned short*)alloc((size_t)kN0 * 128 / 2);
    unsigned short* Agg1  = (unsigned short*)alloc((size_t)kN1 * 512 / 2);
    unsigned short* Agg2  = (unsigned short*)alloc((size_t)kN2 * 1024 / 2);
    unsigned short* h1pre = (unsigned short*)alloc((size_t)kN1 * 256 / 2);
    unsigned short* h1b   = (unsigned short*)alloc((size_t)kN1 * 256 / 2);
    unsigned short* h2pre = (unsigned short*)alloc((size_t)kN2 * 256 / 2);
    unsigned short* h2b   = (unsigned short*)alloc((size_t)kN2 * 256 / 2);
    unsigned short* h3pre = (unsigned short*)alloc((size_t)kN2 * 256 / 2);
    unsigned short* Wcat1t = (unsigned short*)alloc(256 * 640 / 2);
    unsigned short* Wcat2t = (unsigned short*)alloc(256 * 1280 / 2);
    unsigned short* Wm1t   = (unsigned short*)alloc(256 * 256 / 2);
    unsigned short* v1t    = (unsigned short*)alloc(16 * 128 / 2);
    unsigned short* v2t    = (unsigned short*)alloc(16 * 256 / 2);
    float4* w1buf = (float4*)alloc((size_t)kE1 * 4);
    float4* w2buf = (float4*)alloc((size_t)kE2 * 4);
    float* als1 = alloc((size_t)kN0 * 4);
    float* ald1 = alloc((size_t)kN1 * 4);
    float* als2 = alloc((size_t)kN1 * 4);
    float* ald2 = alloc((size_t)kN2 * 4);
    float* zreg = alloc(kNZreg);
    float* stats1 = zreg, *stats2 = zreg + 512, *stats3 = zreg + 1024;
    int* cnt1 = (int*)(zreg + 1536);
    int* cur1 = cnt1 + kN1;
    int* cnt2 = cur1 + kN1;
    int* cur2 = cnt2 + kN2;
    int* srcs1  = (int*)alloc(kE1);
    int* offs1  = (int*)alloc(kN1 + 4);
    int* bsum1  = (int*)alloc(128);
    int* srcs2  = (int*)alloc(kE2);
    int* offs2  = (int*)alloc(kN2 + 4);
    int* bsum2  = (int*)alloc(128);

    hipStream_t st = stream;
    const int nb1 = (kN1 + 1023) / 1024;   // 98
    const int nb2 = (kN2 + 1023) / 1024;   // 20

    // ---- init + precomputes (single launch) ----
    prep_all<<<(kNZreg + 563200 + 255) / 256, 256, 0, st>>>(
        W1, a_src1, a_dst1, W2, a_src2, a_dst2, Wsk1, Wsk2, Wm1,
        zreg, v1t, v2t, Wcat1t, Wcat2t, Wm1t);

    // ---- x -> bf16 + layer-1 attention dots  ||  dst histograms (merged) ----
    const int histBlocks = (kE1 + kE2 + 255) / 256;
    conv_als_hist<<<kConvBlocks + histBlocks, 256, 0, st>>>(
        x, v1t, xb, als1, ald1, dst1, cnt1, dst2, cnt2);

    // ---- CSR scans ----
    scan_block_both<<<nb1 + nb2, 256, 0, st>>>(cnt1, kN1, offs1, bsum1, nb1, cnt2, kN2, offs2, bsum2);
    scan_add_both<<<(kN1 + kN2 + 255) / 256, 256, 0, st>>>(offs1, bsum1, cnt1, kN1, nb1,
                                                           offs2, bsum2, cnt2, kN2, nb2);
    csr_scatter_w<<<(kE1 + 255) / 256, 256, 0, st>>>(dst1, src1, offs1, als1, ald1,
                                                     cur1, srcs1, w1buf, kE1);

    // ================= layer 1 =================
    fused_agg1<<<(kN1 + 3) / 4, 256, 0, st>>>(xb, w1buf, srcs1, offs1, Agg1, kN1);
    gemm_pipe<true, true><<<dim3(2, (kN1 + 127) / 128), 512, 0, st>>>(
        Agg1, 512, xb, 128, Wcat1t, h1pre, b1, bsk1, stats1, kN1, 256, /*rs=*/2, /*kwin=*/256);
    bn_mfma<true><<<1024, 256, 0, st>>>(h1pre, stats1, g1, be1, h1b, v2t, als2, ald2, kN1, kN2);

    // ================= layer 2 =================
    csr_scatter_w<<<(kE2 + 255) / 256, 256, 0, st>>>(dst2, src2, offs2, als2, ald2,
                                                     cur2, srcs2, w2buf, kE2);
    fused_agg2<<<(kN2 + 3) / 4, 256, 0, st>>>(h1b, w2buf, srcs2, offs2, Agg2, kN2);
    gemm_pipe<true, true><<<dim3(2, (kN2 + 127) / 128), 512, 0, st>>>(
        Agg2, 1024, h1b, 256, Wcat2t, h2pre, b2, bsk2, stats2, kN2, 256, /*rs=*/4, /*kwin=*/512);
    bn_mfma<false><<<1024, 256, 0, st>>>(h2pre, stats2, g2, be2, h2b, nullptr, nullptr, nullptr,
                                         kN2, 0);

    // ================= MLP head =================
    gemm_pipe<true, true><<<dim3(2, (kN2 + 127) / 128), 512, 0, st>>>(
        h2b, 256, nullptr, 0, Wm1t, h3pre, bm1, nullptr, stats3, kN2, 256, /*rs=*/0, /*kwin=*/256);
    gemm64_bn<<<dim3(1, (kN2 + 63) / 64), 256, 0, st>>>(
        h3pre, Wm2, (float*)d_out, bm2, stats3, gm, bem, kN2, kOUT, 256);
}